// Round 1
// 2629.694 us; speedup vs baseline: 1.0074x; 1.0074x over previous
//
#include <hip/hip_runtime.h>
#include <hip/hip_bf16.h>
#include <math.h>

#define N_NODES 50000
#define E_EDGES 400000
#define DIM 128
#define HEADS 8
#define CH 16
#define EDIM 64
#define HCDIM 128   // HEADS*CH

#define ECHUNK 50000     // edge chunk for eproj recompute (8 chunks)
#define FCHUNK 100000    // edge chunk for FFN (4 chunks)
#define NODE_WAVES 4

// ---------------- utility kernels ----------------

__global__ void fill_kernel(float* p, float v, int n) {
    int i = blockIdx.x * blockDim.x + threadIdx.x;
    if (i < n) p[i] = v;
}

__device__ inline float gelu_f(float x) {
    return 0.5f * x * (1.0f + erff(x * 0.70710678118654752f));
}

__device__ inline float softplus_f(float x) {
    return x > 20.f ? x : log1pf(expf(x));
}

// ---------------- tiled fp32 GEMM: C = act(scale(A)(MxK) @ W(KxN) + bias) ----------------
// K % 16 == 0. BM=128 fixed; BN in {64,128}; per-thread 8 x TN micro-tile in 2x2 split
// sub-tiles (rows ty*4 / 64+ty*4, cols tx*4 / 64+tx*4) so every ds_read_b128 is <=2-way
// bank-aliased (free). act: 0 = none, 1 = gelu.
// ascale (optional): per-row, per-16-col scale: A[r][k] *= ascale[r*(K/16) + k/16]
template<int BN, int TN>
__global__ __launch_bounds__(256) void gemm_tile(
    const float* __restrict__ A, const float* __restrict__ W,
    const float* __restrict__ bias, const float* __restrict__ ascale,
    float* __restrict__ C, int M, int K, int Nc, int act)
{
    __shared__ float As[16][132];
    __shared__ float Ws[16][BN + 4];
    const int tid = threadIdx.x;
    const int m0 = blockIdx.y * 128;
    const int n0 = blockIdx.x * BN;
    const int tx = tid & 15;
    const int ty = tid >> 4;
    const int k16 = K >> 4;

    float acc[8][TN];
#pragma unroll
    for (int i = 0; i < 8; ++i)
#pragma unroll
        for (int j = 0; j < TN; ++j) acc[i][j] = 0.f;

    for (int k0 = 0; k0 < K; k0 += 16) {
        // ---- load A tile (128 x 16), store transposed to LDS ----
#pragma unroll
        for (int it = 0; it < 2; ++it) {
            int idx = tid + it * 256;
            int r = idx >> 2;
            int c4 = (idx & 3) << 2;
            int ar = m0 + r;
            float4 av = make_float4(0.f, 0.f, 0.f, 0.f);
            if (ar < M) {
                av = *(const float4*)(A + (size_t)ar * K + k0 + c4);
                if (ascale) {
                    float sc = ascale[(size_t)ar * k16 + (k0 >> 4)];
                    av.x *= sc; av.y *= sc; av.z *= sc; av.w *= sc;
                }
            }
            As[c4 + 0][r] = av.x;
            As[c4 + 1][r] = av.y;
            As[c4 + 2][r] = av.z;
            As[c4 + 3][r] = av.w;
        }
        // ---- load W tile (16 x BN) ----
        if constexpr (BN == 128) {
#pragma unroll
            for (int it = 0; it < 2; ++it) {
                int idx = tid + it * 256;
                int k = idx >> 5;
                int c4 = (idx & 31) << 2;
                *(float4*)&Ws[k][c4] = *(const float4*)(W + (size_t)(k0 + k) * Nc + n0 + c4);
            }
        } else {
            int k = tid >> 4;
            int c4 = (tid & 15) << 2;
            *(float4*)&Ws[k][c4] = *(const float4*)(W + (size_t)(k0 + k) * Nc + n0 + c4);
        }
        __syncthreads();
#pragma unroll
        for (int kk = 0; kk < 16; ++kk) {
            float a[8], b[TN];
            *(float4*)&a[0] = *(const float4*)&As[kk][ty * 4];
            *(float4*)&a[4] = *(const float4*)&As[kk][64 + ty * 4];
            *(float4*)&b[0] = *(const float4*)&Ws[kk][tx * 4];
            if constexpr (TN == 8) {
                *(float4*)&b[4] = *(const float4*)&Ws[kk][64 + tx * 4];
            }
#pragma unroll
            for (int i = 0; i < 8; ++i)
#pragma unroll
                for (int j = 0; j < TN; ++j) acc[i][j] += a[i] * b[j];
        }
        __syncthreads();
    }

    // ---- epilogue ----
    float bb[TN];
#pragma unroll
    for (int j = 0; j < TN; ++j) bb[j] = 0.f;
    if (bias) {
        *(float4*)&bb[0] = *(const float4*)(bias + n0 + tx * 4);
        if constexpr (TN == 8) {
            *(float4*)&bb[4] = *(const float4*)(bias + n0 + 64 + tx * 4);
        }
    }
#pragma unroll
    for (int i = 0; i < 8; ++i) {
        int r = m0 + (i >> 2) * 64 + ty * 4 + (i & 3);
        if (r < M) {
#pragma unroll
            for (int jh = 0; jh < TN / 4; ++jh) {
                float4 o;
                o.x = acc[i][jh * 4 + 0] + bb[jh * 4 + 0];
                o.y = acc[i][jh * 4 + 1] + bb[jh * 4 + 1];
                o.z = acc[i][jh * 4 + 2] + bb[jh * 4 + 2];
                o.w = acc[i][jh * 4 + 3] + bb[jh * 4 + 3];
                if (act == 1) { o.x = gelu_f(o.x); o.y = gelu_f(o.y); o.z = gelu_f(o.z); o.w = gelu_f(o.w); }
                *(float4*)(C + (size_t)r * Nc + n0 + jh * 64 + tx * 4) = o;
            }
        }
    }
}

static inline void launch_gemm(const float* A, const float* W, const float* bias,
                               const float* ascale, float* C, int M, int K, int Nc,
                               int act, hipStream_t stream)
{
    int gy = (M + 127) / 128;
    if (Nc % 128 == 0) {
        gemm_tile<128, 8><<<dim3(Nc / 128, gy), dim3(256), 0, stream>>>(A, W, bias, ascale, C, M, K, Nc, act);
    } else {
        gemm_tile<64, 4><<<dim3(Nc / 64, gy), dim3(256), 0, stream>>>(A, W, bias, ascale, C, M, K, Nc, act);
    }
}

// ---------------- precompute: WeX[k][h*16+j] = sum_c We[k][h*16+c] * X[c][j] ----------------
// X is a 16x16 matrix (Wk3 or Wv3). out is 64x128.
__global__ __launch_bounds__(256) void wex_kernel(
    const float* __restrict__ We, const float* __restrict__ X, float* __restrict__ out)
{
    int idx = blockIdx.x * 256 + threadIdx.x;
    if (idx >= 64 * 128) return;
    int k = idx >> 7, hj = idx & 127, h = hj >> 4, j = hj & 15;
    float s = 0.f;
#pragma unroll
    for (int c = 0; c < 16; ++c) s += We[k * 128 + h * 16 + c] * X[c * 16 + j];
    out[idx] = s;
}

// ---------------- precompute per (d,h): c0 = Q·(K@Wk1 + bke); A2[c] = sum_j Wk2[c][j]*Q[j] ----------------
__global__ __launch_bounds__(256) void qk_pre_kernel(
    const float* __restrict__ Q, const float* __restrict__ K,
    const float* __restrict__ Wke, const float* __restrict__ bke,
    float* __restrict__ A2, float* __restrict__ c0)
{
    __shared__ float wk1[256], wk2[256], bks[16];
    for (int i = threadIdx.x; i < 256; i += 256) { wk1[i] = Wke[i]; wk2[i] = Wke[256 + i]; }
    if (threadIdx.x < 16) bks[threadIdx.x] = bke[threadIdx.x];
    __syncthreads();
    int idx = blockIdx.x * 256 + threadIdx.x;   // idx = ((d*8 + h)*16 + j)
    int j = idx & 15; int dh = idx >> 4; int h = dh & 7; int d = dh >> 3;
    if (d >= N_NODES) return;
    const float* q = Q + (size_t)d * HCDIM + h * CH;
    const float* k = K + (size_t)d * HCDIM + h * CH;
    float qv[16], kv[16];
#pragma unroll
    for (int t = 0; t < 4; ++t) {
        *(float4*)&qv[t * 4] = *(const float4*)(q + t * 4);
        *(float4*)&kv[t * 4] = *(const float4*)(k + t * 4);
    }
    float a2 = 0.f;
#pragma unroll
    for (int t = 0; t < 16; ++t) a2 += wk2[j * 16 + t] * qv[t];
    A2[idx] = a2;
    float kn = bks[j];
#pragma unroll
    for (int c = 0; c < 16; ++c) kn += kv[c] * wk1[c * 16 + j];
    float t = qv[j] * kn;
    t += __shfl_xor(t, 1); t += __shfl_xor(t, 2); t += __shfl_xor(t, 4); t += __shfl_xor(t, 8);
    if (j == 0) c0[dh] = t;
}

// ---------------- logits (chunked): logit = 0.25*(c0[d,h] + A2[d,h]·K[s,h] + Q[d,h]·eproj3[e,h]) ----------------
__global__ __launch_bounds__(256) void logits_kernel(
    const float* __restrict__ Q, const float* __restrict__ K,
    const float* __restrict__ A2, const float* __restrict__ c0,
    const float* __restrict__ ep3,
    const int* __restrict__ src, const int* __restrict__ dst,
    float* __restrict__ logits, int e0, int ecnt)
{
    int idx = blockIdx.x * 256 + threadIdx.x;
    if (idx >= ecnt * HEADS) return;
    int el = idx >> 3, h = idx & 7, e = e0 + el;
    int s = src[e], d = dst[e];
    const float* q  = Q  + (size_t)d * HCDIM + h * CH;
    const float* a2 = A2 + (size_t)d * HCDIM + h * CH;
    const float* ks = K  + (size_t)s * HCDIM + h * CH;
    const float* ep = ep3 + (size_t)el * HCDIM + h * CH;
    float acc = c0[(size_t)d * HEADS + h];
    float qv[16], av[16], kv[16], ev[16];
#pragma unroll
    for (int t = 0; t < 4; ++t) {
        *(float4*)&qv[t * 4] = *(const float4*)(q + t * 4);
        *(float4*)&av[t * 4] = *(const float4*)(a2 + t * 4);
        *(float4*)&kv[t * 4] = *(const float4*)(ks + t * 4);
        *(float4*)&ev[t * 4] = *(const float4*)(ep + t * 4);
    }
#pragma unroll
    for (int t = 0; t < 16; ++t) acc += av[t] * kv[t] + qv[t] * ev[t];
    logits[(size_t)e * HEADS + h] = acc * 0.25f;
}

// ---------------- CSR build ----------------
__global__ __launch_bounds__(256) void count_kernel(const int* __restrict__ dst, int* __restrict__ cnt) {
    int e = blockIdx.x * 256 + threadIdx.x;
    if (e < E_EDGES) atomicAdd(&cnt[dst[e]], 1);
}

__global__ __launch_bounds__(1024) void scan_kernel(
    const int* __restrict__ cnt, int* __restrict__ rowptr, int* __restrict__ cursor, int n)
{
    __shared__ int buf[1024];
    __shared__ int base;
    int tid = threadIdx.x;
    if (tid == 0) { base = 0; rowptr[0] = 0; }
    __syncthreads();
    for (int t0 = 0; t0 < n; t0 += 1024) {
        int i = t0 + tid;
        int v = (i < n) ? cnt[i] : 0;
        buf[tid] = v;
        __syncthreads();
        for (int off = 1; off < 1024; off <<= 1) {
            int add = (tid >= off) ? buf[tid - off] : 0;
            __syncthreads();
            buf[tid] += add;
            __syncthreads();
        }
        if (i < n) { rowptr[i + 1] = base + buf[tid]; cursor[i] = base + buf[tid] - v; }
        __syncthreads();
        if (tid == 0) base += buf[1023];
        __syncthreads();
    }
}

__global__ __launch_bounds__(256) void scatter_kernel(
    const int* __restrict__ dst, int* __restrict__ cursor, int* __restrict__ eidx) {
    int e = blockIdx.x * 256 + threadIdx.x;
    if (e < E_EDGES) {
        int p = atomicAdd(&cursor[dst[e]], 1);
        eidx[p] = e;
    }
}

// ---------------- per-node attention: softmax + gather-aggregate + Wv transforms ----------------
// one wave per node. logits -> alpha (in place). aggout[d] = full Vnew-weighted sum.
__global__ __launch_bounds__(256) void node_attn_kernel(
    const float* __restrict__ Vb, const float* __restrict__ edge_attr,
    float* __restrict__ logits,
    const int* __restrict__ rowptr, const int* __restrict__ eidx,
    const int* __restrict__ src,
    const float* __restrict__ Wve, const float* __restrict__ bve,
    const float* __restrict__ WeWv3, float* __restrict__ aggout)
{
    __shared__ float w3s[64 * 128];
    __shared__ float wv1s[256], wv2s[256], bvs[16];
    __shared__ float stage[NODE_WAVES][640];   // per wave: wea[8][64] then aggv[8][16]

    for (int i = threadIdx.x; i < 64 * 128; i += 256) w3s[i] = WeWv3[i];
    for (int i = threadIdx.x; i < 256; i += 256) { wv1s[i] = Wve[i]; wv2s[i] = Wve[256 + i]; }
    if (threadIdx.x < 16) bvs[threadIdx.x] = bve[threadIdx.x];
    __syncthreads();

    int w = threadIdx.x >> 6, lane = threadIdx.x & 63;
    int d = blockIdx.x * NODE_WAVES + w;
    int r0 = rowptr[d], r1 = rowptr[d + 1], deg = r1 - r0;
    int h = lane >> 3, kg = lane & 7;

    if (deg == 0) {
        aggout[(size_t)d * HCDIM + lane] = 0.f;
        aggout[(size_t)d * HCDIM + 64 + lane] = 0.f;
    } else {
        // softmax stats, all 8 heads per lane
        float m[8], ssum[8];
#pragma unroll
        for (int t = 0; t < 8; ++t) { m[t] = -INFINITY; ssum[t] = 0.f; }
        for (int i = r0 + lane; i < r1; i += 64) {
            int e = eidx[i];
            const float* lp = logits + (size_t)e * HEADS;
            float l[8];
            *(float4*)&l[0] = *(const float4*)lp;
            *(float4*)&l[4] = *(const float4*)(lp + 4);
#pragma unroll
            for (int t = 0; t < 8; ++t) m[t] = fmaxf(m[t], l[t]);
        }
#pragma unroll
        for (int o = 1; o < 64; o <<= 1) {
#pragma unroll
            for (int t = 0; t < 8; ++t) m[t] = fmaxf(m[t], __shfl_xor(m[t], o));
        }
        for (int i = r0 + lane; i < r1; i += 64) {
            int e = eidx[i];
            const float* lp = logits + (size_t)e * HEADS;
            float l[8];
            *(float4*)&l[0] = *(const float4*)lp;
            *(float4*)&l[4] = *(const float4*)(lp + 4);
#pragma unroll
            for (int t = 0; t < 8; ++t) ssum[t] += expf(l[t] - m[t]);
        }
#pragma unroll
        for (int o = 1; o < 64; o <<= 1) {
#pragma unroll
            for (int t = 0; t < 8; ++t) ssum[t] += __shfl_xor(ssum[t], o);
        }
        // select this lane's head stats (avoid dynamic register indexing)
        float mh = m[0], dd = ssum[0];
#pragma unroll
        for (int t = 1; t < 8; ++t) { if (h == t) { mh = m[t]; dd = ssum[t]; } }
        float den = dd + 1e-16f;

        // aggregation: all 64 lanes cooperate per edge
        float wea[8] = {0.f, 0.f, 0.f, 0.f, 0.f, 0.f, 0.f, 0.f};
        float av0 = 0.f, av1 = 0.f;
        for (int i = r0; i < r1; ++i) {
            int e = eidx[i];
            float lg = logits[(size_t)e * HEADS + h];
            float alpha = expf(lg - mh) / den;
            if (kg == 0) logits[(size_t)e * HEADS + h] = alpha;   // store alpha for e_out path
            int s = src[e];
            const float* ea = edge_attr + (size_t)e * EDIM + kg * 8;
            float ev[8];
            *(float4*)&ev[0] = *(const float4*)ea;
            *(float4*)&ev[4] = *(const float4*)(ea + 4);
#pragma unroll
            for (int t = 0; t < 8; ++t) wea[t] += alpha * ev[t];
            float2 vv = *(const float2*)(Vb + (size_t)s * HCDIM + h * CH + kg * 2);
            av0 += alpha * vv.x;
            av1 += alpha * vv.y;
        }
        float* st = stage[w];
#pragma unroll
        for (int t = 0; t < 8; ++t) st[h * 64 + kg * 8 + t] = wea[t];
        st[512 + h * 16 + kg * 2] = av0;
        st[512 + h * 16 + kg * 2 + 1] = av1;
    }
    __syncthreads();
    if (deg > 0) {
        float* st = stage[w];
        int c0i = kg * 2;
        float acc0 = bvs[c0i], acc1 = bvs[c0i + 1];
        const float* vd = Vb + (size_t)d * HCDIM + h * CH;
#pragma unroll
        for (int j = 0; j < 16; ++j) {
            float vj = vd[j];
            float a = st[512 + h * 16 + j];
            acc0 += vj * wv1s[j * 16 + c0i] + a * wv2s[j * 16 + c0i];
            acc1 += vj * wv1s[j * 16 + c0i + 1] + a * wv2s[j * 16 + c0i + 1];
        }
#pragma unroll
        for (int k = 0; k < 64; ++k) {
            float wv = st[h * 64 + k];
            acc0 += wv * w3s[k * 128 + h * 16 + c0i];
            acc1 += wv * w3s[k * 128 + h * 16 + c0i + 1];
        }
        aggout[(size_t)d * HCDIM + h * CH + c0i] = acc0;
        aggout[(size_t)d * HCDIM + h * CH + c0i + 1] = acc1;
    }
}

// ---------------- layernorm (+ residual), in-place, one wave per row ----------------
__global__ __launch_bounds__(256) void ln_res_kernel(
    float* __restrict__ y, const float* __restrict__ g, const float* __restrict__ b,
    const float* __restrict__ res, int rows, int w)
{
    int wave = threadIdx.x >> 6;
    int lane = threadIdx.x & 63;
    int nw = blockDim.x >> 6;
    for (int r = blockIdx.x * nw + wave; r < rows; r += gridDim.x * nw) {
        size_t base = (size_t)r * w;
        float v0 = y[base + lane];
        float v1 = (w == 128) ? y[base + 64 + lane] : 0.f;
        float s = v0 + v1;
#pragma unroll
        for (int o = 32; o; o >>= 1) s += __shfl_xor(s, o);
        float m = s / (float)w;
        float d0 = v0 - m;
        float d1 = (w == 128) ? (v1 - m) : 0.f;
        float q = d0 * d0 + d1 * d1;
#pragma unroll
        for (int o = 32; o; o >>= 1) q += __shfl_xor(q, o);
        float inv = rsqrtf(q / (float)w + 1e-5f);
        y[base + lane] = d0 * inv * g[lane] + b[lane] + res[base + lane];
        if (w == 128)
            y[base + 64 + lane] = d1 * inv * g[64 + lane] + b[64 + lane] + res[base + 64 + lane];
    }
}

// ---------------- batchnorm stats ----------------
__global__ __launch_bounds__(256) void bn_stats_kernel(
    const float* __restrict__ y, float* __restrict__ colsum, float* __restrict__ colsq,
    int rows, int cols)
{
    __shared__ float ss[256], sq[256];
    int tid = threadIdx.x;
    int col = tid % cols;
    int rsub = tid / cols;
    int rstep = blockDim.x / cols;
    float ls = 0.f, lq = 0.f;
    for (int r = blockIdx.x * rstep + rsub; r < rows; r += gridDim.x * rstep) {
        float v = y[(size_t)r * cols + col];
        ls += v;
        lq += v * v;
    }
    ss[tid] = ls;
    sq[tid] = lq;
    __syncthreads();
    if (tid < cols) {
        for (int o = cols; o < 256; o += cols) { ls += ss[tid + o]; lq += sq[tid + o]; }
        atomicAdd(&colsum[tid], ls);
        atomicAdd(&colsq[tid], lq);
    }
}

// ---------------- batchnorm apply + residual + softplus -> output ----------------
__global__ __launch_bounds__(256) void bn_apply_softplus_kernel(
    const float* __restrict__ y, const float* __restrict__ res,
    const float* __restrict__ colsum, const float* __restrict__ colsq,
    const float* __restrict__ g, const float* __restrict__ b,
    float* __restrict__ out, int rows, int cols)
{
    int idx = blockIdx.x * blockDim.x + threadIdx.x;
    int n = rows * cols;
    if (idx >= n) return;
    int c = idx % cols;
    float m = colsum[c] / (float)rows;
    float var = colsq[c] / (float)rows - m * m;
    float inv = rsqrtf(var + 1e-5f);
    float v = (y[idx] - m) * inv * g[c] + b[c] + res[idx];
    out[idx] = softplus_f(v);
}

// ---------------- launcher ----------------

extern "C" void kernel_launch(void* const* d_in, const int* in_sizes, int n_in,
                              void* d_out, int out_size, void* d_ws, size_t ws_size,
                              hipStream_t stream) {
    const float* x         = (const float*)d_in[0];
    const int*   ei        = (const int*)d_in[1];
    const float* edge_attr = (const float*)d_in[2];
    const float* Wq  = (const float*)d_in[3];
    const float* bq  = (const float*)d_in[4];
    const float* Wk  = (const float*)d_in[5];
    const float* bk  = (const float*)d_in[6];
    const float* Wv  = (const float*)d_in[7];
    const float* bv  = (const float*)d_in[8];
    const float* We  = (const float*)d_in[9];
    const float* Wke = (const float*)d_in[10];
    const float* bke = (const float*)d_in[11];
    const float* Wve = (const float*)d_in[12];
    const float* bve = (const float*)d_in[13];
    const float* Wfce = (const float*)d_in[14];
    const float* bfce = (const float*)d_in[15];
    const float* lne_g = (const float*)d_in[16];
    const float* lne_b = (const float*)d_in[17];
    const float* Wfcn = (const float*)d_in[18];
    const float* bfcn = (const float*)d_in[19];
    const float* lnn_g = (const float*)d_in[20];
    const float* lnn_b = (const float*)d_in[21];
    const float* W1n = (const float*)d_in[22];
    const float* b1n = (const float*)d_in[23];
    const float* W2n = (const float*)d_in[24];
    const float* b2n = (const float*)d_in[25];
    const float* W1e = (const float*)d_in[26];
    const float* b1e = (const float*)d_in[27];
    const float* W2e = (const float*)d_in[28];
    const float* b2e = (const float*)d_in[29];
    const float* bnn_g = (const float*)d_in[30];
    const float* bnn_b = (const float*)d_in[31];
    const float* bne_g = (const float*)d_in[32];
    const float* bne_b = (const float*)d_in[33];

    const int* src = ei;
    const int* dst = ei + E_EDGES;

    float* ws = (float*)d_ws;
    const size_t M64   = (size_t)E_EDGES * EDIM;       // 25.6M
    const size_t NODE2 = (size_t)N_NODES * HCDIM;      // 6.4M

    // regionR [0, 25.6M): phase A = Qb|Kb|Vb|eproj_c; phase B = h_n; phase C = h_e
    float* regionR = ws;
    float* Qb  = regionR;
    float* Kb  = regionR + NODE2;
    float* Vb  = regionR + 2 * NODE2;
    float* eproj_c = regionR + 3 * NODE2;              // chunk buffer (ECHUNK x 128)
    float* h_n = regionR;                              // 25.6M (N x 512)
    float* h_e = regionR;                              // 25.6M (FCHUNK x 256)

    // overlayY [25.6M, 51.2M): logits|c0|csr|aggout|y_n|x_out; phase C = y_e
    float* overlayY = ws + M64;
    float* logits = overlayY;                                  // 3.2M (holds alpha later)
    float* c0buf  = logits + (size_t)E_EDGES * HEADS;          // 0.4M
    int*   cnt_i    = (int*)(c0buf + (size_t)N_NODES * HEADS); // 50000
    int*   rowptr_i = cnt_i + N_NODES;                         // 50001
    int*   cursor_i = rowptr_i + N_NODES + 1;                  // 50000
    int*   eidx_i   = cursor_i + N_NODES;                      // 400000
    float* aggout = (float*)(eidx_i + E_EDGES);                // 6.4M
    float* y_n    = aggout + NODE2;                            // 6.4M
    float* x_out  = y_n + NODE2;                               // 6.4M
    float* y_e    = overlayY;                                  // 25.6M (phase C)

    // e_out region [51.2M, 76.8M): A2 parks at its start (dead before e_out written)
    float* e_out = ws + 2 * M64;
    float* A2buf = e_out;                                      // 6.4M, dead after logits

    // tail [76.8M, +)
    float* tail = ws + 3 * M64;
    float* colsum_n = tail;            // 128
    float* colsq_n  = tail + 128;      // 128
    float* colsum_e = tail + 256;      // 64
    float* colsq_e  = tail + 320;      // 64
    float* WeK3  = tail + 384;         // 8192
    float* WeWv3 = WeK3 + 8192;        // 8192

    dim3 blk(256);

    // ---- init ----
    fill_kernel<<<dim3(2), blk, 0, stream>>>(colsum_n, 0.f, 384);
    fill_kernel<<<dim3((N_NODES + 255) / 256), blk, 0, stream>>>((float*)cnt_i, 0.f, N_NODES); // int 0 bits

    // ---- precompute folded weights ----
    wex_kernel<<<dim3(32), blk, 0, stream>>>(We, Wke + 2 * CH * CH, WeK3);
    wex_kernel<<<dim3(32), blk, 0, stream>>>(We, Wve + 2 * CH * CH, WeWv3);

    // ---- QKV projections ----
    launch_gemm(x, Wq, bq, nullptr, Qb, N_NODES, DIM, HCDIM, 0, stream);
    launch_gemm(x, Wk, bk, nullptr, Kb, N_NODES, DIM, HCDIM, 0, stream);
    launch_gemm(x, Wv, bv, nullptr, Vb, N_NODES, DIM, HCDIM, 0, stream);

    // ---- per-node QK precompute ----
    qk_pre_kernel<<<dim3(N_NODES * HCDIM / 256), blk, 0, stream>>>(Qb, Kb, Wke, bke, A2buf, c0buf);

    // ---- CSR build ----
    count_kernel<<<dim3((E_EDGES + 255) / 256), blk, 0, stream>>>(dst, cnt_i);
    scan_kernel<<<dim3(1), dim3(1024), 0, stream>>>(cnt_i, rowptr_i, cursor_i, N_NODES);
    scatter_kernel<<<dim3((E_EDGES + 255) / 256), blk, 0, stream>>>(dst, cursor_i, eidx_i);

    // ---- logits per edge chunk (eproj3 = edge_attr @ WeK3) ----
    for (int e0 = 0; e0 < E_EDGES; e0 += ECHUNK) {
        launch_gemm(edge_attr + (size_t)e0 * EDIM, WeK3, nullptr, nullptr, eproj_c, ECHUNK, EDIM, HCDIM, 0, stream);
        logits_kernel<<<dim3((ECHUNK * HEADS + 255) / 256), blk, 0, stream>>>(
            Qb, Kb, A2buf, c0buf, eproj_c, src, dst, logits, e0, ECHUNK);
    }

    // ---- per-node softmax + aggregation (no atomics); logits -> alpha ----
    node_attn_kernel<<<dim3(N_NODES / NODE_WAVES), blk, 0, stream>>>(
        Vb, edge_attr, logits, rowptr_i, eidx_i, src, Wve, bve, WeWv3, aggout);

    // ---- e_out = LN((alpha ⊙ eproj) @ Wfce + bfce) + edge_attr ----
    for (int e0 = 0; e0 < E_EDGES; e0 += ECHUNK) {
        launch_gemm(edge_attr + (size_t)e0 * EDIM, We, nullptr, nullptr, eproj_c, ECHUNK, EDIM, HCDIM, 0, stream);
        launch_gemm(eproj_c, Wfce, bfce, logits + (size_t)e0 * HEADS,
                    e_out + (size_t)e0 * EDIM, ECHUNK, HCDIM, EDIM, 0, stream);
    }
    ln_res_kernel<<<dim3(25000), blk, 0, stream>>>(e_out, lne_g, lne_b, edge_attr, E_EDGES, EDIM);

    // ---- node output path ----
    launch_gemm(aggout, Wfcn, bfcn, nullptr, x_out, N_NODES, HCDIM, DIM, 0, stream);
    ln_res_kernel<<<dim3(12500), blk, 0, stream>>>(x_out, lnn_g, lnn_b, x, N_NODES, DIM);

    // ---- node FFN + BN + residual + softplus (h_n overlays regionR) ----
    launch_gemm(x_out, W1n, b1n, nullptr, h_n, N_NODES, DIM, 4 * DIM, 1, stream);
    launch_gemm(h_n, W2n, b2n, nullptr, y_n, N_NODES, 4 * DIM, DIM, 0, stream);
    bn_stats_kernel<<<dim3(256), blk, 0, stream>>>(y_n, colsum_n, colsq_n, N_NODES, DIM);
    {
        int n = N_NODES * DIM;
        bn_apply_softplus_kernel<<<dim3((n + 255) / 256), blk, 0, stream>>>(
            y_n, x_out, colsum_n, colsq_n, bnn_g, bnn_b, (float*)d_out, N_NODES, DIM);
    }

    // ---- edge FFN (chunked; h_e overlays regionR, y_e overlays overlayY) ----
    for (int f0 = 0; f0 < E_EDGES; f0 += FCHUNK) {
        launch_gemm(e_out + (size_t)f0 * EDIM, W1e, b1e, nullptr, h_e, FCHUNK, EDIM, 4 * EDIM, 1, stream);
        launch_gemm(h_e, W2e, b2e, nullptr, y_e + (size_t)f0 * EDIM, FCHUNK, 4 * EDIM, EDIM, 0, stream);
    }
    bn_stats_kernel<<<dim3(256), blk, 0, stream>>>(y_e, colsum_e, colsq_e, E_EDGES, EDIM);
    {
        int n = E_EDGES * EDIM;
        bn_apply_softplus_kernel<<<dim3((n + 255) / 256), blk, 0, stream>>>(
            y_e, e_out, colsum_e, colsq_e, bne_g, bne_b, (float*)d_out + (size_t)N_NODES * DIM, E_EDGES, EDIM);
    }
}

// Round 2
// 2592.854 us; speedup vs baseline: 1.0217x; 1.0142x over previous
//
#include <hip/hip_runtime.h>
#include <math.h>
#include <stdint.h>

#define N_NODES 50000
#define E_EDGES 400000
#define DIM 128
#define HEADS 8
#define CH 16
#define EDIM 64
#define HCDIM 128   // HEADS*CH

#define EPCHUNK 100000   // edge chunk for eproj/logits and e_out loops (4 chunks)
#define FCHUNK 100000    // edge chunk for FFN (4 chunks)
#define NODE_WAVES 4

using bf16x8 = __attribute__((ext_vector_type(8))) short;
using f32x4v = __attribute__((ext_vector_type(4))) float;

// ---------------- utility ----------------

__global__ void fill_kernel(float* p, float v, int n) {
    int i = blockIdx.x * blockDim.x + threadIdx.x;
    if (i < n) p[i] = v;
}

__global__ void concat3_kernel(const float* __restrict__ a, const float* __restrict__ b,
                               const float* __restrict__ c, float* __restrict__ o) {
    int i = blockIdx.x * 256 + threadIdx.x;
    if (i < 128) o[i] = a[i];
    else if (i < 256) o[i] = b[i - 128];
    else if (i < 384) o[i] = c[i - 256];
}

__device__ inline float gelu_f(float x) {
    return 0.5f * x * (1.0f + erff(x * 0.70710678118654752f));
}

__device__ inline float softplus_f(float x) {
    return x > 20.f ? x : log1pf(expf(x));
}

__device__ inline unsigned short f32_to_bf16_rn(float f) {
    unsigned u = __float_as_uint(f);
    u += 0x7FFFu + ((u >> 16) & 1u);
    return (unsigned short)(u >> 16);
}
__device__ inline float bf16_to_f32(unsigned short h) {
    return __uint_as_float((unsigned)h << 16);
}

// ---------------- weight pre-transpose + bf16 split ----------------
// in: W (KxN f32, row-major). out: hi/lo bf16 planes, [n][k] layout.
__global__ __launch_bounds__(256) void wsplit_kernel(
    const float* __restrict__ W, unsigned short* __restrict__ hi,
    unsigned short* __restrict__ lo, int K, int N)
{
    int idx = blockIdx.x * 256 + threadIdx.x;
    if (idx >= K * N) return;
    int n = idx / K, k = idx - n * K;
    float x = W[(size_t)k * N + n];
    unsigned short h = f32_to_bf16_rn(x);
    hi[idx] = h;
    lo[idx] = f32_to_bf16_rn(x - bf16_to_f32(h));
}

// ---------------- MFMA GEMM: C = act(scale(A)(MxK) @ W(KxN) + bias) ----------------
// split-bf16 x3 emulation of fp32. BM=128, BN in {64,128}, BK=32, 256 threads (4 waves).
// BN=128: waves 2x2, per-wave 4x4 16x16 tiles. BN=64: waves 4x1 (32 rows), 2x4 tiles.
// A staged through LDS in [plane][granule][row] bf16x8 form (conflict-free b128).
// B fragments loaded directly from pre-split weights (Whi/Wlo, [n][k], L2-resident).
// ascale: per-row per-16-col scale on A. cmode 1 = QKV split-output (col>>7 selects buffer).
template<int BN>
__global__ __launch_bounds__(256) void gemm_mfma(
    const float* __restrict__ A,
    const unsigned short* __restrict__ Whi, const unsigned short* __restrict__ Wlo,
    const float* __restrict__ bias, const float* __restrict__ ascale,
    float* __restrict__ C, int M, int K, int Nc, int act, int cmode)
{
    constexpr int MT = (BN == 128) ? 4 : 2;
    __shared__ bf16x8 As[2][4][128];   // [plane hi/lo][k-granule][row], 16 KB

    const int tid = threadIdx.x;
    const int w = tid >> 6, lane = tid & 63;
    const int l15 = lane & 15, lg = lane >> 4;
    const int m0 = blockIdx.y * 128;
    const int n0 = blockIdx.x * BN;
    const int rowbase = (BN == 128) ? (w >> 1) * 64 : w * 32;
    const int colbase = (BN == 128) ? (w & 1) * 64 : 0;
    const int k16 = K >> 4;

    f32x4v acc[MT][4];
#pragma unroll
    for (int i = 0; i < MT; ++i)
#pragma unroll
        for (int j = 0; j < 4; ++j)
#pragma unroll
            for (int cidx = 0; cidx < 4; ++cidx) acc[i][j][cidx] = 0.f;

    for (int k0 = 0; k0 < K; k0 += 32) {
        // ---- stage A: each thread converts 2 granules (8 f32 -> bf16 hi/lo) ----
#pragma unroll
        for (int it = 0; it < 2; ++it) {
            int row = w * 16 + l15 + it * 64;
            int ar = m0 + row;
            float v[8];
            if (ar < M) {
                const float* ap = A + (size_t)ar * K + k0 + lg * 8;
                *(float4*)&v[0] = *(const float4*)ap;
                *(float4*)&v[4] = *(const float4*)(ap + 4);
                if (ascale) {
                    float s = ascale[(size_t)ar * k16 + ((k0 >> 4) + (lg >> 1))];
#pragma unroll
                    for (int j = 0; j < 8; ++j) v[j] *= s;
                }
            } else {
#pragma unroll
                for (int j = 0; j < 8; ++j) v[j] = 0.f;
            }
            bf16x8 gh, gl;
#pragma unroll
            for (int j = 0; j < 8; ++j) {
                unsigned short h = f32_to_bf16_rn(v[j]);
                gh[j] = (short)h;
                gl[j] = (short)f32_to_bf16_rn(v[j] - bf16_to_f32(h));
            }
            As[0][lg][row] = gh;
            As[1][lg][row] = gl;
        }
        // ---- B fragments straight from global (L2-resident pre-split weights) ----
        bf16x8 bh[4], bl[4];
#pragma unroll
        for (int nt = 0; nt < 4; ++nt) {
            size_t off = (size_t)(n0 + colbase + nt * 16 + l15) * K + k0 + lg * 8;
            bh[nt] = *(const bf16x8*)(Whi + off);
            bl[nt] = *(const bf16x8*)(Wlo + off);
        }
        __syncthreads();
        // ---- MFMA: hi*hi + lo*hi + hi*lo ----
#pragma unroll
        for (int mt = 0; mt < MT; ++mt) {
            int arow = rowbase + mt * 16 + l15;
            bf16x8 ah = As[0][lg][arow];
            bf16x8 al = As[1][lg][arow];
#pragma unroll
            for (int nt = 0; nt < 4; ++nt) {
                acc[mt][nt] = __builtin_amdgcn_mfma_f32_16x16x32_bf16(ah, bh[nt], acc[mt][nt], 0, 0, 0);
                acc[mt][nt] = __builtin_amdgcn_mfma_f32_16x16x32_bf16(al, bh[nt], acc[mt][nt], 0, 0, 0);
                acc[mt][nt] = __builtin_amdgcn_mfma_f32_16x16x32_bf16(ah, bl[nt], acc[mt][nt], 0, 0, 0);
            }
        }
        __syncthreads();
    }

    // ---- epilogue: D frag layout col=lane&15, row=(lane>>4)*4+reg ----
#pragma unroll
    for (int nt = 0; nt < 4; ++nt) {
        int col = n0 + colbase + nt * 16 + l15;
        float bb = bias ? bias[col] : 0.f;
#pragma unroll
        for (int mt = 0; mt < MT; ++mt) {
#pragma unroll
            for (int i = 0; i < 4; ++i) {
                int r = m0 + rowbase + mt * 16 + lg * 4 + i;
                if (r < M) {
                    float o = acc[mt][nt][i] + bb;
                    if (act == 1) o = gelu_f(o);
                    if (cmode == 1) {
                        C[(size_t)(col >> 7) * ((size_t)N_NODES * HCDIM) + (size_t)r * HCDIM + (col & 127)] = o;
                    } else {
                        C[(size_t)r * Nc + col] = o;
                    }
                }
            }
        }
    }
}

static inline void launch_mfma(const float* A, const unsigned short* Whi, const unsigned short* Wlo,
                               const float* bias, const float* ascale, float* C,
                               int M, int K, int Nc, int act, int cmode, hipStream_t stream)
{
    int gy = (M + 127) / 128;
    if (Nc % 128 == 0)
        gemm_mfma<128><<<dim3(Nc / 128, gy), dim3(256), 0, stream>>>(A, Whi, Wlo, bias, ascale, C, M, K, Nc, act, cmode);
    else
        gemm_mfma<64><<<dim3(Nc / 64, gy), dim3(256), 0, stream>>>(A, Whi, Wlo, bias, ascale, C, M, K, Nc, act, cmode);
}

// ---------------- precompute: WeX[k][h*16+j] = sum_c We[k][h*16+c] * X[c][j] ----------------
__global__ __launch_bounds__(256) void wex_kernel(
    const float* __restrict__ We, const float* __restrict__ X, float* __restrict__ out)
{
    int idx = blockIdx.x * 256 + threadIdx.x;
    if (idx >= 64 * 128) return;
    int k = idx >> 7, hj = idx & 127, h = hj >> 4, j = hj & 15;
    float s = 0.f;
#pragma unroll
    for (int c = 0; c < 16; ++c) s += We[k * 128 + h * 16 + c] * X[c * 16 + j];
    out[idx] = s;
}

// ---------------- precompute per (d,h): c0 = Q·(K@Wk1 + bke); A2[c] = sum_j Wk2[c][j]*Q[j] ----------------
__global__ __launch_bounds__(256) void qk_pre_kernel(
    const float* __restrict__ Q, const float* __restrict__ K,
    const float* __restrict__ Wke, const float* __restrict__ bke,
    float* __restrict__ A2, float* __restrict__ c0)
{
    __shared__ float wk1[256], wk2[256], bks[16];
    for (int i = threadIdx.x; i < 256; i += 256) { wk1[i] = Wke[i]; wk2[i] = Wke[256 + i]; }
    if (threadIdx.x < 16) bks[threadIdx.x] = bke[threadIdx.x];
    __syncthreads();
    int idx = blockIdx.x * 256 + threadIdx.x;   // idx = ((d*8 + h)*16 + j)
    int j = idx & 15; int dh = idx >> 4; int h = dh & 7; int d = dh >> 3;
    if (d >= N_NODES) return;
    const float* q = Q + (size_t)d * HCDIM + h * CH;
    const float* k = K + (size_t)d * HCDIM + h * CH;
    float qv[16], kv[16];
#pragma unroll
    for (int t = 0; t < 4; ++t) {
        *(float4*)&qv[t * 4] = *(const float4*)(q + t * 4);
        *(float4*)&kv[t * 4] = *(const float4*)(k + t * 4);
    }
    float a2 = 0.f;
#pragma unroll
    for (int t = 0; t < 16; ++t) a2 += wk2[j * 16 + t] * qv[t];
    A2[idx] = a2;
    float kn = bks[j];
#pragma unroll
    for (int c = 0; c < 16; ++c) kn += kv[c] * wk1[c * 16 + j];
    float t = qv[j] * kn;
    t += __shfl_xor(t, 1); t += __shfl_xor(t, 2); t += __shfl_xor(t, 4); t += __shfl_xor(t, 8);
    if (j == 0) c0[dh] = t;
}

// ---------------- logits (chunked) ----------------
__global__ __launch_bounds__(256) void logits_kernel(
    const float* __restrict__ Q, const float* __restrict__ K,
    const float* __restrict__ A2, const float* __restrict__ c0,
    const float* __restrict__ ep3,
    const int* __restrict__ src, const int* __restrict__ dst,
    float* __restrict__ logits, int e0, int ecnt)
{
    int idx = blockIdx.x * 256 + threadIdx.x;
    if (idx >= ecnt * HEADS) return;
    int el = idx >> 3, h = idx & 7, e = e0 + el;
    int s = src[e], d = dst[e];
    const float* q  = Q  + (size_t)d * HCDIM + h * CH;
    const float* a2 = A2 + (size_t)d * HCDIM + h * CH;
    const float* ks = K  + (size_t)s * HCDIM + h * CH;
    const float* ep = ep3 + (size_t)el * HCDIM + h * CH;
    float acc = c0[(size_t)d * HEADS + h];
    float qv[16], av[16], kv[16], ev[16];
#pragma unroll
    for (int t = 0; t < 4; ++t) {
        *(float4*)&qv[t * 4] = *(const float4*)(q + t * 4);
        *(float4*)&av[t * 4] = *(const float4*)(a2 + t * 4);
        *(float4*)&kv[t * 4] = *(const float4*)(ks + t * 4);
        *(float4*)&ev[t * 4] = *(const float4*)(ep + t * 4);
    }
#pragma unroll
    for (int t = 0; t < 16; ++t) acc += av[t] * kv[t] + qv[t] * ev[t];
    logits[(size_t)e * HEADS + h] = acc * 0.25f;
}

// ---------------- CSR build ----------------
__global__ __launch_bounds__(256) void count_kernel(const int* __restrict__ dst, int* __restrict__ cnt) {
    int e = blockIdx.x * 256 + threadIdx.x;
    if (e < E_EDGES) atomicAdd(&cnt[dst[e]], 1);
}

__global__ __launch_bounds__(1024) void scan_kernel(
    const int* __restrict__ cnt, int* __restrict__ rowptr, int* __restrict__ cursor, int n)
{
    __shared__ int buf[1024];
    __shared__ int base;
    int tid = threadIdx.x;
    if (tid == 0) { base = 0; rowptr[0] = 0; }
    __syncthreads();
    for (int t0 = 0; t0 < n; t0 += 1024) {
        int i = t0 + tid;
        int v = (i < n) ? cnt[i] : 0;
        buf[tid] = v;
        __syncthreads();
        for (int off = 1; off < 1024; off <<= 1) {
            int add = (tid >= off) ? buf[tid - off] : 0;
            __syncthreads();
            buf[tid] += add;
            __syncthreads();
        }
        if (i < n) { rowptr[i + 1] = base + buf[tid]; cursor[i] = base + buf[tid] - v; }
        __syncthreads();
        if (tid == 0) base += buf[1023];
        __syncthreads();
    }
}

__global__ __launch_bounds__(256) void scatter_kernel(
    const int* __restrict__ dst, int* __restrict__ cursor, int* __restrict__ eidx) {
    int e = blockIdx.x * 256 + threadIdx.x;
    if (e < E_EDGES) {
        int p = atomicAdd(&cursor[dst[e]], 1);
        eidx[p] = e;
    }
}

// ---------------- per-node attention ----------------
__global__ __launch_bounds__(256) void node_attn_kernel(
    const float* __restrict__ Vb, const float* __restrict__ edge_attr,
    float* __restrict__ logits,
    const int* __restrict__ rowptr, const int* __restrict__ eidx,
    const int* __restrict__ src,
    const float* __restrict__ Wve, const float* __restrict__ bve,
    const float* __restrict__ WeWv3, float* __restrict__ aggout)
{
    __shared__ float w3s[64 * 128];
    __shared__ float wv1s[256], wv2s[256], bvs[16];
    __shared__ float stage[NODE_WAVES][640];

    for (int i = threadIdx.x; i < 64 * 128; i += 256) w3s[i] = WeWv3[i];
    for (int i = threadIdx.x; i < 256; i += 256) { wv1s[i] = Wve[i]; wv2s[i] = Wve[256 + i]; }
    if (threadIdx.x < 16) bvs[threadIdx.x] = bve[threadIdx.x];
    __syncthreads();

    int w = threadIdx.x >> 6, lane = threadIdx.x & 63;
    int d = blockIdx.x * NODE_WAVES + w;
    int r0 = rowptr[d], r1 = rowptr[d + 1], deg = r1 - r0;
    int h = lane >> 3, kg = lane & 7;

    if (deg == 0) {
        aggout[(size_t)d * HCDIM + lane] = 0.f;
        aggout[(size_t)d * HCDIM + 64 + lane] = 0.f;
    } else {
        float m[8], ssum[8];
#pragma unroll
        for (int t = 0; t < 8; ++t) { m[t] = -INFINITY; ssum[t] = 0.f; }
        for (int i = r0 + lane; i < r1; i += 64) {
            int e = eidx[i];
            const float* lp = logits + (size_t)e * HEADS;
            float l[8];
            *(float4*)&l[0] = *(const float4*)lp;
            *(float4*)&l[4] = *(const float4*)(lp + 4);
#pragma unroll
            for (int t = 0; t < 8; ++t) m[t] = fmaxf(m[t], l[t]);
        }
#pragma unroll
        for (int o = 1; o < 64; o <<= 1) {
#pragma unroll
            for (int t = 0; t < 8; ++t) m[t] = fmaxf(m[t], __shfl_xor(m[t], o));
        }
        for (int i = r0 + lane; i < r1; i += 64) {
            int e = eidx[i];
            const float* lp = logits + (size_t)e * HEADS;
            float l[8];
            *(float4*)&l[0] = *(const float4*)lp;
            *(float4*)&l[4] = *(const float4*)(lp + 4);
#pragma unroll
            for (int t = 0; t < 8; ++t) ssum[t] += expf(l[t] - m[t]);
        }
#pragma unroll
        for (int o = 1; o < 64; o <<= 1) {
#pragma unroll
            for (int t = 0; t < 8; ++t) ssum[t] += __shfl_xor(ssum[t], o);
        }
        float mh = m[0], dd = ssum[0];
#pragma unroll
        for (int t = 1; t < 8; ++t) { if (h == t) { mh = m[t]; dd = ssum[t]; } }
        float den = dd + 1e-16f;

        float wea[8] = {0.f, 0.f, 0.f, 0.f, 0.f, 0.f, 0.f, 0.f};
        float av0 = 0.f, av1 = 0.f;
        for (int i = r0; i < r1; ++i) {
            int e = eidx[i];
            float lg = logits[(size_t)e * HEADS + h];
            float alpha = expf(lg - mh) / den;
            if (kg == 0) logits[(size_t)e * HEADS + h] = alpha;
            int s = src[e];
            const float* ea = edge_attr + (size_t)e * EDIM + kg * 8;
            float ev[8];
            *(float4*)&ev[0] = *(const float4*)ea;
            *(float4*)&ev[4] = *(const float4*)(ea + 4);
#pragma unroll
            for (int t = 0; t < 8; ++t) wea[t] += alpha * ev[t];
            float2 vv = *(const float2*)(Vb + (size_t)s * HCDIM + h * CH + kg * 2);
            av0 += alpha * vv.x;
            av1 += alpha * vv.y;
        }
        float* st = stage[w];
#pragma unroll
        for (int t = 0; t < 8; ++t) st[h * 64 + kg * 8 + t] = wea[t];
        st[512 + h * 16 + kg * 2] = av0;
        st[512 + h * 16 + kg * 2 + 1] = av1;
    }
    __syncthreads();
    if (deg > 0) {
        float* st = stage[w];
        int c0i = kg * 2;
        float acc0 = bvs[c0i], acc1 = bvs[c0i + 1];
        const float* vd = Vb + (size_t)d * HCDIM + h * CH;
#pragma unroll
        for (int j = 0; j < 16; ++j) {
            float vj = vd[j];
            float a = st[512 + h * 16 + j];
            acc0 += vj * wv1s[j * 16 + c0i] + a * wv2s[j * 16 + c0i];
            acc1 += vj * wv1s[j * 16 + c0i + 1] + a * wv2s[j * 16 + c0i + 1];
        }
#pragma unroll
        for (int k = 0; k < 64; ++k) {
            float wv = st[h * 64 + k];
            acc0 += wv * w3s[k * 128 + h * 16 + c0i];
            acc1 += wv * w3s[k * 128 + h * 16 + c0i + 1];
        }
        aggout[(size_t)d * HCDIM + h * CH + c0i] = acc0;
        aggout[(size_t)d * HCDIM + h * CH + c0i + 1] = acc1;
    }
}

// ---------------- layernorm (+ residual) ----------------
__global__ __launch_bounds__(256) void ln_res_kernel(
    float* __restrict__ y, const float* __restrict__ g, const float* __restrict__ b,
    const float* __restrict__ res, int rows, int w)
{
    int wave = threadIdx.x >> 6;
    int lane = threadIdx.x & 63;
    int nw = blockDim.x >> 6;
    for (int r = blockIdx.x * nw + wave; r < rows; r += gridDim.x * nw) {
        size_t base = (size_t)r * w;
        float v0 = y[base + lane];
        float v1 = (w == 128) ? y[base + 64 + lane] : 0.f;
        float s = v0 + v1;
#pragma unroll
        for (int o = 32; o; o >>= 1) s += __shfl_xor(s, o);
        float m = s / (float)w;
        float d0 = v0 - m;
        float d1 = (w == 128) ? (v1 - m) : 0.f;
        float q = d0 * d0 + d1 * d1;
#pragma unroll
        for (int o = 32; o; o >>= 1) q += __shfl_xor(q, o);
        float inv = rsqrtf(q / (float)w + 1e-5f);
        y[base + lane] = d0 * inv * g[lane] + b[lane] + res[base + lane];
        if (w == 128)
            y[base + 64 + lane] = d1 * inv * g[64 + lane] + b[64 + lane] + res[base + 64 + lane];
    }
}

// ---------------- batchnorm stats ----------------
__global__ __launch_bounds__(256) void bn_stats_kernel(
    const float* __restrict__ y, float* __restrict__ colsum, float* __restrict__ colsq,
    int rows, int cols)
{
    __shared__ float ss[256], sq[256];
    int tid = threadIdx.x;
    int col = tid % cols;
    int rsub = tid / cols;
    int rstep = blockDim.x / cols;
    float ls = 0.f, lq = 0.f;
    for (int r = blockIdx.x * rstep + rsub; r < rows; r += gridDim.x * rstep) {
        float v = y[(size_t)r * cols + col];
        ls += v;
        lq += v * v;
    }
    ss[tid] = ls;
    sq[tid] = lq;
    __syncthreads();
    if (tid < cols) {
        for (int o = cols; o < 256; o += cols) { ls += ss[tid + o]; lq += sq[tid + o]; }
        atomicAdd(&colsum[tid], ls);
        atomicAdd(&colsq[tid], lq);
    }
}

// ---------------- batchnorm apply + residual + softplus ----------------
__global__ __launch_bounds__(256) void bn_apply_softplus_kernel(
    const float* __restrict__ y, const float* __restrict__ res,
    const float* __restrict__ colsum, const float* __restrict__ colsq,
    const float* __restrict__ g, const float* __restrict__ b,
    float* __restrict__ out, int rows, int cols)
{
    int idx = blockIdx.x * blockDim.x + threadIdx.x;
    int n = rows * cols;
    if (idx >= n) return;
    int c = idx % cols;
    float m = colsum[c] / (float)rows;
    float var = colsq[c] / (float)rows - m * m;
    float inv = rsqrtf(var + 1e-5f);
    float v = (y[idx] - m) * inv * g[c] + b[c] + res[idx];
    out[idx] = softplus_f(v);
}

// ---------------- launcher ----------------

extern "C" void kernel_launch(void* const* d_in, const int* in_sizes, int n_in,
                              void* d_out, int out_size, void* d_ws, size_t ws_size,
                              hipStream_t stream) {
    const float* x         = (const float*)d_in[0];
    const int*   ei        = (const int*)d_in[1];
    const float* edge_attr = (const float*)d_in[2];
    const float* Wq  = (const float*)d_in[3];
    const float* bq  = (const float*)d_in[4];
    const float* Wk  = (const float*)d_in[5];
    const float* bk  = (const float*)d_in[6];
    const float* Wv  = (const float*)d_in[7];
    const float* bv  = (const float*)d_in[8];
    const float* We  = (const float*)d_in[9];
    const float* Wke = (const float*)d_in[10];
    const float* bke = (const float*)d_in[11];
    const float* Wve = (const float*)d_in[12];
    const float* bve = (const float*)d_in[13];
    const float* Wfce = (const float*)d_in[14];
    const float* bfce = (const float*)d_in[15];
    const float* lne_g = (const float*)d_in[16];
    const float* lne_b = (const float*)d_in[17];
    const float* Wfcn = (const float*)d_in[18];
    const float* bfcn = (const float*)d_in[19];
    const float* lnn_g = (const float*)d_in[20];
    const float* lnn_b = (const float*)d_in[21];
    const float* W1n = (const float*)d_in[22];
    const float* b1n = (const float*)d_in[23];
    const float* W2n = (const float*)d_in[24];
    const float* b2n = (const float*)d_in[25];
    const float* W1e = (const float*)d_in[26];
    const float* b1e = (const float*)d_in[27];
    const float* W2e = (const float*)d_in[28];
    const float* b2e = (const float*)d_in[29];
    const float* bnn_g = (const float*)d_in[30];
    const float* bnn_b = (const float*)d_in[31];
    const float* bne_g = (const float*)d_in[32];
    const float* bne_b = (const float*)d_in[33];

    const int* src = ei;
    const int* dst = ei + E_EDGES;

    float* ws = (float*)d_ws;
    const size_t M64   = (size_t)E_EDGES * EDIM;       // 25.6M
    const size_t NODE2 = (size_t)N_NODES * HCDIM;      // 6.4M

    // regionR [0, 25.6M): phase A = Qb|Kb|Vb; phase B = h_n; phase C = h_e
    float* regionR = ws;
    float* Qb  = regionR;
    float* Kb  = regionR + NODE2;
    float* Vb  = regionR + 2 * NODE2;
    float* h_n = regionR;                              // 25.6M (N x 512)
    float* h_e = regionR;                              // 25.6M (FCHUNK x 256)

    // overlayY [25.6M, 51.2M): logits|c0|csr|aggout|y_n|x_out; phase C = y_e
    float* overlayY = ws + M64;
    float* logits = overlayY;                                  // 3.2M (holds alpha later)
    float* c0buf  = logits + (size_t)E_EDGES * HEADS;          // 0.4M
    int*   cnt_i    = (int*)(c0buf + (size_t)N_NODES * HEADS); // 50000
    int*   rowptr_i = cnt_i + N_NODES;                         // 50001
    int*   cursor_i = rowptr_i + N_NODES + 1;                  // 50000
    int*   eidx_i   = cursor_i + N_NODES;                      // 400000
    float* aggout = (float*)(((uintptr_t)(eidx_i + E_EDGES) + 15) & ~(uintptr_t)15); // 6.4M, 16B-aligned
    float* y_n    = aggout + NODE2;                            // 6.4M
    float* x_out  = y_n + NODE2;                               // 6.4M
    float* y_e    = overlayY;                                  // 25.6M (phase C)
    float* epbig  = y_n;       // 12.8M scratch (EPCHUNK x 128) while y_n/x_out are dead

    // e_out region [51.2M, 76.8M): A2 parks at its start (dead before e_out written)
    float* e_out = ws + 2 * M64;
    float* A2buf = e_out;                                      // 6.4M, dead after logits

    // tail [76.8M, +)
    float* tail = ws + 3 * M64;
    float* colsum_n = tail;            // 128
    float* colsq_n  = tail + 128;      // 128
    float* colsum_e = tail + 256;      // 64
    float* colsq_e  = tail + 320;      // 64
    float* WeK3  = tail + 384;         // 8192
    float* WeWv3 = WeK3 + 8192;        // 8192
    float* bqkv  = WeWv3 + 8192;       // 384

    // split-weight arena (bf16 hi/lo planes, [n][k] layout), ~1 MB
    unsigned short* wsp = (unsigned short*)(bqkv + 384);
    unsigned short* QKV_s  = wsp;                     // [384][128] hi then lo (49152 each)
    unsigned short* WeK3_s = QKV_s  + 2 * 49152;      // K=64,N=128
    unsigned short* We_s   = WeK3_s + 2 * 8192;       // K=64,N=128
    unsigned short* Wfce_s = We_s   + 2 * 8192;       // K=128,N=64
    unsigned short* Wfcn_s = Wfce_s + 2 * 8192;       // K=128,N=128
    unsigned short* W1n_s  = Wfcn_s + 2 * 16384;      // K=128,N=512
    unsigned short* W2n_s  = W1n_s  + 2 * 65536;      // K=512,N=128
    unsigned short* W1e_s  = W2n_s  + 2 * 65536;      // K=64,N=256
    unsigned short* W2e_s  = W1e_s  + 2 * 16384;      // K=256,N=64

    dim3 blk(256);

    // ---- init ----
    fill_kernel<<<dim3(2), blk, 0, stream>>>(colsum_n, 0.f, 384);
    fill_kernel<<<dim3((N_NODES + 255) / 256), blk, 0, stream>>>((float*)cnt_i, 0.f, N_NODES);

    // ---- folded weights ----
    wex_kernel<<<dim3(32), blk, 0, stream>>>(We, Wke + 2 * CH * CH, WeK3);
    wex_kernel<<<dim3(32), blk, 0, stream>>>(We, Wve + 2 * CH * CH, WeWv3);

    // ---- weight transpose + bf16 split ----
    wsplit_kernel<<<dim3(64), blk, 0, stream>>>(Wq, QKV_s,          QKV_s + 49152,          128, 128);
    wsplit_kernel<<<dim3(64), blk, 0, stream>>>(Wk, QKV_s + 16384,  QKV_s + 49152 + 16384,  128, 128);
    wsplit_kernel<<<dim3(64), blk, 0, stream>>>(Wv, QKV_s + 32768,  QKV_s + 49152 + 32768,  128, 128);
    wsplit_kernel<<<dim3(32), blk, 0, stream>>>(WeK3, WeK3_s, WeK3_s + 8192,  64, 128);
    wsplit_kernel<<<dim3(32), blk, 0, stream>>>(We,   We_s,   We_s + 8192,    64, 128);
    wsplit_kernel<<<dim3(32), blk, 0, stream>>>(Wfce, Wfce_s, Wfce_s + 8192,  128, 64);
    wsplit_kernel<<<dim3(64), blk, 0, stream>>>(Wfcn, Wfcn_s, Wfcn_s + 16384, 128, 128);
    wsplit_kernel<<<dim3(256), blk, 0, stream>>>(W1n, W1n_s, W1n_s + 65536,   128, 512);
    wsplit_kernel<<<dim3(256), blk, 0, stream>>>(W2n, W2n_s, W2n_s + 65536,   512, 128);
    wsplit_kernel<<<dim3(64), blk, 0, stream>>>(W1e, W1e_s, W1e_s + 16384,    64, 256);
    wsplit_kernel<<<dim3(64), blk, 0, stream>>>(W2e, W2e_s, W2e_s + 16384,    256, 64);
    concat3_kernel<<<dim3(2), blk, 0, stream>>>(bq, bk, bv, bqkv);

    // ---- QKV projection (merged, N=384, split-output) ----
    launch_mfma(x, QKV_s, QKV_s + 49152, bqkv, nullptr, Qb, N_NODES, 128, 384, 0, 1, stream);

    // ---- per-node QK precompute ----
    qk_pre_kernel<<<dim3(N_NODES * HCDIM / 256), blk, 0, stream>>>(Qb, Kb, Wke, bke, A2buf, c0buf);

    // ---- CSR build ----
    count_kernel<<<dim3((E_EDGES + 255) / 256), blk, 0, stream>>>(dst, cnt_i);
    scan_kernel<<<dim3(1), dim3(1024), 0, stream>>>(cnt_i, rowptr_i, cursor_i, N_NODES);
    scatter_kernel<<<dim3((E_EDGES + 255) / 256), blk, 0, stream>>>(dst, cursor_i, eidx_i);

    // ---- logits per edge chunk (eproj3 = edge_attr @ WeK3) ----
    for (int e0 = 0; e0 < E_EDGES; e0 += EPCHUNK) {
        launch_mfma(edge_attr + (size_t)e0 * EDIM, WeK3_s, WeK3_s + 8192, nullptr, nullptr,
                    epbig, EPCHUNK, EDIM, HCDIM, 0, 0, stream);
        logits_kernel<<<dim3((EPCHUNK * HEADS + 255) / 256), blk, 0, stream>>>(
            Qb, Kb, A2buf, c0buf, epbig, src, dst, logits, e0, EPCHUNK);
    }

    // ---- per-node softmax + aggregation; logits -> alpha ----
    node_attn_kernel<<<dim3(N_NODES / NODE_WAVES), blk, 0, stream>>>(
        Vb, edge_attr, logits, rowptr_i, eidx_i, src, Wve, bve, WeWv3, aggout);

    // ---- e_out = LN((alpha ⊙ eproj) @ Wfce + bfce) + edge_attr ----
    for (int e0 = 0; e0 < E_EDGES; e0 += EPCHUNK) {
        launch_mfma(edge_attr + (size_t)e0 * EDIM, We_s, We_s + 8192, nullptr, nullptr,
                    epbig, EPCHUNK, EDIM, HCDIM, 0, 0, stream);
        launch_mfma(epbig, Wfce_s, Wfce_s + 8192, bfce, logits + (size_t)e0 * HEADS,
                    e_out + (size_t)e0 * EDIM, EPCHUNK, HCDIM, EDIM, 0, 0, stream);
    }
    ln_res_kernel<<<dim3(25000), blk, 0, stream>>>(e_out, lne_g, lne_b, edge_attr, E_EDGES, EDIM);

    // ---- node output path ----
    launch_mfma(aggout, Wfcn_s, Wfcn_s + 16384, bfcn, nullptr, x_out, N_NODES, HCDIM, DIM, 0, 0, stream);
    ln_res_kernel<<<dim3(12500), blk, 0, stream>>>(x_out, lnn_g, lnn_b, x, N_NODES, DIM);

    // ---- node FFN + BN + residual + softplus ----
    launch_mfma(x_out, W1n_s, W1n_s + 65536, b1n, nullptr, h_n, N_NODES, DIM, 4 * DIM, 1, 0, stream);
    launch_mfma(h_n, W2n_s, W2n_s + 65536, b2n, nullptr, y_n, N_NODES, 4 * DIM, DIM, 0, 0, stream);
    bn_stats_kernel<<<dim3(256), blk, 0, stream>>>(y_n, colsum_n, colsq_n, N_NODES, DIM);
    {
        int n = N_NODES * DIM;
        bn_apply_softplus_kernel<<<dim3((n + 255) / 256), blk, 0, stream>>>(
            y_n, x_out, colsum_n, colsq_n, bnn_g, bnn_b, (float*)d_out, N_NODES, DIM);
    }

    // ---- edge FFN (chunked) ----
    for (int f0 = 0; f0 < E_EDGES; f0 += FCHUNK) {
        launch_mfma(e_out + (size_t)f0 * EDIM, W1e_s, W1e_s + 16384, b1e, nullptr,
                    h_e, FCHUNK, EDIM, 4 * EDIM, 1, 0, stream);
        launch_mfma(h_e, W2e_s, W2e_s + 16384, b2e, nullptr,
                    y_e + (size_t)f0 * EDIM, FCHUNK, 4 * EDIM, EDIM, 0, 0, stream);
    }
    bn_stats_kernel<<<dim3(256), blk, 0, stream>>>(y_e, colsum_e, colsq_e, E_EDGES, EDIM);
    {
        int n = E_EDGES * EDIM;
        bn_apply_softplus_kernel<<<dim3((n + 255) / 256), blk, 0, stream>>>(
            y_e, e_out, colsum_e, colsq_e, bne_g, bne_b, (float*)d_out + (size_t)N_NODES * DIM, E_EDGES, EDIM);
    }
}

// Round 3
// 2376.902 us; speedup vs baseline: 1.1145x; 1.0909x over previous
//
#include <hip/hip_runtime.h>
#include <math.h>
#include <stdint.h>

#define N_NODES 50000
#define E_EDGES 400000
#define DIM 128
#define HEADS 8
#define CH 16
#define EDIM 64
#define HCDIM 128   // HEADS*CH

#define EPCHUNK 100000   // edge chunk for eproj/logits loop (4 chunks)
#define NODE_WAVES 4

using bf16x8 = __attribute__((ext_vector_type(8))) short;
using f32x4v = __attribute__((ext_vector_type(4))) float;

// ---------------- utility ----------------

__global__ void fill_kernel(float* p, float v, int n) {
    int i = blockIdx.x * blockDim.x + threadIdx.x;
    if (i < n) p[i] = v;
}

__global__ void concat3_kernel(const float* __restrict__ a, const float* __restrict__ b,
                               const float* __restrict__ c, float* __restrict__ o) {
    int i = blockIdx.x * 256 + threadIdx.x;
    if (i < 128) o[i] = a[i];
    else if (i < 256) o[i] = b[i - 128];
    else if (i < 384) o[i] = c[i - 256];
}

__device__ inline float gelu_f(float x) {
    return 0.5f * x * (1.0f + erff(x * 0.70710678118654752f));
}

__device__ inline float softplus_f(float x) {
    return x > 20.f ? x : log1pf(expf(x));
}

__device__ inline unsigned short f32_to_bf16_rn(float f) {
    unsigned u = __float_as_uint(f);
    u += 0x7FFFu + ((u >> 16) & 1u);
    return (unsigned short)(u >> 16);
}
__device__ inline float bf16_to_f32(unsigned short h) {
    return __uint_as_float((unsigned)h << 16);
}

// ---------------- weight pre-transpose + bf16 split ----------------
// in: W (KxN f32, row-major). out: hi/lo bf16 planes, [n][k] layout.
__global__ __launch_bounds__(256) void wsplit_kernel(
    const float* __restrict__ W, unsigned short* __restrict__ hi,
    unsigned short* __restrict__ lo, int K, int N)
{
    int idx = blockIdx.x * 256 + threadIdx.x;
    if (idx >= K * N) return;
    int n = idx / K, k = idx - n * K;
    float x = W[(size_t)k * N + n];
    unsigned short h = f32_to_bf16_rn(x);
    hi[idx] = h;
    lo[idx] = f32_to_bf16_rn(x - bf16_to_f32(h));
}

// ---------------- MFMA GEMM (single): C = act(A @ W + bias) ----------------
template<int BN>
__global__ __launch_bounds__(256) void gemm_mfma(
    const float* __restrict__ A,
    const unsigned short* __restrict__ Whi, const unsigned short* __restrict__ Wlo,
    const float* __restrict__ bias, const float* __restrict__ ascale,
    float* __restrict__ C, int M, int K, int Nc, int act, int cmode)
{
    constexpr int MT = (BN == 128) ? 4 : 2;
    __shared__ bf16x8 As[2][4][128];   // [plane hi/lo][k-granule][row], 16 KB

    const int tid = threadIdx.x;
    const int w = tid >> 6, lane = tid & 63;
    const int l15 = lane & 15, lg = lane >> 4;
    const int m0 = blockIdx.y * 128;
    const int n0 = blockIdx.x * BN;
    const int rowbase = (BN == 128) ? (w >> 1) * 64 : w * 32;
    const int colbase = (BN == 128) ? (w & 1) * 64 : 0;
    const int k16 = K >> 4;

    f32x4v acc[MT][4];
#pragma unroll
    for (int i = 0; i < MT; ++i)
#pragma unroll
        for (int j = 0; j < 4; ++j)
#pragma unroll
            for (int cidx = 0; cidx < 4; ++cidx) acc[i][j][cidx] = 0.f;

    for (int k0 = 0; k0 < K; k0 += 32) {
#pragma unroll
        for (int it = 0; it < 2; ++it) {
            int row = w * 16 + l15 + it * 64;
            int ar = m0 + row;
            float v[8];
            if (ar < M) {
                const float* ap = A + (size_t)ar * K + k0 + lg * 8;
                *(float4*)&v[0] = *(const float4*)ap;
                *(float4*)&v[4] = *(const float4*)(ap + 4);
                if (ascale) {
                    float s = ascale[(size_t)ar * k16 + ((k0 >> 4) + (lg >> 1))];
#pragma unroll
                    for (int j = 0; j < 8; ++j) v[j] *= s;
                }
            } else {
#pragma unroll
                for (int j = 0; j < 8; ++j) v[j] = 0.f;
            }
            bf16x8 gh, gl;
#pragma unroll
            for (int j = 0; j < 8; ++j) {
                unsigned short h = f32_to_bf16_rn(v[j]);
                gh[j] = (short)h;
                gl[j] = (short)f32_to_bf16_rn(v[j] - bf16_to_f32(h));
            }
            As[0][lg][row] = gh;
            As[1][lg][row] = gl;
        }
        bf16x8 bh[4], bl[4];
#pragma unroll
        for (int nt = 0; nt < 4; ++nt) {
            size_t off = (size_t)(n0 + colbase + nt * 16 + l15) * K + k0 + lg * 8;
            bh[nt] = *(const bf16x8*)(Whi + off);
            bl[nt] = *(const bf16x8*)(Wlo + off);
        }
        __syncthreads();
#pragma unroll
        for (int mt = 0; mt < MT; ++mt) {
            int arow = rowbase + mt * 16 + l15;
            bf16x8 ah = As[0][lg][arow];
            bf16x8 al = As[1][lg][arow];
#pragma unroll
            for (int nt = 0; nt < 4; ++nt) {
                acc[mt][nt] = __builtin_amdgcn_mfma_f32_16x16x32_bf16(ah, bh[nt], acc[mt][nt], 0, 0, 0);
                acc[mt][nt] = __builtin_amdgcn_mfma_f32_16x16x32_bf16(al, bh[nt], acc[mt][nt], 0, 0, 0);
                acc[mt][nt] = __builtin_amdgcn_mfma_f32_16x16x32_bf16(ah, bl[nt], acc[mt][nt], 0, 0, 0);
            }
        }
        __syncthreads();
    }

#pragma unroll
    for (int nt = 0; nt < 4; ++nt) {
        int col = n0 + colbase + nt * 16 + l15;
        float bb = bias ? bias[col] : 0.f;
#pragma unroll
        for (int mt = 0; mt < MT; ++mt) {
#pragma unroll
            for (int i = 0; i < 4; ++i) {
                int r = m0 + rowbase + mt * 16 + lg * 4 + i;
                if (r < M) {
                    float o = acc[mt][nt][i] + bb;
                    if (act == 1) o = gelu_f(o);
                    if (cmode == 1) {
                        C[(size_t)(col >> 7) * ((size_t)N_NODES * HCDIM) + (size_t)r * HCDIM + (col & 127)] = o;
                    } else {
                        C[(size_t)r * Nc + col] = o;
                    }
                }
            }
        }
    }
}

static inline void launch_mfma(const float* A, const unsigned short* Whi, const unsigned short* Wlo,
                               const float* bias, const float* ascale, float* C,
                               int M, int K, int Nc, int act, int cmode, hipStream_t stream)
{
    int gy = (M + 127) / 128;
    if (Nc % 128 == 0)
        gemm_mfma<128><<<dim3(Nc / 128, gy), dim3(256), 0, stream>>>(A, Whi, Wlo, bias, ascale, C, M, K, Nc, act, cmode);
    else
        gemm_mfma<64><<<dim3(Nc / 64, gy), dim3(256), 0, stream>>>(A, Whi, Wlo, bias, ascale, C, M, K, Nc, act, cmode);
}

// ---------------- fused double GEMM: out = (act(A@W1 + b1) [* ascale]) @ W2 + b2 ----------------
// A: MxK1, W1: K1xNH (pre-split [n][k]), W2: NHxN2 (pre-split [n][k]).
// Hidden never touches global: computed per 64-col chunk in registers, staged via LDS.
// ASC: hidden col j scaled by ascale[row*(NH/16) + j/16] (per-row per-head alpha).
// BM=128: 4 waves x 32 rows; BM=64: 4 waves x 16 rows.
template<int BM, int K1, int NH, int N2, int ACT1, int ASC>
__global__ __launch_bounds__(256) void ffn2_fused(
    const float* __restrict__ A,
    const unsigned short* __restrict__ W1hi, const unsigned short* __restrict__ W1lo,
    const float* __restrict__ b1,
    const unsigned short* __restrict__ W2hi, const unsigned short* __restrict__ W2lo,
    const float* __restrict__ b2,
    const float* __restrict__ ascale,
    float* __restrict__ Cout, int M)
{
    constexpr int MT = BM / 64;        // 16-row tiles per wave
    constexpr int NT2 = N2 / 16;
    __shared__ bf16x8 As[2][K1 / 8][BM];          // split A, [plane][k-granule][row]
    __shared__ unsigned short Hs[2][BM][64];      // split hidden chunk, XOR-swizzled

    const int tid = threadIdx.x;
    const int w = tid >> 6, lane = tid & 63;
    const int l15 = lane & 15, lg = lane >> 4;
    const int m0 = blockIdx.x * BM;
    const int wr0 = w * (BM / 4);

    // ---- stage A once (bf16 hi/lo) ----
    for (int k0 = 0; k0 < K1; k0 += 32) {
#pragma unroll
        for (int it = 0; it < BM / 64; ++it) {
            int row = w * 16 + l15 + it * 64;
            int ar = m0 + row;
            float v[8];
            if (ar < M) {
                const float* ap = A + (size_t)ar * K1 + k0 + lg * 8;
                *(float4*)&v[0] = *(const float4*)ap;
                *(float4*)&v[4] = *(const float4*)(ap + 4);
            } else {
#pragma unroll
                for (int j = 0; j < 8; ++j) v[j] = 0.f;
            }
            bf16x8 gh, gl;
#pragma unroll
            for (int j = 0; j < 8; ++j) {
                unsigned short h = f32_to_bf16_rn(v[j]);
                gh[j] = (short)h;
                gl[j] = (short)f32_to_bf16_rn(v[j] - bf16_to_f32(h));
            }
            As[0][(k0 >> 3) + lg][row] = gh;
            As[1][(k0 >> 3) + lg][row] = gl;
        }
    }
    __syncthreads();

    f32x4v oacc[MT][NT2];
#pragma unroll
    for (int mt = 0; mt < MT; ++mt)
#pragma unroll
        for (int nt = 0; nt < NT2; ++nt)
#pragma unroll
            for (int cidx = 0; cidx < 4; ++cidx) oacc[mt][nt][cidx] = 0.f;

    for (int hc = 0; hc < NH; hc += 64) {
        // ---- GEMM1: hidden chunk (BM x 64) ----
        f32x4v acc1[MT][4];
#pragma unroll
        for (int mt = 0; mt < MT; ++mt)
#pragma unroll
            for (int nt = 0; nt < 4; ++nt)
#pragma unroll
                for (int cidx = 0; cidx < 4; ++cidx) acc1[mt][nt][cidx] = 0.f;

        for (int k0 = 0; k0 < K1; k0 += 32) {
            bf16x8 bh[4], bl[4];
#pragma unroll
            for (int nt = 0; nt < 4; ++nt) {
                size_t off = (size_t)(hc + nt * 16 + l15) * K1 + k0 + lg * 8;
                bh[nt] = *(const bf16x8*)(W1hi + off);
                bl[nt] = *(const bf16x8*)(W1lo + off);
            }
#pragma unroll
            for (int mt = 0; mt < MT; ++mt) {
                bf16x8 ah = As[0][(k0 >> 3) + lg][wr0 + mt * 16 + l15];
                bf16x8 al = As[1][(k0 >> 3) + lg][wr0 + mt * 16 + l15];
#pragma unroll
                for (int nt = 0; nt < 4; ++nt) {
                    acc1[mt][nt] = __builtin_amdgcn_mfma_f32_16x16x32_bf16(ah, bh[nt], acc1[mt][nt], 0, 0, 0);
                    acc1[mt][nt] = __builtin_amdgcn_mfma_f32_16x16x32_bf16(al, bh[nt], acc1[mt][nt], 0, 0, 0);
                    acc1[mt][nt] = __builtin_amdgcn_mfma_f32_16x16x32_bf16(ah, bl[nt], acc1[mt][nt], 0, 0, 0);
                }
            }
        }

        __syncthreads();   // prior chunk's Hs readers done
        // ---- bias/act/scale + split + stage hidden ----
#pragma unroll
        for (int nt = 0; nt < 4; ++nt) {
            float b1v = b1 ? b1[hc + nt * 16 + l15] : 0.f;
#pragma unroll
            for (int mt = 0; mt < MT; ++mt) {
#pragma unroll
                for (int i = 0; i < 4; ++i) {
                    int row = wr0 + mt * 16 + lg * 4 + i;
                    float o = acc1[mt][nt][i] + b1v;
                    if (ACT1) o = gelu_f(o);
                    if (ASC) {
                        int r = m0 + row;
                        float s = (r < M) ? ascale[(size_t)r * (NH >> 4) + (hc >> 4) + nt] : 0.f;
                        o *= s;
                    }
                    unsigned short hh = f32_to_bf16_rn(o);
                    unsigned short hl = f32_to_bf16_rn(o - bf16_to_f32(hh));
                    int slot = (nt * 16 + l15) ^ ((row & 7) << 3);
                    Hs[0][row][slot] = hh;
                    Hs[1][row][slot] = hl;
                }
            }
        }
        __syncthreads();

        // ---- GEMM2: accumulate out += h_chunk @ W2[hc:hc+64, :] ----
#pragma unroll
        for (int k2 = 0; k2 < 64; k2 += 32) {
            bf16x8 b2h[NT2], b2l[NT2];
#pragma unroll
            for (int nt = 0; nt < NT2; ++nt) {
                size_t off = (size_t)(nt * 16 + l15) * NH + hc + k2 + lg * 8;
                b2h[nt] = *(const bf16x8*)(W2hi + off);
                b2l[nt] = *(const bf16x8*)(W2lo + off);
            }
#pragma unroll
            for (int mt = 0; mt < MT; ++mt) {
                int row = wr0 + mt * 16 + l15;
                int slot = (k2 + lg * 8) ^ ((row & 7) << 3);
                bf16x8 ah = *(const bf16x8*)&Hs[0][row][slot];
                bf16x8 al = *(const bf16x8*)&Hs[1][row][slot];
#pragma unroll
                for (int nt = 0; nt < NT2; ++nt) {
                    oacc[mt][nt] = __builtin_amdgcn_mfma_f32_16x16x32_bf16(ah, b2h[nt], oacc[mt][nt], 0, 0, 0);
                    oacc[mt][nt] = __builtin_amdgcn_mfma_f32_16x16x32_bf16(al, b2h[nt], oacc[mt][nt], 0, 0, 0);
                    oacc[mt][nt] = __builtin_amdgcn_mfma_f32_16x16x32_bf16(ah, b2l[nt], oacc[mt][nt], 0, 0, 0);
                }
            }
        }
    }

    // ---- epilogue ----
#pragma unroll
    for (int nt = 0; nt < NT2; ++nt) {
        int col = nt * 16 + l15;
        float bb = b2 ? b2[col] : 0.f;
#pragma unroll
        for (int mt = 0; mt < MT; ++mt) {
#pragma unroll
            for (int i = 0; i < 4; ++i) {
                int r = m0 + wr0 + mt * 16 + lg * 4 + i;
                if (r < M) Cout[(size_t)r * N2 + col] = oacc[mt][nt][i] + bb;
            }
        }
    }
}

// ---------------- precompute: WeX[k][h*16+j] = sum_c We[k][h*16+c] * X[c][j] ----------------
__global__ __launch_bounds__(256) void wex_kernel(
    const float* __restrict__ We, const float* __restrict__ X, float* __restrict__ out)
{
    int idx = blockIdx.x * 256 + threadIdx.x;
    if (idx >= 64 * 128) return;
    int k = idx >> 7, hj = idx & 127, h = hj >> 4, j = hj & 15;
    float s = 0.f;
#pragma unroll
    for (int c = 0; c < 16; ++c) s += We[k * 128 + h * 16 + c] * X[c * 16 + j];
    out[idx] = s;
}

// ---------------- precompute per (d,h): c0 = Q·(K@Wk1 + bke); A2[c] = sum_j Wk2[c][j]*Q[j] ----------------
__global__ __launch_bounds__(256) void qk_pre_kernel(
    const float* __restrict__ Q, const float* __restrict__ K,
    const float* __restrict__ Wke, const float* __restrict__ bke,
    float* __restrict__ A2, float* __restrict__ c0)
{
    __shared__ float wk1[256], wk2[256], bks[16];
    for (int i = threadIdx.x; i < 256; i += 256) { wk1[i] = Wke[i]; wk2[i] = Wke[256 + i]; }
    if (threadIdx.x < 16) bks[threadIdx.x] = bke[threadIdx.x];
    __syncthreads();
    int idx = blockIdx.x * 256 + threadIdx.x;   // idx = ((d*8 + h)*16 + j)
    int j = idx & 15; int dh = idx >> 4; int h = dh & 7; int d = dh >> 3;
    if (d >= N_NODES) return;
    const float* q = Q + (size_t)d * HCDIM + h * CH;
    const float* k = K + (size_t)d * HCDIM + h * CH;
    float qv[16], kv[16];
#pragma unroll
    for (int t = 0; t < 4; ++t) {
        *(float4*)&qv[t * 4] = *(const float4*)(q + t * 4);
        *(float4*)&kv[t * 4] = *(const float4*)(k + t * 4);
    }
    float a2 = 0.f;
#pragma unroll
    for (int t = 0; t < 16; ++t) a2 += wk2[j * 16 + t] * qv[t];
    A2[idx] = a2;
    float kn = bks[j];
#pragma unroll
    for (int c = 0; c < 16; ++c) kn += kv[c] * wk1[c * 16 + j];
    float t = qv[j] * kn;
    t += __shfl_xor(t, 1); t += __shfl_xor(t, 2); t += __shfl_xor(t, 4); t += __shfl_xor(t, 8);
    if (j == 0) c0[dh] = t;
}

// ---------------- logits (chunked) ----------------
__global__ __launch_bounds__(256) void logits_kernel(
    const float* __restrict__ Q, const float* __restrict__ K,
    const float* __restrict__ A2, const float* __restrict__ c0,
    const float* __restrict__ ep3,
    const int* __restrict__ src, const int* __restrict__ dst,
    float* __restrict__ logits, int e0, int ecnt)
{
    int idx = blockIdx.x * 256 + threadIdx.x;
    if (idx >= ecnt * HEADS) return;
    int el = idx >> 3, h = idx & 7, e = e0 + el;
    int s = src[e], d = dst[e];
    const float* q  = Q  + (size_t)d * HCDIM + h * CH;
    const float* a2 = A2 + (size_t)d * HCDIM + h * CH;
    const float* ks = K  + (size_t)s * HCDIM + h * CH;
    const float* ep = ep3 + (size_t)el * HCDIM + h * CH;
    float acc = c0[(size_t)d * HEADS + h];
    float qv[16], av[16], kv[16], ev[16];
#pragma unroll
    for (int t = 0; t < 4; ++t) {
        *(float4*)&qv[t * 4] = *(const float4*)(q + t * 4);
        *(float4*)&av[t * 4] = *(const float4*)(a2 + t * 4);
        *(float4*)&kv[t * 4] = *(const float4*)(ks + t * 4);
        *(float4*)&ev[t * 4] = *(const float4*)(ep + t * 4);
    }
#pragma unroll
    for (int t = 0; t < 16; ++t) acc += av[t] * kv[t] + qv[t] * ev[t];
    logits[(size_t)e * HEADS + h] = acc * 0.25f;
}

// ---------------- CSR build ----------------
__global__ __launch_bounds__(256) void count_kernel(const int* __restrict__ dst, int* __restrict__ cnt) {
    int e = blockIdx.x * 256 + threadIdx.x;
    if (e < E_EDGES) atomicAdd(&cnt[dst[e]], 1);
}

__global__ __launch_bounds__(1024) void scan_kernel(
    const int* __restrict__ cnt, int* __restrict__ rowptr, int* __restrict__ cursor, int n)
{
    __shared__ int buf[1024];
    __shared__ int base;
    int tid = threadIdx.x;
    if (tid == 0) { base = 0; rowptr[0] = 0; }
    __syncthreads();
    for (int t0 = 0; t0 < n; t0 += 1024) {
        int i = t0 + tid;
        int v = (i < n) ? cnt[i] : 0;
        buf[tid] = v;
        __syncthreads();
        for (int off = 1; off < 1024; off <<= 1) {
            int add = (tid >= off) ? buf[tid - off] : 0;
            __syncthreads();
            buf[tid] += add;
            __syncthreads();
        }
        if (i < n) { rowptr[i + 1] = base + buf[tid]; cursor[i] = base + buf[tid] - v; }
        __syncthreads();
        if (tid == 0) base += buf[1023];
        __syncthreads();
    }
}

__global__ __launch_bounds__(256) void scatter_kernel(
    const int* __restrict__ dst, int* __restrict__ cursor, int* __restrict__ eidx) {
    int e = blockIdx.x * 256 + threadIdx.x;
    if (e < E_EDGES) {
        int p = atomicAdd(&cursor[dst[e]], 1);
        eidx[p] = e;
    }
}

// ---------------- per-node attention ----------------
__global__ __launch_bounds__(256) void node_attn_kernel(
    const float* __restrict__ Vb, const float* __restrict__ edge_attr,
    float* __restrict__ logits,
    const int* __restrict__ rowptr, const int* __restrict__ eidx,
    const int* __restrict__ src,
    const float* __restrict__ Wve, const float* __restrict__ bve,
    const float* __restrict__ WeWv3, float* __restrict__ aggout)
{
    __shared__ float w3s[64 * 128];
    __shared__ float wv1s[256], wv2s[256], bvs[16];
    __shared__ float stage[NODE_WAVES][640];

    for (int i = threadIdx.x; i < 64 * 128; i += 256) w3s[i] = WeWv3[i];
    for (int i = threadIdx.x; i < 256; i += 256) { wv1s[i] = Wve[i]; wv2s[i] = Wve[256 + i]; }
    if (threadIdx.x < 16) bvs[threadIdx.x] = bve[threadIdx.x];
    __syncthreads();

    int w = threadIdx.x >> 6, lane = threadIdx.x & 63;
    int d = blockIdx.x * NODE_WAVES + w;
    int r0 = rowptr[d], r1 = rowptr[d + 1], deg = r1 - r0;
    int h = lane >> 3, kg = lane & 7;

    if (deg == 0) {
        aggout[(size_t)d * HCDIM + lane] = 0.f;
        aggout[(size_t)d * HCDIM + 64 + lane] = 0.f;
    } else {
        float m[8], ssum[8];
#pragma unroll
        for (int t = 0; t < 8; ++t) { m[t] = -INFINITY; ssum[t] = 0.f; }
        for (int i = r0 + lane; i < r1; i += 64) {
            int e = eidx[i];
            const float* lp = logits + (size_t)e * HEADS;
            float l[8];
            *(float4*)&l[0] = *(const float4*)lp;
            *(float4*)&l[4] = *(const float4*)(lp + 4);
#pragma unroll
            for (int t = 0; t < 8; ++t) m[t] = fmaxf(m[t], l[t]);
        }
#pragma unroll
        for (int o = 1; o < 64; o <<= 1) {
#pragma unroll
            for (int t = 0; t < 8; ++t) m[t] = fmaxf(m[t], __shfl_xor(m[t], o));
        }
        for (int i = r0 + lane; i < r1; i += 64) {
            int e = eidx[i];
            const float* lp = logits + (size_t)e * HEADS;
            float l[8];
            *(float4*)&l[0] = *(const float4*)lp;
            *(float4*)&l[4] = *(const float4*)(lp + 4);
#pragma unroll
            for (int t = 0; t < 8; ++t) ssum[t] += expf(l[t] - m[t]);
        }
#pragma unroll
        for (int o = 1; o < 64; o <<= 1) {
#pragma unroll
            for (int t = 0; t < 8; ++t) ssum[t] += __shfl_xor(ssum[t], o);
        }
        float mh = m[0], dd = ssum[0];
#pragma unroll
        for (int t = 1; t < 8; ++t) { if (h == t) { mh = m[t]; dd = ssum[t]; } }
        float den = dd + 1e-16f;

        float wea[8] = {0.f, 0.f, 0.f, 0.f, 0.f, 0.f, 0.f, 0.f};
        float av0 = 0.f, av1 = 0.f;
        for (int i = r0; i < r1; ++i) {
            int e = eidx[i];
            float lg = logits[(size_t)e * HEADS + h];
            float alpha = expf(lg - mh) / den;
            if (kg == 0) logits[(size_t)e * HEADS + h] = alpha;
            int s = src[e];
            const float* ea = edge_attr + (size_t)e * EDIM + kg * 8;
            float ev[8];
            *(float4*)&ev[0] = *(const float4*)ea;
            *(float4*)&ev[4] = *(const float4*)(ea + 4);
#pragma unroll
            for (int t = 0; t < 8; ++t) wea[t] += alpha * ev[t];
            float2 vv = *(const float2*)(Vb + (size_t)s * HCDIM + h * CH + kg * 2);
            av0 += alpha * vv.x;
            av1 += alpha * vv.y;
        }
        float* st = stage[w];
#pragma unroll
        for (int t = 0; t < 8; ++t) st[h * 64 + kg * 8 + t] = wea[t];
        st[512 + h * 16 + kg * 2] = av0;
        st[512 + h * 16 + kg * 2 + 1] = av1;
    }
    __syncthreads();
    if (deg > 0) {
        float* st = stage[w];
        int c0i = kg * 2;
        float acc0 = bvs[c0i], acc1 = bvs[c0i + 1];
        const float* vd = Vb + (size_t)d * HCDIM + h * CH;
#pragma unroll
        for (int j = 0; j < 16; ++j) {
            float vj = vd[j];
            float a = st[512 + h * 16 + j];
            acc0 += vj * wv1s[j * 16 + c0i] + a * wv2s[j * 16 + c0i];
            acc1 += vj * wv1s[j * 16 + c0i + 1] + a * wv2s[j * 16 + c0i + 1];
        }
#pragma unroll
        for (int k = 0; k < 64; ++k) {
            float wv = st[h * 64 + k];
            acc0 += wv * w3s[k * 128 + h * 16 + c0i];
            acc1 += wv * w3s[k * 128 + h * 16 + c0i + 1];
        }
        aggout[(size_t)d * HCDIM + h * CH + c0i] = acc0;
        aggout[(size_t)d * HCDIM + h * CH + c0i + 1] = acc1;
    }
}

// ---------------- layernorm (+ residual) ----------------
__global__ __launch_bounds__(256) void ln_res_kernel(
    float* __restrict__ y, const float* __restrict__ g, const float* __restrict__ b,
    const float* __restrict__ res, int rows, int w)
{
    int wave = threadIdx.x >> 6;
    int lane = threadIdx.x & 63;
    int nw = blockDim.x >> 6;
    for (int r = blockIdx.x * nw + wave; r < rows; r += gridDim.x * nw) {
        size_t base = (size_t)r * w;
        float v0 = y[base + lane];
        float v1 = (w == 128) ? y[base + 64 + lane] : 0.f;
        float s = v0 + v1;
#pragma unroll
        for (int o = 32; o; o >>= 1) s += __shfl_xor(s, o);
        float m = s / (float)w;
        float d0 = v0 - m;
        float d1 = (w == 128) ? (v1 - m) : 0.f;
        float q = d0 * d0 + d1 * d1;
#pragma unroll
        for (int o = 32; o; o >>= 1) q += __shfl_xor(q, o);
        float inv = rsqrtf(q / (float)w + 1e-5f);
        y[base + lane] = d0 * inv * g[lane] + b[lane] + res[base + lane];
        if (w == 128)
            y[base + 64 + lane] = d1 * inv * g[64 + lane] + b[64 + lane] + res[base + 64 + lane];
    }
}

// ---------------- batchnorm stats ----------------
__global__ __launch_bounds__(256) void bn_stats_kernel(
    const float* __restrict__ y, float* __restrict__ colsum, float* __restrict__ colsq,
    int rows, int cols)
{
    __shared__ float ss[256], sq[256];
    int tid = threadIdx.x;
    int col = tid % cols;
    int rsub = tid / cols;
    int rstep = blockDim.x / cols;
    float ls = 0.f, lq = 0.f;
    for (int r = blockIdx.x * rstep + rsub; r < rows; r += gridDim.x * rstep) {
        float v = y[(size_t)r * cols + col];
        ls += v;
        lq += v * v;
    }
    ss[tid] = ls;
    sq[tid] = lq;
    __syncthreads();
    if (tid < cols) {
        for (int o = cols; o < 256; o += cols) { ls += ss[tid + o]; lq += sq[tid + o]; }
        atomicAdd(&colsum[tid], ls);
        atomicAdd(&colsq[tid], lq);
    }
}

// ---------------- batchnorm apply + residual + softplus ----------------
__global__ __launch_bounds__(256) void bn_apply_softplus_kernel(
    const float* __restrict__ y, const float* __restrict__ res,
    const float* __restrict__ colsum, const float* __restrict__ colsq,
    const float* __restrict__ g, const float* __restrict__ b,
    float* __restrict__ out, int rows, int cols)
{
    int idx = blockIdx.x * blockDim.x + threadIdx.x;
    int n = rows * cols;
    if (idx >= n) return;
    int c = idx % cols;
    float m = colsum[c] / (float)rows;
    float var = colsq[c] / (float)rows - m * m;
    float inv = rsqrtf(var + 1e-5f);
    float v = (y[idx] - m) * inv * g[c] + b[c] + res[idx];
    out[idx] = softplus_f(v);
}

// ---------------- launcher ----------------

extern "C" void kernel_launch(void* const* d_in, const int* in_sizes, int n_in,
                              void* d_out, int out_size, void* d_ws, size_t ws_size,
                              hipStream_t stream) {
    const float* x         = (const float*)d_in[0];
    const int*   ei        = (const int*)d_in[1];
    const float* edge_attr = (const float*)d_in[2];
    const float* Wq  = (const float*)d_in[3];
    const float* bq  = (const float*)d_in[4];
    const float* Wk  = (const float*)d_in[5];
    const float* bk  = (const float*)d_in[6];
    const float* Wv  = (const float*)d_in[7];
    const float* bv  = (const float*)d_in[8];
    const float* We  = (const float*)d_in[9];
    const float* Wke = (const float*)d_in[10];
    const float* bke = (const float*)d_in[11];
    const float* Wve = (const float*)d_in[12];
    const float* bve = (const float*)d_in[13];
    const float* Wfce = (const float*)d_in[14];
    const float* bfce = (const float*)d_in[15];
    const float* lne_g = (const float*)d_in[16];
    const float* lne_b = (const float*)d_in[17];
    const float* Wfcn = (const float*)d_in[18];
    const float* bfcn = (const float*)d_in[19];
    const float* lnn_g = (const float*)d_in[20];
    const float* lnn_b = (const float*)d_in[21];
    const float* W1n = (const float*)d_in[22];
    const float* b1n = (const float*)d_in[23];
    const float* W2n = (const float*)d_in[24];
    const float* b2n = (const float*)d_in[25];
    const float* W1e = (const float*)d_in[26];
    const float* b1e = (const float*)d_in[27];
    const float* W2e = (const float*)d_in[28];
    const float* b2e = (const float*)d_in[29];
    const float* bnn_g = (const float*)d_in[30];
    const float* bnn_b = (const float*)d_in[31];
    const float* bne_g = (const float*)d_in[32];
    const float* bne_b = (const float*)d_in[33];

    const int* src = ei;
    const int* dst = ei + E_EDGES;

    float* ws = (float*)d_ws;
    const size_t M64   = (size_t)E_EDGES * EDIM;       // 25.6M
    const size_t NODE2 = (size_t)N_NODES * HCDIM;      // 6.4M

    // regionR [0, 25.6M): Qb|Kb|Vb
    float* regionR = ws;
    float* Qb  = regionR;
    float* Kb  = regionR + NODE2;
    float* Vb  = regionR + 2 * NODE2;

    // overlayY [25.6M, 51.2M): logits|c0|csr|aggout|y_n|x_out; later y_e
    float* overlayY = ws + M64;
    float* logits = overlayY;                                  // 3.2M (holds alpha later)
    float* c0buf  = logits + (size_t)E_EDGES * HEADS;          // 0.4M
    int*   cnt_i    = (int*)(c0buf + (size_t)N_NODES * HEADS); // 50000
    int*   rowptr_i = cnt_i + N_NODES;                         // 50001
    int*   cursor_i = rowptr_i + N_NODES + 1;                  // 50000
    int*   eidx_i   = cursor_i + N_NODES;                      // 400000
    float* aggout = (float*)(((uintptr_t)(eidx_i + E_EDGES) + 15) & ~(uintptr_t)15); // 6.4M
    float* y_n    = aggout + NODE2;                            // 6.4M
    float* x_out  = y_n + NODE2;                               // 6.4M
    float* y_e    = overlayY;                                  // 25.6M (late phase)
    float* epbig  = y_n;       // 12.8M scratch (EPCHUNK x 128) while y_n/x_out are dead

    // e_out region [51.2M, 76.8M): A2 parks at its start (dead before e_out written)
    float* e_out = ws + 2 * M64;
    float* A2buf = e_out;                                      // 6.4M, dead after logits

    // tail [76.8M, +)
    float* tail = ws + 3 * M64;
    float* colsum_n = tail;            // 128
    float* colsq_n  = tail + 128;      // 128
    float* colsum_e = tail + 256;      // 64
    float* colsq_e  = tail + 320;      // 64
    float* WeK3  = tail + 384;         // 8192
    float* WeWv3 = WeK3 + 8192;        // 8192
    float* bqkv  = WeWv3 + 8192;       // 384

    // split-weight arena (bf16 hi/lo planes, [n][k] layout), ~1 MB
    unsigned short* wsp = (unsigned short*)(bqkv + 384);
    unsigned short* QKV_s  = wsp;                     // [384][128] hi then lo (49152 each)
    unsigned short* WeK3_s = QKV_s  + 2 * 49152;      // K=64,N=128
    unsigned short* We_s   = WeK3_s + 2 * 8192;       // K=64,N=128
    unsigned short* Wfce_s = We_s   + 2 * 8192;       // K=128,N=64
    unsigned short* Wfcn_s = Wfce_s + 2 * 8192;       // K=128,N=128
    unsigned short* W1n_s  = Wfcn_s + 2 * 16384;      // K=128,N=512
    unsigned short* W2n_s  = W1n_s  + 2 * 65536;      // K=512,N=128
    unsigned short* W1e_s  = W2n_s  + 2 * 65536;      // K=64,N=256
    unsigned short* W2e_s  = W1e_s  + 2 * 16384;      // K=256,N=64

    dim3 blk(256);

    // ---- init ----
    fill_kernel<<<dim3(2), blk, 0, stream>>>(colsum_n, 0.f, 384);
    fill_kernel<<<dim3((N_NODES + 255) / 256), blk, 0, stream>>>((float*)cnt_i, 0.f, N_NODES);

    // ---- folded weights ----
    wex_kernel<<<dim3(32), blk, 0, stream>>>(We, Wke + 2 * CH * CH, WeK3);
    wex_kernel<<<dim3(32), blk, 0, stream>>>(We, Wve + 2 * CH * CH, WeWv3);

    // ---- weight transpose + bf16 split ----
    wsplit_kernel<<<dim3(64), blk, 0, stream>>>(Wq, QKV_s,          QKV_s + 49152,          128, 128);
    wsplit_kernel<<<dim3(64), blk, 0, stream>>>(Wk, QKV_s + 16384,  QKV_s + 49152 + 16384,  128, 128);
    wsplit_kernel<<<dim3(64), blk, 0, stream>>>(Wv, QKV_s + 32768,  QKV_s + 49152 + 32768,  128, 128);
    wsplit_kernel<<<dim3(32), blk, 0, stream>>>(WeK3, WeK3_s, WeK3_s + 8192,  64, 128);
    wsplit_kernel<<<dim3(32), blk, 0, stream>>>(We,   We_s,   We_s + 8192,    64, 128);
    wsplit_kernel<<<dim3(32), blk, 0, stream>>>(Wfce, Wfce_s, Wfce_s + 8192,  128, 64);
    wsplit_kernel<<<dim3(64), blk, 0, stream>>>(Wfcn, Wfcn_s, Wfcn_s + 16384, 128, 128);
    wsplit_kernel<<<dim3(256), blk, 0, stream>>>(W1n, W1n_s, W1n_s + 65536,   128, 512);
    wsplit_kernel<<<dim3(256), blk, 0, stream>>>(W2n, W2n_s, W2n_s + 65536,   512, 128);
    wsplit_kernel<<<dim3(64), blk, 0, stream>>>(W1e, W1e_s, W1e_s + 16384,    64, 256);
    wsplit_kernel<<<dim3(64), blk, 0, stream>>>(W2e, W2e_s, W2e_s + 16384,    256, 64);
    concat3_kernel<<<dim3(2), blk, 0, stream>>>(bq, bk, bv, bqkv);

    // ---- QKV projection (merged, N=384, split-output) ----
    launch_mfma(x, QKV_s, QKV_s + 49152, bqkv, nullptr, Qb, N_NODES, 128, 384, 0, 1, stream);

    // ---- per-node QK precompute ----
    qk_pre_kernel<<<dim3(N_NODES * HCDIM / 256), blk, 0, stream>>>(Qb, Kb, Wke, bke, A2buf, c0buf);

    // ---- CSR build ----
    count_kernel<<<dim3((E_EDGES + 255) / 256), blk, 0, stream>>>(dst, cnt_i);
    scan_kernel<<<dim3(1), dim3(1024), 0, stream>>>(cnt_i, rowptr_i, cursor_i, N_NODES);
    scatter_kernel<<<dim3((E_EDGES + 255) / 256), blk, 0, stream>>>(dst, cursor_i, eidx_i);

    // ---- logits per edge chunk (eproj3 = edge_attr @ WeK3) ----
    for (int e0 = 0; e0 < E_EDGES; e0 += EPCHUNK) {
        launch_mfma(edge_attr + (size_t)e0 * EDIM, WeK3_s, WeK3_s + 8192, nullptr, nullptr,
                    epbig, EPCHUNK, EDIM, HCDIM, 0, 0, stream);
        logits_kernel<<<dim3((EPCHUNK * HEADS + 255) / 256), blk, 0, stream>>>(
            Qb, Kb, A2buf, c0buf, epbig, src, dst, logits, e0, EPCHUNK);
    }

    // ---- per-node softmax + aggregation; logits -> alpha ----
    node_attn_kernel<<<dim3(N_NODES / NODE_WAVES), blk, 0, stream>>>(
        Vb, edge_attr, logits, rowptr_i, eidx_i, src, Wve, bve, WeWv3, aggout);

    // ---- e_out = LN((alpha ⊙ (edge_attr@We)) @ Wfce + bfce) + edge_attr  (fused, no eproj round-trip) ----
    ffn2_fused<128, 64, 128, 64, 0, 1><<<dim3(E_EDGES / 128), blk, 0, stream>>>(
        edge_attr, We_s, We_s + 8192, nullptr, Wfce_s, Wfce_s + 8192, bfce,
        logits, e_out, E_EDGES);
    ln_res_kernel<<<dim3(25000), blk, 0, stream>>>(e_out, lne_g, lne_b, edge_attr, E_EDGES, EDIM);

    // ---- node output path ----
    launch_mfma(aggout, Wfcn_s, Wfcn_s + 16384, bfcn, nullptr, x_out, N_NODES, HCDIM, DIM, 0, 0, stream);
    ln_res_kernel<<<dim3(12500), blk, 0, stream>>>(x_out, lnn_g, lnn_b, x, N_NODES, DIM);

    // ---- node FFN (fused W1n+gelu+W2n) + BN + residual + softplus ----
    ffn2_fused<64, 128, 512, 128, 1, 0><<<dim3((N_NODES + 63) / 64), blk, 0, stream>>>(
        x_out, W1n_s, W1n_s + 65536, b1n, W2n_s, W2n_s + 65536, b2n,
        nullptr, y_n, N_NODES);
    bn_stats_kernel<<<dim3(256), blk, 0, stream>>>(y_n, colsum_n, colsq_n, N_NODES, DIM);
    {
        int n = N_NODES * DIM;
        bn_apply_softplus_kernel<<<dim3((n + 255) / 256), blk, 0, stream>>>(
            y_n, x_out, colsum_n, colsq_n, bnn_g, bnn_b, (float*)d_out, N_NODES, DIM);
    }

    // ---- edge FFN (fused W1e+gelu+W2e) ----
    ffn2_fused<128, 64, 256, 64, 1, 0><<<dim3(E_EDGES / 128), blk, 0, stream>>>(
        e_out, W1e_s, W1e_s + 16384, b1e, W2e_s, W2e_s + 16384, b2e,
        nullptr, y_e, E_EDGES);
    bn_stats_kernel<<<dim3(256), blk, 0, stream>>>(y_e, colsum_e, colsq_e, E_EDGES, EDIM);
    {
        int n = E_EDGES * EDIM;
        bn_apply_softplus_kernel<<<dim3((n + 255) / 256), blk, 0, stream>>>(
            y_e, e_out, colsum_e, colsq_e, bne_g, bne_b, (float*)d_out + (size_t)N_NODES * DIM, E_EDGES, EDIM);
    }
}

// Round 4
// 2181.613 us; speedup vs baseline: 1.2143x; 1.0895x over previous
//
#include <hip/hip_runtime.h>
#include <math.h>
#include <stdint.h>

#define N_NODES 50000
#define E_EDGES 400000
#define DIM 128
#define HEADS 8
#define CH 16
#define EDIM 64
#define HCDIM 128   // HEADS*CH

#define EPCHUNK 100000   // edge chunk for eproj/logits loop (4 chunks)
#define NODE_WAVES 4

using bf16x8 = __attribute__((ext_vector_type(8))) short;
using f32x4v = __attribute__((ext_vector_type(4))) float;

// ---------------- utility ----------------

__global__ void fill_kernel(float* p, float v, int n) {
    int i = blockIdx.x * blockDim.x + threadIdx.x;
    if (i < n) p[i] = v;
}

__global__ void concat3_kernel(const float* __restrict__ a, const float* __restrict__ b,
                               const float* __restrict__ c, float* __restrict__ o) {
    int i = blockIdx.x * 256 + threadIdx.x;
    if (i < 128) o[i] = a[i];
    else if (i < 256) o[i] = b[i - 128];
    else if (i < 384) o[i] = c[i - 256];
}

__device__ inline float gelu_f(float x) {
    return 0.5f * x * (1.0f + erff(x * 0.70710678118654752f));
}

__device__ inline float softplus_f(float x) {
    return x > 20.f ? x : log1pf(expf(x));
}

__device__ inline unsigned short f32_to_bf16_rn(float f) {
    unsigned u = __float_as_uint(f);
    u += 0x7FFFu + ((u >> 16) & 1u);
    return (unsigned short)(u >> 16);
}
__device__ inline float bf16_to_f32(unsigned short h) {
    return __uint_as_float((unsigned)h << 16);
}

// ---------------- weight pre-transpose + bf16 split ----------------
// in: W (KxN f32, row-major). out: hi/lo bf16 planes, [n][k] layout.
__global__ __launch_bounds__(256) void wsplit_kernel(
    const float* __restrict__ W, unsigned short* __restrict__ hi,
    unsigned short* __restrict__ lo, int K, int N)
{
    int idx = blockIdx.x * 256 + threadIdx.x;
    if (idx >= K * N) return;
    int n = idx / K, k = idx - n * K;
    float x = W[(size_t)k * N + n];
    unsigned short h = f32_to_bf16_rn(x);
    hi[idx] = h;
    lo[idx] = f32_to_bf16_rn(x - bf16_to_f32(h));
}

// ---------------- MFMA GEMM (single): C = act(A @ W + bias) ----------------
template<int BN>
__global__ __launch_bounds__(256) void gemm_mfma(
    const float* __restrict__ A,
    const unsigned short* __restrict__ Whi, const unsigned short* __restrict__ Wlo,
    const float* __restrict__ bias, const float* __restrict__ ascale,
    float* __restrict__ C, int M, int K, int Nc, int act, int cmode)
{
    constexpr int MT = (BN == 128) ? 4 : 2;
    __shared__ bf16x8 As[2][4][128];   // [plane hi/lo][k-granule][row], 16 KB

    const int tid = threadIdx.x;
    const int w = tid >> 6, lane = tid & 63;
    const int l15 = lane & 15, lg = lane >> 4;
    const int m0 = blockIdx.y * 128;
    const int n0 = blockIdx.x * BN;
    const int rowbase = (BN == 128) ? (w >> 1) * 64 : w * 32;
    const int colbase = (BN == 128) ? (w & 1) * 64 : 0;
    const int k16 = K >> 4;

    f32x4v acc[MT][4];
#pragma unroll
    for (int i = 0; i < MT; ++i)
#pragma unroll
        for (int j = 0; j < 4; ++j)
#pragma unroll
            for (int cidx = 0; cidx < 4; ++cidx) acc[i][j][cidx] = 0.f;

    for (int k0 = 0; k0 < K; k0 += 32) {
#pragma unroll
        for (int it = 0; it < 2; ++it) {
            int row = w * 16 + l15 + it * 64;
            int ar = m0 + row;
            float v[8];
            if (ar < M) {
                const float* ap = A + (size_t)ar * K + k0 + lg * 8;
                *(float4*)&v[0] = *(const float4*)ap;
                *(float4*)&v[4] = *(const float4*)(ap + 4);
                if (ascale) {
                    float s = ascale[(size_t)ar * k16 + ((k0 >> 4) + (lg >> 1))];
#pragma unroll
                    for (int j = 0; j < 8; ++j) v[j] *= s;
                }
            } else {
#pragma unroll
                for (int j = 0; j < 8; ++j) v[j] = 0.f;
            }
            bf16x8 gh, gl;
#pragma unroll
            for (int j = 0; j < 8; ++j) {
                unsigned short h = f32_to_bf16_rn(v[j]);
                gh[j] = (short)h;
                gl[j] = (short)f32_to_bf16_rn(v[j] - bf16_to_f32(h));
            }
            As[0][lg][row] = gh;
            As[1][lg][row] = gl;
        }
        bf16x8 bh[4], bl[4];
#pragma unroll
        for (int nt = 0; nt < 4; ++nt) {
            size_t off = (size_t)(n0 + colbase + nt * 16 + l15) * K + k0 + lg * 8;
            bh[nt] = *(const bf16x8*)(Whi + off);
            bl[nt] = *(const bf16x8*)(Wlo + off);
        }
        __syncthreads();
#pragma unroll
        for (int mt = 0; mt < MT; ++mt) {
            int arow = rowbase + mt * 16 + l15;
            bf16x8 ah = As[0][lg][arow];
            bf16x8 al = As[1][lg][arow];
#pragma unroll
            for (int nt = 0; nt < 4; ++nt) {
                acc[mt][nt] = __builtin_amdgcn_mfma_f32_16x16x32_bf16(ah, bh[nt], acc[mt][nt], 0, 0, 0);
                acc[mt][nt] = __builtin_amdgcn_mfma_f32_16x16x32_bf16(al, bh[nt], acc[mt][nt], 0, 0, 0);
                acc[mt][nt] = __builtin_amdgcn_mfma_f32_16x16x32_bf16(ah, bl[nt], acc[mt][nt], 0, 0, 0);
            }
        }
        __syncthreads();
    }

#pragma unroll
    for (int nt = 0; nt < 4; ++nt) {
        int col = n0 + colbase + nt * 16 + l15;
        float bb = bias ? bias[col] : 0.f;
#pragma unroll
        for (int mt = 0; mt < MT; ++mt) {
#pragma unroll
            for (int i = 0; i < 4; ++i) {
                int r = m0 + rowbase + mt * 16 + lg * 4 + i;
                if (r < M) {
                    float o = acc[mt][nt][i] + bb;
                    if (act == 1) o = gelu_f(o);
                    if (cmode == 1) {
                        C[(size_t)(col >> 7) * ((size_t)N_NODES * HCDIM) + (size_t)r * HCDIM + (col & 127)] = o;
                    } else {
                        C[(size_t)r * Nc + col] = o;
                    }
                }
            }
        }
    }
}

static inline void launch_mfma(const float* A, const unsigned short* Whi, const unsigned short* Wlo,
                               const float* bias, const float* ascale, float* C,
                               int M, int K, int Nc, int act, int cmode, hipStream_t stream)
{
    int gy = (M + 127) / 128;
    if (Nc % 128 == 0)
        gemm_mfma<128><<<dim3(Nc / 128, gy), dim3(256), 0, stream>>>(A, Whi, Wlo, bias, ascale, C, M, K, Nc, act, cmode);
    else
        gemm_mfma<64><<<dim3(Nc / 64, gy), dim3(256), 0, stream>>>(A, Whi, Wlo, bias, ascale, C, M, K, Nc, act, cmode);
}

// ---------------- fused double GEMM: out = (act(A@W1 + b1) [* ascale]) @ W2 + b2 ----------------
// A-fragments held in REGISTERS (each wave owns its rows; each lane a fixed (row,granule)
// set) -- no A LDS, no staging barrier. Hidden staged via 32KB (BM=128) XOR-swizzled LDS.
// LN2: fuse LayerNorm(out)+resid into epilogue (requires N2==64: wave owns whole rows).
template<int BM, int K1, int NH, int N2, int ACT1, int ASC, int LN2>
__global__ __launch_bounds__(256) void ffn2_fused(
    const float* __restrict__ A,
    const unsigned short* __restrict__ W1hi, const unsigned short* __restrict__ W1lo,
    const float* __restrict__ b1,
    const unsigned short* __restrict__ W2hi, const unsigned short* __restrict__ W2lo,
    const float* __restrict__ b2,
    const float* __restrict__ ascale,
    const float* __restrict__ lng, const float* __restrict__ lnb,
    const float* __restrict__ resid,
    float* __restrict__ Cout, int M)
{
    constexpr int MT = BM / 64;        // 16-row tiles per wave
    constexpr int NT2 = N2 / 16;
    constexpr int NK = K1 / 32;        // k-steps (granules per lane per row)
    __shared__ unsigned short Hs[2][BM][64];      // split hidden chunk, XOR-swizzled

    const int tid = threadIdx.x;
    const int w = tid >> 6, lane = tid & 63;
    const int l15 = lane & 15, lg = lane >> 4;
    const int m0 = blockIdx.x * BM;
    const int wr0 = w * (BM / 4);

    // ---- load A fragments into registers (bf16 hi/lo split) ----
    bf16x8 aA[2][MT][NK];
#pragma unroll
    for (int mt = 0; mt < MT; ++mt) {
        int ar = m0 + wr0 + mt * 16 + l15;
#pragma unroll
        for (int t = 0; t < NK; ++t) {
            float v[8];
            if (ar < M) {
                const float* ap = A + (size_t)ar * K1 + t * 32 + lg * 8;
                *(float4*)&v[0] = *(const float4*)ap;
                *(float4*)&v[4] = *(const float4*)(ap + 4);
            } else {
#pragma unroll
                for (int j = 0; j < 8; ++j) v[j] = 0.f;
            }
            bf16x8 gh, gl;
#pragma unroll
            for (int j = 0; j < 8; ++j) {
                unsigned short h = f32_to_bf16_rn(v[j]);
                gh[j] = (short)h;
                gl[j] = (short)f32_to_bf16_rn(v[j] - bf16_to_f32(h));
            }
            aA[0][mt][t] = gh;
            aA[1][mt][t] = gl;
        }
    }

    f32x4v oacc[MT][NT2];
#pragma unroll
    for (int mt = 0; mt < MT; ++mt)
#pragma unroll
        for (int nt = 0; nt < NT2; ++nt)
#pragma unroll
            for (int cidx = 0; cidx < 4; ++cidx) oacc[mt][nt][cidx] = 0.f;

    for (int hc = 0; hc < NH; hc += 64) {
        // ---- GEMM1: hidden chunk (BM x 64) ----
        f32x4v acc1[MT][4];
#pragma unroll
        for (int mt = 0; mt < MT; ++mt)
#pragma unroll
            for (int nt = 0; nt < 4; ++nt)
#pragma unroll
                for (int cidx = 0; cidx < 4; ++cidx) acc1[mt][nt][cidx] = 0.f;

#pragma unroll
        for (int t = 0; t < NK; ++t) {
            bf16x8 bh[4], bl[4];
#pragma unroll
            for (int nt = 0; nt < 4; ++nt) {
                size_t off = (size_t)(hc + nt * 16 + l15) * K1 + t * 32 + lg * 8;
                bh[nt] = *(const bf16x8*)(W1hi + off);
                bl[nt] = *(const bf16x8*)(W1lo + off);
            }
#pragma unroll
            for (int mt = 0; mt < MT; ++mt) {
                bf16x8 ah = aA[0][mt][t];
                bf16x8 al = aA[1][mt][t];
#pragma unroll
                for (int nt = 0; nt < 4; ++nt) {
                    acc1[mt][nt] = __builtin_amdgcn_mfma_f32_16x16x32_bf16(ah, bh[nt], acc1[mt][nt], 0, 0, 0);
                    acc1[mt][nt] = __builtin_amdgcn_mfma_f32_16x16x32_bf16(al, bh[nt], acc1[mt][nt], 0, 0, 0);
                    acc1[mt][nt] = __builtin_amdgcn_mfma_f32_16x16x32_bf16(ah, bl[nt], acc1[mt][nt], 0, 0, 0);
                }
            }
        }

        __syncthreads();   // prior chunk's Hs readers done
        // ---- bias/act/scale + split + stage hidden ----
#pragma unroll
        for (int nt = 0; nt < 4; ++nt) {
            float b1v = b1 ? b1[hc + nt * 16 + l15] : 0.f;
#pragma unroll
            for (int mt = 0; mt < MT; ++mt) {
#pragma unroll
                for (int i = 0; i < 4; ++i) {
                    int row = wr0 + mt * 16 + lg * 4 + i;
                    float o = acc1[mt][nt][i] + b1v;
                    if (ACT1) o = gelu_f(o);
                    if (ASC) {
                        int r = m0 + row;
                        float s = (r < M) ? ascale[(size_t)r * (NH >> 4) + (hc >> 4) + nt] : 0.f;
                        o *= s;
                    }
                    unsigned short hh = f32_to_bf16_rn(o);
                    unsigned short hl = f32_to_bf16_rn(o - bf16_to_f32(hh));
                    int slot = (nt * 16 + l15) ^ ((row & 7) << 3);
                    Hs[0][row][slot] = hh;
                    Hs[1][row][slot] = hl;
                }
            }
        }
        __syncthreads();

        // ---- GEMM2: accumulate out += h_chunk @ W2[hc:hc+64, :] ----
#pragma unroll
        for (int k2 = 0; k2 < 64; k2 += 32) {
            bf16x8 b2h[NT2], b2l[NT2];
#pragma unroll
            for (int nt = 0; nt < NT2; ++nt) {
                size_t off = (size_t)(nt * 16 + l15) * NH + hc + k2 + lg * 8;
                b2h[nt] = *(const bf16x8*)(W2hi + off);
                b2l[nt] = *(const bf16x8*)(W2lo + off);
            }
#pragma unroll
            for (int mt = 0; mt < MT; ++mt) {
                int row = wr0 + mt * 16 + l15;
                int slot = (k2 + lg * 8) ^ ((row & 7) << 3);
                bf16x8 ah = *(const bf16x8*)&Hs[0][row][slot];
                bf16x8 al = *(const bf16x8*)&Hs[1][row][slot];
#pragma unroll
                for (int nt = 0; nt < NT2; ++nt) {
                    oacc[mt][nt] = __builtin_amdgcn_mfma_f32_16x16x32_bf16(ah, b2h[nt], oacc[mt][nt], 0, 0, 0);
                    oacc[mt][nt] = __builtin_amdgcn_mfma_f32_16x16x32_bf16(al, b2h[nt], oacc[mt][nt], 0, 0, 0);
                    oacc[mt][nt] = __builtin_amdgcn_mfma_f32_16x16x32_bf16(ah, b2l[nt], oacc[mt][nt], 0, 0, 0);
                }
            }
        }
    }

    // ---- epilogue ----
    if (LN2) {
        // N2 == 64: each wave owns complete rows; LN + residual fused.
        float b2v[4], gv[4], bv[4];
#pragma unroll
        for (int nt = 0; nt < NT2; ++nt) {
            int col = nt * 16 + l15;
            b2v[nt] = b2 ? b2[col] : 0.f;
            gv[nt] = lng[col];
            bv[nt] = lnb[col];
        }
#pragma unroll
        for (int mt = 0; mt < MT; ++mt) {
#pragma unroll
            for (int i = 0; i < 4; ++i) {
                int r = m0 + wr0 + mt * 16 + lg * 4 + i;
                float o[4];
                float s = 0.f;
#pragma unroll
                for (int nt = 0; nt < NT2; ++nt) { o[nt] = oacc[mt][nt][i] + b2v[nt]; s += o[nt]; }
                s += __shfl_xor(s, 1); s += __shfl_xor(s, 2); s += __shfl_xor(s, 4); s += __shfl_xor(s, 8);
                float mean = s * (1.f / 64.f);
                float q = 0.f;
                float d[4];
#pragma unroll
                for (int nt = 0; nt < NT2; ++nt) { d[nt] = o[nt] - mean; q += d[nt] * d[nt]; }
                q += __shfl_xor(q, 1); q += __shfl_xor(q, 2); q += __shfl_xor(q, 4); q += __shfl_xor(q, 8);
                float inv = rsqrtf(q * (1.f / 64.f) + 1e-5f);
                if (r < M) {
#pragma unroll
                    for (int nt = 0; nt < NT2; ++nt) {
                        int col = nt * 16 + l15;
                        Cout[(size_t)r * N2 + col] = d[nt] * inv * gv[nt] + bv[nt] + resid[(size_t)r * N2 + col];
                    }
                }
            }
        }
    } else {
#pragma unroll
        for (int nt = 0; nt < NT2; ++nt) {
            int col = nt * 16 + l15;
            float bb = b2 ? b2[col] : 0.f;
#pragma unroll
            for (int mt = 0; mt < MT; ++mt) {
#pragma unroll
                for (int i = 0; i < 4; ++i) {
                    int r = m0 + wr0 + mt * 16 + lg * 4 + i;
                    if (r < M) Cout[(size_t)r * N2 + col] = oacc[mt][nt][i] + bb;
                }
            }
        }
    }
}

// ---------------- precompute: WeX[k][h*16+j] = sum_c We[k][h*16+c] * X[c][j] ----------------
__global__ __launch_bounds__(256) void wex_kernel(
    const float* __restrict__ We, const float* __restrict__ X, float* __restrict__ out)
{
    int idx = blockIdx.x * 256 + threadIdx.x;
    if (idx >= 64 * 128) return;
    int k = idx >> 7, hj = idx & 127, h = hj >> 4, j = hj & 15;
    float s = 0.f;
#pragma unroll
    for (int c = 0; c < 16; ++c) s += We[k * 128 + h * 16 + c] * X[c * 16 + j];
    out[idx] = s;
}

// ---------------- precompute per (d,h): c0 = Q·(K@Wk1 + bke); A2[c] = sum_j Wk2[c][j]*Q[j] ----------------
__global__ __launch_bounds__(256) void qk_pre_kernel(
    const float* __restrict__ Q, const float* __restrict__ K,
    const float* __restrict__ Wke, const float* __restrict__ bke,
    float* __restrict__ A2, float* __restrict__ c0)
{
    __shared__ float wk1[256], wk2[256], bks[16];
    for (int i = threadIdx.x; i < 256; i += 256) { wk1[i] = Wke[i]; wk2[i] = Wke[256 + i]; }
    if (threadIdx.x < 16) bks[threadIdx.x] = bke[threadIdx.x];
    __syncthreads();
    int idx = blockIdx.x * 256 + threadIdx.x;   // idx = ((d*8 + h)*16 + j)
    int j = idx & 15; int dh = idx >> 4; int h = dh & 7; int d = dh >> 3;
    if (d >= N_NODES) return;
    const float* q = Q + (size_t)d * HCDIM + h * CH;
    const float* k = K + (size_t)d * HCDIM + h * CH;
    float qv[16], kv[16];
#pragma unroll
    for (int t = 0; t < 4; ++t) {
        *(float4*)&qv[t * 4] = *(const float4*)(q + t * 4);
        *(float4*)&kv[t * 4] = *(const float4*)(k + t * 4);
    }
    float a2 = 0.f;
#pragma unroll
    for (int t = 0; t < 16; ++t) a2 += wk2[j * 16 + t] * qv[t];
    A2[idx] = a2;
    float kn = bks[j];
#pragma unroll
    for (int c = 0; c < 16; ++c) kn += kv[c] * wk1[c * 16 + j];
    float t = qv[j] * kn;
    t += __shfl_xor(t, 1); t += __shfl_xor(t, 2); t += __shfl_xor(t, 4); t += __shfl_xor(t, 8);
    if (j == 0) c0[dh] = t;
}

// ---------------- logits (chunked) ----------------
__global__ __launch_bounds__(256) void logits_kernel(
    const float* __restrict__ Q, const float* __restrict__ K,
    const float* __restrict__ A2, const float* __restrict__ c0,
    const float* __restrict__ ep3,
    const int* __restrict__ src, const int* __restrict__ dst,
    float* __restrict__ logits, int e0, int ecnt)
{
    int idx = blockIdx.x * 256 + threadIdx.x;
    if (idx >= ecnt * HEADS) return;
    int el = idx >> 3, h = idx & 7, e = e0 + el;
    int s = src[e], d = dst[e];
    const float* q  = Q  + (size_t)d * HCDIM + h * CH;
    const float* a2 = A2 + (size_t)d * HCDIM + h * CH;
    const float* ks = K  + (size_t)s * HCDIM + h * CH;
    const float* ep = ep3 + (size_t)el * HCDIM + h * CH;
    float acc = c0[(size_t)d * HEADS + h];
    float qv[16], av[16], kv[16], ev[16];
#pragma unroll
    for (int t = 0; t < 4; ++t) {
        *(float4*)&qv[t * 4] = *(const float4*)(q + t * 4);
        *(float4*)&av[t * 4] = *(const float4*)(a2 + t * 4);
        *(float4*)&kv[t * 4] = *(const float4*)(ks + t * 4);
        *(float4*)&ev[t * 4] = *(const float4*)(ep + t * 4);
    }
#pragma unroll
    for (int t = 0; t < 16; ++t) acc += av[t] * kv[t] + qv[t] * ev[t];
    logits[(size_t)e * HEADS + h] = acc * 0.25f;
}

// ---------------- CSR build ----------------
__global__ __launch_bounds__(256) void count_kernel(const int* __restrict__ dst, int* __restrict__ cnt) {
    int e = blockIdx.x * 256 + threadIdx.x;
    if (e < E_EDGES) atomicAdd(&cnt[dst[e]], 1);
}

__global__ __launch_bounds__(1024) void scan_kernel(
    const int* __restrict__ cnt, int* __restrict__ rowptr, int* __restrict__ cursor, int n)
{
    __shared__ int buf[1024];
    __shared__ int base;
    int tid = threadIdx.x;
    if (tid == 0) { base = 0; rowptr[0] = 0; }
    __syncthreads();
    for (int t0 = 0; t0 < n; t0 += 1024) {
        int i = t0 + tid;
        int v = (i < n) ? cnt[i] : 0;
        buf[tid] = v;
        __syncthreads();
        for (int off = 1; off < 1024; off <<= 1) {
            int add = (tid >= off) ? buf[tid - off] : 0;
            __syncthreads();
            buf[tid] += add;
            __syncthreads();
        }
        if (i < n) { rowptr[i + 1] = base + buf[tid]; cursor[i] = base + buf[tid] - v; }
        __syncthreads();
        if (tid == 0) base += buf[1023];
        __syncthreads();
    }
}

__global__ __launch_bounds__(256) void scatter_kernel(
    const int* __restrict__ dst, int* __restrict__ cursor, int* __restrict__ eidx) {
    int e = blockIdx.x * 256 + threadIdx.x;
    if (e < E_EDGES) {
        int p = atomicAdd(&cursor[dst[e]], 1);
        eidx[p] = e;
    }
}

// ---------------- per-node attention ----------------
__global__ __launch_bounds__(256) void node_attn_kernel(
    const float* __restrict__ Vb, const float* __restrict__ edge_attr,
    float* __restrict__ logits,
    const int* __restrict__ rowptr, const int* __restrict__ eidx,
    const int* __restrict__ src,
    const float* __restrict__ Wve, const float* __restrict__ bve,
    const float* __restrict__ WeWv3, float* __restrict__ aggout)
{
    __shared__ float wv1s[256], wv2s[256], bvs[16];
    __shared__ float stage[NODE_WAVES][640];

    for (int i = threadIdx.x; i < 256; i += 256) { wv1s[i] = Wve[i]; wv2s[i] = Wve[256 + i]; }
    if (threadIdx.x < 16) bvs[threadIdx.x] = bve[threadIdx.x];
    __syncthreads();

    int w = threadIdx.x >> 6, lane = threadIdx.x & 63;
    int d = blockIdx.x * NODE_WAVES + w;
    int r0 = rowptr[d], r1 = rowptr[d + 1], deg = r1 - r0;
    int h = lane >> 3, kg = lane & 7;

    if (deg == 0) {
        aggout[(size_t)d * HCDIM + lane] = 0.f;
        aggout[(size_t)d * HCDIM + 64 + lane] = 0.f;
    } else {
        float m[8], ssum[8];
#pragma unroll
        for (int t = 0; t < 8; ++t) { m[t] = -INFINITY; ssum[t] = 0.f; }
        for (int i = r0 + lane; i < r1; i += 64) {
            int e = eidx[i];
            const float* lp = logits + (size_t)e * HEADS;
            float l[8];
            *(float4*)&l[0] = *(const float4*)lp;
            *(float4*)&l[4] = *(const float4*)(lp + 4);
#pragma unroll
            for (int t = 0; t < 8; ++t) m[t] = fmaxf(m[t], l[t]);
        }
#pragma unroll
        for (int o = 1; o < 64; o <<= 1) {
#pragma unroll
            for (int t = 0; t < 8; ++t) m[t] = fmaxf(m[t], __shfl_xor(m[t], o));
        }
        for (int i = r0 + lane; i < r1; i += 64) {
            int e = eidx[i];
            const float* lp = logits + (size_t)e * HEADS;
            float l[8];
            *(float4*)&l[0] = *(const float4*)lp;
            *(float4*)&l[4] = *(const float4*)(lp + 4);
#pragma unroll
            for (int t = 0; t < 8; ++t) ssum[t] += expf(l[t] - m[t]);
        }
#pragma unroll
        for (int o = 1; o < 64; o <<= 1) {
#pragma unroll
            for (int t = 0; t < 8; ++t) ssum[t] += __shfl_xor(ssum[t], o);
        }
        float mh = m[0], dd = ssum[0];
#pragma unroll
        for (int t = 1; t < 8; ++t) { if (h == t) { mh = m[t]; dd = ssum[t]; } }
        float den = dd + 1e-16f;

        float wea[8] = {0.f, 0.f, 0.f, 0.f, 0.f, 0.f, 0.f, 0.f};
        float av0 = 0.f, av1 = 0.f;
        for (int i = r0; i < r1; ++i) {
            int e = eidx[i];
            float lg = logits[(size_t)e * HEADS + h];
            float alpha = expf(lg - mh) / den;
            if (kg == 0) logits[(size_t)e * HEADS + h] = alpha;
            int s = src[e];
            const float* ea = edge_attr + (size_t)e * EDIM + kg * 8;
            float ev[8];
            *(float4*)&ev[0] = *(const float4*)ea;
            *(float4*)&ev[4] = *(const float4*)(ea + 4);
#pragma unroll
            for (int t = 0; t < 8; ++t) wea[t] += alpha * ev[t];
            float2 vv = *(const float2*)(Vb + (size_t)s * HCDIM + h * CH + kg * 2);
            av0 += alpha * vv.x;
            av1 += alpha * vv.y;
        }
        float* st = stage[w];
#pragma unroll
        for (int t = 0; t < 8; ++t) st[h * 64 + kg * 8 + t] = wea[t];
        st[512 + h * 16 + kg * 2] = av0;
        st[512 + h * 16 + kg * 2 + 1] = av1;
    }
    __syncthreads();
    if (deg > 0) {
        float* st = stage[w];
        int c0i = kg * 2;
        float acc0 = bvs[c0i], acc1 = bvs[c0i + 1];
        const float* vd = Vb + (size_t)d * HCDIM + h * CH;
#pragma unroll
        for (int j = 0; j < 16; ++j) {
            float vj = vd[j];
            float a = st[512 + h * 16 + j];
            acc0 += vj * wv1s[j * 16 + c0i] + a * wv2s[j * 16 + c0i];
            acc1 += vj * wv1s[j * 16 + c0i + 1] + a * wv2s[j * 16 + c0i + 1];
        }
        const float* w3 = WeWv3 + h * 16 + c0i;
#pragma unroll 16
        for (int k = 0; k < 64; ++k) {
            float wv = st[h * 64 + k];
            float2 w2v = *(const float2*)(w3 + k * 128);
            acc0 += wv * w2v.x;
            acc1 += wv * w2v.y;
        }
        aggout[(size_t)d * HCDIM + h * CH + c0i] = acc0;
        aggout[(size_t)d * HCDIM + h * CH + c0i + 1] = acc1;
    }
}

// ---------------- layernorm (+ residual) ----------------
__global__ __launch_bounds__(256) void ln_res_kernel(
    float* __restrict__ y, const float* __restrict__ g, const float* __restrict__ b,
    const float* __restrict__ res, int rows, int w)
{
    int wave = threadIdx.x >> 6;
    int lane = threadIdx.x & 63;
    int nw = blockDim.x >> 6;
    for (int r = blockIdx.x * nw + wave; r < rows; r += gridDim.x * nw) {
        size_t base = (size_t)r * w;
        float v0 = y[base + lane];
        float v1 = (w == 128) ? y[base + 64 + lane] : 0.f;
        float s = v0 + v1;
#pragma unroll
        for (int o = 32; o; o >>= 1) s += __shfl_xor(s, o);
        float m = s / (float)w;
        float d0 = v0 - m;
        float d1 = (w == 128) ? (v1 - m) : 0.f;
        float q = d0 * d0 + d1 * d1;
#pragma unroll
        for (int o = 32; o; o >>= 1) q += __shfl_xor(q, o);
        float inv = rsqrtf(q / (float)w + 1e-5f);
        y[base + lane] = d0 * inv * g[lane] + b[lane] + res[base + lane];
        if (w == 128)
            y[base + 64 + lane] = d1 * inv * g[64 + lane] + b[64 + lane] + res[base + 64 + lane];
    }
}

// ---------------- batchnorm stats ----------------
__global__ __launch_bounds__(256) void bn_stats_kernel(
    const float* __restrict__ y, float* __restrict__ colsum, float* __restrict__ colsq,
    int rows, int cols)
{
    __shared__ float ss[256], sq[256];
    int tid = threadIdx.x;
    int col = tid % cols;
    int rsub = tid / cols;
    int rstep = blockDim.x / cols;
    float ls = 0.f, lq = 0.f;
    for (int r = blockIdx.x * rstep + rsub; r < rows; r += gridDim.x * rstep) {
        float v = y[(size_t)r * cols + col];
        ls += v;
        lq += v * v;
    }
    ss[tid] = ls;
    sq[tid] = lq;
    __syncthreads();
    if (tid < cols) {
        for (int o = cols; o < 256; o += cols) { ls += ss[tid + o]; lq += sq[tid + o]; }
        atomicAdd(&colsum[tid], ls);
        atomicAdd(&colsq[tid], lq);
    }
}

// ---------------- batchnorm apply + residual + softplus ----------------
__global__ __launch_bounds__(256) void bn_apply_softplus_kernel(
    const float* __restrict__ y, const float* __restrict__ res,
    const float* __restrict__ colsum, const float* __restrict__ colsq,
    const float* __restrict__ g, const float* __restrict__ b,
    float* __restrict__ out, int rows, int cols)
{
    int idx = blockIdx.x * blockDim.x + threadIdx.x;
    int n = rows * cols;
    if (idx >= n) return;
    int c = idx % cols;
    float m = colsum[c] / (float)rows;
    float var = colsq[c] / (float)rows - m * m;
    float inv = rsqrtf(var + 1e-5f);
    float v = (y[idx] - m) * inv * g[c] + b[c] + res[idx];
    out[idx] = softplus_f(v);
}

// ---------------- launcher ----------------

extern "C" void kernel_launch(void* const* d_in, const int* in_sizes, int n_in,
                              void* d_out, int out_size, void* d_ws, size_t ws_size,
                              hipStream_t stream) {
    const float* x         = (const float*)d_in[0];
    const int*   ei        = (const int*)d_in[1];
    const float* edge_attr = (const float*)d_in[2];
    const float* Wq  = (const float*)d_in[3];
    const float* bq  = (const float*)d_in[4];
    const float* Wk  = (const float*)d_in[5];
    const float* bk  = (const float*)d_in[6];
    const float* Wv  = (const float*)d_in[7];
    const float* bv  = (const float*)d_in[8];
    const float* We  = (const float*)d_in[9];
    const float* Wke = (const float*)d_in[10];
    const float* bke = (const float*)d_in[11];
    const float* Wve = (const float*)d_in[12];
    const float* bve = (const float*)d_in[13];
    const float* Wfce = (const float*)d_in[14];
    const float* bfce = (const float*)d_in[15];
    const float* lne_g = (const float*)d_in[16];
    const float* lne_b = (const float*)d_in[17];
    const float* Wfcn = (const float*)d_in[18];
    const float* bfcn = (const float*)d_in[19];
    const float* lnn_g = (const float*)d_in[20];
    const float* lnn_b = (const float*)d_in[21];
    const float* W1n = (const float*)d_in[22];
    const float* b1n = (const float*)d_in[23];
    const float* W2n = (const float*)d_in[24];
    const float* b2n = (const float*)d_in[25];
    const float* W1e = (const float*)d_in[26];
    const float* b1e = (const float*)d_in[27];
    const float* W2e = (const float*)d_in[28];
    const float* b2e = (const float*)d_in[29];
    const float* bnn_g = (const float*)d_in[30];
    const float* bnn_b = (const float*)d_in[31];
    const float* bne_g = (const float*)d_in[32];
    const float* bne_b = (const float*)d_in[33];

    const int* src = ei;
    const int* dst = ei + E_EDGES;

    float* ws = (float*)d_ws;
    const size_t M64   = (size_t)E_EDGES * EDIM;       // 25.6M
    const size_t NODE2 = (size_t)N_NODES * HCDIM;      // 6.4M

    // regionR [0, 25.6M): Qb|Kb|Vb
    float* regionR = ws;
    float* Qb  = regionR;
    float* Kb  = regionR + NODE2;
    float* Vb  = regionR + 2 * NODE2;

    // overlayY [25.6M, 51.2M): logits|c0|csr|aggout|y_n|x_out; later y_e
    float* overlayY = ws + M64;
    float* logits = overlayY;                                  // 3.2M (holds alpha later)
    float* c0buf  = logits + (size_t)E_EDGES * HEADS;          // 0.4M
    int*   cnt_i    = (int*)(c0buf + (size_t)N_NODES * HEADS); // 50000
    int*   rowptr_i = cnt_i + N_NODES;                         // 50001
    int*   cursor_i = rowptr_i + N_NODES + 1;                  // 50000
    int*   eidx_i   = cursor_i + N_NODES;                      // 400000
    float* aggout = (float*)(((uintptr_t)(eidx_i + E_EDGES) + 15) & ~(uintptr_t)15); // 6.4M
    float* y_n    = aggout + NODE2;                            // 6.4M
    float* x_out  = y_n + NODE2;                               // 6.4M
    float* y_e    = overlayY;                                  // 25.6M (late phase)
    float* epbig  = y_n;       // 12.8M scratch (EPCHUNK x 128) while y_n/x_out are dead

    // e_out region [51.2M, 76.8M): A2 parks at its start (dead before e_out written)
    float* e_out = ws + 2 * M64;
    float* A2buf = e_out;                                      // 6.4M, dead after logits

    // tail [76.8M, +)
    float* tail = ws + 3 * M64;
    float* colsum_n = tail;            // 128
    float* colsq_n  = tail + 128;      // 128
    float* colsum_e = tail + 256;      // 64
    float* colsq_e  = tail + 320;      // 64
    float* WeK3  = tail + 384;         // 8192
    float* WeWv3 = WeK3 + 8192;        // 8192
    float* bqkv  = WeWv3 + 8192;       // 384

    // split-weight arena (bf16 hi/lo planes, [n][k] layout), ~1 MB
    unsigned short* wsp = (unsigned short*)(bqkv + 384);
    unsigned short* QKV_s  = wsp;                     // [384][128] hi then lo (49152 each)
    unsigned short* WeK3_s = QKV_s  + 2 * 49152;      // K=64,N=128
    unsigned short* We_s   = WeK3_s + 2 * 8192;       // K=64,N=128
    unsigned short* Wfce_s = We_s   + 2 * 8192;       // K=128,N=64
    unsigned short* Wfcn_s = Wfce_s + 2 * 8192;       // K=128,N=128
    unsigned short* W1n_s  = Wfcn_s + 2 * 16384;      // K=128,N=512
    unsigned short* W2n_s  = W1n_s  + 2 * 65536;      // K=512,N=128
    unsigned short* W1e_s  = W2n_s  + 2 * 65536;      // K=64,N=256
    unsigned short* W2e_s  = W1e_s  + 2 * 16384;      // K=256,N=64

    dim3 blk(256);

    // ---- init ----
    fill_kernel<<<dim3(2), blk, 0, stream>>>(colsum_n, 0.f, 384);
    fill_kernel<<<dim3((N_NODES + 255) / 256), blk, 0, stream>>>((float*)cnt_i, 0.f, N_NODES);

    // ---- folded weights ----
    wex_kernel<<<dim3(32), blk, 0, stream>>>(We, Wke + 2 * CH * CH, WeK3);
    wex_kernel<<<dim3(32), blk, 0, stream>>>(We, Wve + 2 * CH * CH, WeWv3);

    // ---- weight transpose + bf16 split ----
    wsplit_kernel<<<dim3(64), blk, 0, stream>>>(Wq, QKV_s,          QKV_s + 49152,          128, 128);
    wsplit_kernel<<<dim3(64), blk, 0, stream>>>(Wk, QKV_s + 16384,  QKV_s + 49152 + 16384,  128, 128);
    wsplit_kernel<<<dim3(64), blk, 0, stream>>>(Wv, QKV_s + 32768,  QKV_s + 49152 + 32768,  128, 128);
    wsplit_kernel<<<dim3(32), blk, 0, stream>>>(WeK3, WeK3_s, WeK3_s + 8192,  64, 128);
    wsplit_kernel<<<dim3(32), blk, 0, stream>>>(We,   We_s,   We_s + 8192,    64, 128);
    wsplit_kernel<<<dim3(32), blk, 0, stream>>>(Wfce, Wfce_s, Wfce_s + 8192,  128, 64);
    wsplit_kernel<<<dim3(64), blk, 0, stream>>>(Wfcn, Wfcn_s, Wfcn_s + 16384, 128, 128);
    wsplit_kernel<<<dim3(256), blk, 0, stream>>>(W1n, W1n_s, W1n_s + 65536,   128, 512);
    wsplit_kernel<<<dim3(256), blk, 0, stream>>>(W2n, W2n_s, W2n_s + 65536,   512, 128);
    wsplit_kernel<<<dim3(64), blk, 0, stream>>>(W1e, W1e_s, W1e_s + 16384,    64, 256);
    wsplit_kernel<<<dim3(64), blk, 0, stream>>>(W2e, W2e_s, W2e_s + 16384,    256, 64);
    concat3_kernel<<<dim3(2), blk, 0, stream>>>(bq, bk, bv, bqkv);

    // ---- QKV projection (merged, N=384, split-output) ----
    launch_mfma(x, QKV_s, QKV_s + 49152, bqkv, nullptr, Qb, N_NODES, 128, 384, 0, 1, stream);

    // ---- per-node QK precompute ----
    qk_pre_kernel<<<dim3(N_NODES * HCDIM / 256), blk, 0, stream>>>(Qb, Kb, Wke, bke, A2buf, c0buf);

    // ---- CSR build ----
    count_kernel<<<dim3((E_EDGES + 255) / 256), blk, 0, stream>>>(dst, cnt_i);
    scan_kernel<<<dim3(1), dim3(1024), 0, stream>>>(cnt_i, rowptr_i, cursor_i, N_NODES);
    scatter_kernel<<<dim3((E_EDGES + 255) / 256), blk, 0, stream>>>(dst, cursor_i, eidx_i);

    // ---- logits per edge chunk (eproj3 = edge_attr @ WeK3) ----
    for (int e0 = 0; e0 < E_EDGES; e0 += EPCHUNK) {
        launch_mfma(edge_attr + (size_t)e0 * EDIM, WeK3_s, WeK3_s + 8192, nullptr, nullptr,
                    epbig, EPCHUNK, EDIM, HCDIM, 0, 0, stream);
        logits_kernel<<<dim3((EPCHUNK * HEADS + 255) / 256), blk, 0, stream>>>(
            Qb, Kb, A2buf, c0buf, epbig, src, dst, logits, e0, EPCHUNK);
    }

    // ---- per-node softmax + aggregation; logits -> alpha ----
    node_attn_kernel<<<dim3(N_NODES / NODE_WAVES), blk, 0, stream>>>(
        Vb, edge_attr, logits, rowptr_i, eidx_i, src, Wve, bve, WeWv3, aggout);

    // ---- e_out = LN((alpha ⊙ (edge_attr@We)) @ Wfce + bfce) + edge_attr  (fully fused incl. LN) ----
    ffn2_fused<128, 64, 128, 64, 0, 1, 1><<<dim3(E_EDGES / 128), blk, 0, stream>>>(
        edge_attr, We_s, We_s + 8192, nullptr, Wfce_s, Wfce_s + 8192, bfce,
        logits, lne_g, lne_b, edge_attr, e_out, E_EDGES);

    // ---- node output path ----
    launch_mfma(aggout, Wfcn_s, Wfcn_s + 16384, bfcn, nullptr, x_out, N_NODES, HCDIM, DIM, 0, 0, stream);
    ln_res_kernel<<<dim3(12500), blk, 0, stream>>>(x_out, lnn_g, lnn_b, x, N_NODES, DIM);

    // ---- node FFN (fused W1n+gelu+W2n) + BN + residual + softplus ----
    ffn2_fused<64, 128, 512, 128, 1, 0, 0><<<dim3((N_NODES + 63) / 64), blk, 0, stream>>>(
        x_out, W1n_s, W1n_s + 65536, b1n, W2n_s, W2n_s + 65536, b2n,
        nullptr, nullptr, nullptr, nullptr, y_n, N_NODES);
    bn_stats_kernel<<<dim3(256), blk, 0, stream>>>(y_n, colsum_n, colsq_n, N_NODES, DIM);
    {
        int n = N_NODES * DIM;
        bn_apply_softplus_kernel<<<dim3((n + 255) / 256), blk, 0, stream>>>(
            y_n, x_out, colsum_n, colsq_n, bnn_g, bnn_b, (float*)d_out, N_NODES, DIM);
    }

    // ---- edge FFN (fused W1e+gelu+W2e) ----
    ffn2_fused<128, 64, 256, 64, 1, 0, 0><<<dim3(E_EDGES / 128), blk, 0, stream>>>(
        e_out, W1e_s, W1e_s + 16384, b1e, W2e_s, W2e_s + 16384, b2e,
        nullptr, nullptr, nullptr, nullptr, y_e, E_EDGES);
    bn_stats_kernel<<<dim3(256), blk, 0, stream>>>(y_e, colsum_e, colsq_e, E_EDGES, EDIM);
    {
        int n = E_EDGES * EDIM;
        bn_apply_softplus_kernel<<<dim3((n + 255) / 256), blk, 0, stream>>>(
            y_e, e_out, colsum_e, colsq_e, bne_g, bne_b, (float*)d_out + (size_t)N_NODES * DIM, E_EDGES, EDIM);
    }
}

// Round 6
// 2043.054 us; speedup vs baseline: 1.2966x; 1.0678x over previous
//
#include <hip/hip_runtime.h>
#include <math.h>
#include <stdint.h>

#define N_NODES 50000
#define E_EDGES 400000
#define DIM 128
#define HEADS 8
#define CH 16
#define EDIM 64
#define HCDIM 128   // HEADS*CH

#define EPCHUNK 100000   // edge chunk for eproj/logits loop (4 chunks)
#define NODE_WAVES 4

using bf16x8 = __attribute__((ext_vector_type(8))) short;
using f32x4v = __attribute__((ext_vector_type(4))) float;

// ---------------- utility ----------------

__global__ void fill_kernel(float* p, float v, int n) {
    int i = blockIdx.x * blockDim.x + threadIdx.x;
    if (i < n) p[i] = v;
}

__global__ void concat3_kernel(const float* __restrict__ a, const float* __restrict__ b,
                               const float* __restrict__ c, float* __restrict__ o) {
    int i = blockIdx.x * 256 + threadIdx.x;
    if (i < 128) o[i] = a[i];
    else if (i < 256) o[i] = b[i - 128];
    else if (i < 384) o[i] = c[i - 256];
}

__device__ inline float gelu_f(float x) {
    return 0.5f * x * (1.0f + erff(x * 0.70710678118654752f));
}

__device__ inline float softplus_f(float x) {
    return x > 20.f ? x : log1pf(expf(x));
}

__device__ inline unsigned short f32_to_bf16_rn(float f) {
    unsigned u = __float_as_uint(f);
    u += 0x7FFFu + ((u >> 16) & 1u);
    return (unsigned short)(u >> 16);
}
__device__ inline float bf16_to_f32(unsigned short h) {
    return __uint_as_float((unsigned)h << 16);
}

// ---------------- weight pre-transpose + bf16 split ----------------
// in: W (KxN f32, row-major). out: hi/lo bf16 planes, [n][k] layout.
__global__ __launch_bounds__(256) void wsplit_kernel(
    const float* __restrict__ W, unsigned short* __restrict__ hi,
    unsigned short* __restrict__ lo, int K, int N)
{
    int idx = blockIdx.x * 256 + threadIdx.x;
    if (idx >= K * N) return;
    int n = idx / K, k = idx - n * K;
    float x = W[(size_t)k * N + n];
    unsigned short h = f32_to_bf16_rn(x);
    hi[idx] = h;
    lo[idx] = f32_to_bf16_rn(x - bf16_to_f32(h));
}

// Same, but k-slots permuted within each 32-block to match the packed-hidden
// fragment layout of ffn2_nobar's GEMM2: slot s holds source k = base + pi(s),
// pi(s): lg=s>>3, j=s&7 -> (j<4 ? lg*4+j : 16+lg*4+(j-4))  (bijection on [0,32)).
__global__ __launch_bounds__(256) void wsplit_perm_kernel(
    const float* __restrict__ W, unsigned short* __restrict__ hi,
    unsigned short* __restrict__ lo, int K, int N)
{
    int idx = blockIdx.x * 256 + threadIdx.x;
    if (idx >= K * N) return;
    int n = idx / K, k = idx - n * K;
    int s = k & 31, base = k & ~31;
    int lgp = s >> 3, j = s & 7;
    int ksrc = base + ((j < 4) ? (lgp * 4 + j) : (16 + lgp * 4 + (j - 4)));
    float x = W[(size_t)ksrc * N + n];
    unsigned short h = f32_to_bf16_rn(x);
    hi[idx] = h;
    lo[idx] = f32_to_bf16_rn(x - bf16_to_f32(h));
}

// ---------------- MFMA GEMM (single): C = act(A @ W + bias) ----------------
template<int BN>
__global__ __launch_bounds__(256) void gemm_mfma(
    const float* __restrict__ A,
    const unsigned short* __restrict__ Whi, const unsigned short* __restrict__ Wlo,
    const float* __restrict__ bias, const float* __restrict__ ascale,
    float* __restrict__ C, int M, int K, int Nc, int act, int cmode)
{
    constexpr int MT = (BN == 128) ? 4 : 2;
    __shared__ bf16x8 As[2][4][128];   // [plane hi/lo][k-granule][row], 16 KB

    const int tid = threadIdx.x;
    const int w = tid >> 6, lane = tid & 63;
    const int l15 = lane & 15, lg = lane >> 4;
    const int m0 = blockIdx.y * 128;
    const int n0 = blockIdx.x * BN;
    const int rowbase = (BN == 128) ? (w >> 1) * 64 : w * 32;
    const int colbase = (BN == 128) ? (w & 1) * 64 : 0;
    const int k16 = K >> 4;

    f32x4v acc[MT][4];
#pragma unroll
    for (int i = 0; i < MT; ++i)
#pragma unroll
        for (int j = 0; j < 4; ++j)
#pragma unroll
            for (int cidx = 0; cidx < 4; ++cidx) acc[i][j][cidx] = 0.f;

    for (int k0 = 0; k0 < K; k0 += 32) {
#pragma unroll
        for (int it = 0; it < 2; ++it) {
            int row = w * 16 + l15 + it * 64;
            int ar = m0 + row;
            float v[8];
            if (ar < M) {
                const float* ap = A + (size_t)ar * K + k0 + lg * 8;
                *(float4*)&v[0] = *(const float4*)ap;
                *(float4*)&v[4] = *(const float4*)(ap + 4);
                if (ascale) {
                    float s = ascale[(size_t)ar * k16 + ((k0 >> 4) + (lg >> 1))];
#pragma unroll
                    for (int j = 0; j < 8; ++j) v[j] *= s;
                }
            } else {
#pragma unroll
                for (int j = 0; j < 8; ++j) v[j] = 0.f;
            }
            bf16x8 gh, gl;
#pragma unroll
            for (int j = 0; j < 8; ++j) {
                unsigned short h = f32_to_bf16_rn(v[j]);
                gh[j] = (short)h;
                gl[j] = (short)f32_to_bf16_rn(v[j] - bf16_to_f32(h));
            }
            As[0][lg][row] = gh;
            As[1][lg][row] = gl;
        }
        bf16x8 bh[4], bl[4];
#pragma unroll
        for (int nt = 0; nt < 4; ++nt) {
            size_t off = (size_t)(n0 + colbase + nt * 16 + l15) * K + k0 + lg * 8;
            bh[nt] = *(const bf16x8*)(Whi + off);
            bl[nt] = *(const bf16x8*)(Wlo + off);
        }
        __syncthreads();
#pragma unroll
        for (int mt = 0; mt < MT; ++mt) {
            int arow = rowbase + mt * 16 + l15;
            bf16x8 ah = As[0][lg][arow];
            bf16x8 al = As[1][lg][arow];
#pragma unroll
            for (int nt = 0; nt < 4; ++nt) {
                acc[mt][nt] = __builtin_amdgcn_mfma_f32_16x16x32_bf16(ah, bh[nt], acc[mt][nt], 0, 0, 0);
                acc[mt][nt] = __builtin_amdgcn_mfma_f32_16x16x32_bf16(al, bh[nt], acc[mt][nt], 0, 0, 0);
                acc[mt][nt] = __builtin_amdgcn_mfma_f32_16x16x32_bf16(ah, bl[nt], acc[mt][nt], 0, 0, 0);
            }
        }
        __syncthreads();
    }

#pragma unroll
    for (int nt = 0; nt < 4; ++nt) {
        int col = n0 + colbase + nt * 16 + l15;
        float bb = bias ? bias[col] : 0.f;
#pragma unroll
        for (int mt = 0; mt < MT; ++mt) {
#pragma unroll
            for (int i = 0; i < 4; ++i) {
                int r = m0 + rowbase + mt * 16 + lg * 4 + i;
                if (r < M) {
                    float o = acc[mt][nt][i] + bb;
                    if (act == 1) o = gelu_f(o);
                    if (cmode == 1) {
                        C[(size_t)(col >> 7) * ((size_t)N_NODES * HCDIM) + (size_t)r * HCDIM + (col & 127)] = o;
                    } else {
                        C[(size_t)r * Nc + col] = o;
                    }
                }
            }
        }
    }
}

static inline void launch_mfma(const float* A, const unsigned short* Whi, const unsigned short* Wlo,
                               const float* bias, const float* ascale, float* C,
                               int M, int K, int Nc, int act, int cmode, hipStream_t stream)
{
    int gy = (M + 127) / 128;
    if (Nc % 128 == 0)
        gemm_mfma<128><<<dim3(Nc / 128, gy), dim3(256), 0, stream>>>(A, Whi, Wlo, bias, ascale, C, M, K, Nc, act, cmode);
    else
        gemm_mfma<64><<<dim3(Nc / 64, gy), dim3(256), 0, stream>>>(A, Whi, Wlo, bias, ascale, C, M, K, Nc, act, cmode);
}

// ---------------- barrier-free fused double GEMM ----------------
// out = (act(A@W1 + b1) [* ascale]) @ W2 + b2  [+ LN+resid]
// GEMM1 swapped: mfma16x16x32(W1^T-frag, A-frag) -> lane holds h[r = row0+mt*16+l15]
// [hidden col = it*16 + lg*4 + i]. Two consecutive subtiles pack into one bf16x8
// (slots j<4 = even subtile, j>=4 = odd subtile), a valid 16x16x32 B-operand under
// the pi() k-permutation baked into W2 (wsplit_perm). GEMM2 consumes hidden straight
// from registers: NO LDS, NO barriers, waves fully independent.
// ascale: hidden col n scaled by ascale[row*(NH/16) + n/16].
// LN2 (N2==64): fused LayerNorm+residual epilogue (row over 4 lanes; shfl_xor 16/32).
template<int MT, int K1, int NH, int N2, int ACT1, int ASC, int LN2>
__global__ __launch_bounds__(256) void ffn2_nobar(
    const float* __restrict__ A,
    const unsigned short* __restrict__ W1hi, const unsigned short* __restrict__ W1lo,
    const float* __restrict__ b1,
    const unsigned short* __restrict__ W2hi, const unsigned short* __restrict__ W2lo,
    const float* __restrict__ b2,
    const float* __restrict__ ascale,
    const float* __restrict__ lng, const float* __restrict__ lnb,
    const float* __restrict__ resid,
    float* __restrict__ Cout, int M)
{
    constexpr int NK = K1 / 32;    // GEMM1 k-steps
    constexpr int NT2 = N2 / 16;   // output col tiles
    constexpr int NI = NH / 16;    // hidden subtiles
    constexpr int NP = NH / 32;    // hidden subtile pairs (= GEMM2 k-steps)
    const int tid = threadIdx.x;
    const int w = tid >> 6, lane = tid & 63;
    const int l15 = lane & 15, lg = lane >> 4;
    const int row0 = (blockIdx.x * 4 + w) * (MT * 16);

    // ---- A fragments in registers: row=row0+mt*16+l15, k=ks*32+lg*8+j ----
    bf16x8 aAh[MT][NK], aAl[MT][NK];
#pragma unroll
    for (int mt = 0; mt < MT; ++mt) {
        int r = row0 + mt * 16 + l15;
#pragma unroll
        for (int ks = 0; ks < NK; ++ks) {
            float v[8];
            if (r < M) {
                const float* ap = A + (size_t)r * K1 + ks * 32 + lg * 8;
                *(float4*)&v[0] = *(const float4*)ap;
                *(float4*)&v[4] = *(const float4*)(ap + 4);
            } else {
#pragma unroll
                for (int j = 0; j < 8; ++j) v[j] = 0.f;
            }
            bf16x8 gh, gl;
#pragma unroll
            for (int j = 0; j < 8; ++j) {
                unsigned short h = f32_to_bf16_rn(v[j]);
                gh[j] = (short)h;
                gl[j] = (short)f32_to_bf16_rn(v[j] - bf16_to_f32(h));
            }
            aAh[mt][ks] = gh;
            aAl[mt][ks] = gl;
        }
    }

    f32x4v oacc[MT][NT2];
#pragma unroll
    for (int mt = 0; mt < MT; ++mt)
#pragma unroll
        for (int nt = 0; nt < NT2; ++nt)
#pragma unroll
            for (int c = 0; c < 4; ++c) oacc[mt][nt][c] = 0.f;

    for (int p = 0; p < NP; ++p) {
        bf16x8 hh[MT], hl[MT];
#pragma unroll
        for (int half = 0; half < 2; ++half) {
            const int it = p * 2 + half;
            // ---- GEMM1 subtile: h^T = W1^T-rows(it*16..+15) x A^T ----
            f32x4v h[MT];
#pragma unroll
            for (int mt = 0; mt < MT; ++mt)
#pragma unroll
                for (int c = 0; c < 4; ++c) h[mt][c] = 0.f;
#pragma unroll
            for (int ks = 0; ks < NK; ++ks) {
                size_t off = (size_t)(it * 16 + l15) * K1 + ks * 32 + lg * 8;
                bf16x8 xh = *(const bf16x8*)(W1hi + off);
                bf16x8 xl = *(const bf16x8*)(W1lo + off);
#pragma unroll
                for (int mt = 0; mt < MT; ++mt) {
                    h[mt] = __builtin_amdgcn_mfma_f32_16x16x32_bf16(xh, aAh[mt][ks], h[mt], 0, 0, 0);
                    h[mt] = __builtin_amdgcn_mfma_f32_16x16x32_bf16(xl, aAh[mt][ks], h[mt], 0, 0, 0);
                    h[mt] = __builtin_amdgcn_mfma_f32_16x16x32_bf16(xh, aAl[mt][ks], h[mt], 0, 0, 0);
                }
            }
            // ---- bias/act/scale + bf16 split into packed slots ----
            float b1a[4] = {0.f, 0.f, 0.f, 0.f};
            if (b1) *(float4*)b1a = *(const float4*)(b1 + it * 16 + lg * 4);
#pragma unroll
            for (int mt = 0; mt < MT; ++mt) {
                float sc = 1.f;
                if (ASC) {
                    int r = row0 + mt * 16 + l15;
                    sc = (r < M) ? ascale[(size_t)r * NI + it] : 0.f;
                }
#pragma unroll
                for (int i = 0; i < 4; ++i) {
                    float o = h[mt][i] + b1a[i];
                    if (ACT1) o = gelu_f(o);
                    if (ASC) o *= sc;
                    unsigned short oh = f32_to_bf16_rn(o);
                    hh[mt][half * 4 + i] = (short)oh;
                    hl[mt][half * 4 + i] = (short)f32_to_bf16_rn(o - bf16_to_f32(oh));
                }
            }
        }
        // ---- GEMM2 k-step (K=32, permuted W2): consume h from registers ----
#pragma unroll
        for (int nt2 = 0; nt2 < NT2; ++nt2) {
            size_t off2 = (size_t)(nt2 * 16 + l15) * NH + p * 32 + lg * 8;
            bf16x8 x2h = *(const bf16x8*)(W2hi + off2);
            bf16x8 x2l = *(const bf16x8*)(W2lo + off2);
#pragma unroll
            for (int mt = 0; mt < MT; ++mt) {
                oacc[mt][nt2] = __builtin_amdgcn_mfma_f32_16x16x32_bf16(x2h, hh[mt], oacc[mt][nt2], 0, 0, 0);
                oacc[mt][nt2] = __builtin_amdgcn_mfma_f32_16x16x32_bf16(x2l, hh[mt], oacc[mt][nt2], 0, 0, 0);
                oacc[mt][nt2] = __builtin_amdgcn_mfma_f32_16x16x32_bf16(x2h, hl[mt], oacc[mt][nt2], 0, 0, 0);
            }
        }
    }

    // ---- epilogue: lane holds y[m = row0+mt*16+l15][n2 = nt2*16+lg*4+reg] ----
    float b2a[NT2][4];
#pragma unroll
    for (int nt2 = 0; nt2 < NT2; ++nt2) {
        if (b2) *(float4*)b2a[nt2] = *(const float4*)(b2 + nt2 * 16 + lg * 4);
        else { b2a[nt2][0] = 0.f; b2a[nt2][1] = 0.f; b2a[nt2][2] = 0.f; b2a[nt2][3] = 0.f; }
    }
    if (LN2) {
        float ga[NT2][4], bba[NT2][4];
#pragma unroll
        for (int nt2 = 0; nt2 < NT2; ++nt2) {
            *(float4*)ga[nt2] = *(const float4*)(lng + nt2 * 16 + lg * 4);
            *(float4*)bba[nt2] = *(const float4*)(lnb + nt2 * 16 + lg * 4);
        }
#pragma unroll
        for (int mt = 0; mt < MT; ++mt) {
            int r = row0 + mt * 16 + l15;
            float o[NT2][4];
            float s = 0.f;
#pragma unroll
            for (int nt2 = 0; nt2 < NT2; ++nt2)
#pragma unroll
                for (int i = 0; i < 4; ++i) { o[nt2][i] = oacc[mt][nt2][i] + b2a[nt2][i]; s += o[nt2][i]; }
            s += __shfl_xor(s, 16); s += __shfl_xor(s, 32);
            float mean = s * (1.f / (float)N2);
            float q = 0.f;
#pragma unroll
            for (int nt2 = 0; nt2 < NT2; ++nt2)
#pragma unroll
                for (int i = 0; i < 4; ++i) { o[nt2][i] -= mean; q += o[nt2][i] * o[nt2][i]; }
            q += __shfl_xor(q, 16); q += __shfl_xor(q, 32);
            float inv = rsqrtf(q * (1.f / (float)N2) + 1e-5f);
            if (r < M) {
#pragma unroll
                for (int nt2 = 0; nt2 < NT2; ++nt2) {
                    float4 rv = *(const float4*)(resid + (size_t)r * N2 + nt2 * 16 + lg * 4);
                    float4 ov;
                    ov.x = o[nt2][0] * inv * ga[nt2][0] + bba[nt2][0] + rv.x;
                    ov.y = o[nt2][1] * inv * ga[nt2][1] + bba[nt2][1] + rv.y;
                    ov.z = o[nt2][2] * inv * ga[nt2][2] + bba[nt2][2] + rv.z;
                    ov.w = o[nt2][3] * inv * ga[nt2][3] + bba[nt2][3] + rv.w;
                    *(float4*)(Cout + (size_t)r * N2 + nt2 * 16 + lg * 4) = ov;
                }
            }
        }
    } else {
#pragma unroll
        for (int mt = 0; mt < MT; ++mt) {
            int r = row0 + mt * 16 + l15;
            if (r < M) {
#pragma unroll
                for (int nt2 = 0; nt2 < NT2; ++nt2) {
                    float4 ov;
                    ov.x = oacc[mt][nt2][0] + b2a[nt2][0];
                    ov.y = oacc[mt][nt2][1] + b2a[nt2][1];
                    ov.z = oacc[mt][nt2][2] + b2a[nt2][2];
                    ov.w = oacc[mt][nt2][3] + b2a[nt2][3];
                    *(float4*)(Cout + (size_t)r * N2 + nt2 * 16 + lg * 4) = ov;
                }
            }
        }
    }
}

// ---------------- precompute: WeX[k][h*16+j] = sum_c We[k][h*16+c] * X[c][j] ----------------
__global__ __launch_bounds__(256) void wex_kernel(
    const float* __restrict__ We, const float* __restrict__ X, float* __restrict__ out)
{
    int idx = blockIdx.x * 256 + threadIdx.x;
    if (idx >= 64 * 128) return;
    int k = idx >> 7, hj = idx & 127, h = hj >> 4, j = hj & 15;
    float s = 0.f;
#pragma unroll
    for (int c = 0; c < 16; ++c) s += We[k * 128 + h * 16 + c] * X[c * 16 + j];
    out[idx] = s;
}

// ---------------- precompute per (d,h): c0 = Q·(K@Wk1 + bke); A2[c] = sum_j Wk2[c][j]*Q[j] ----------------
__global__ __launch_bounds__(256) void qk_pre_kernel(
    const float* __restrict__ Q, const float* __restrict__ K,
    const float* __restrict__ Wke, const float* __restrict__ bke,
    float* __restrict__ A2, float* __restrict__ c0)
{
    __shared__ float wk1[256], wk2[256], bks[16];
    for (int i = threadIdx.x; i < 256; i += 256) { wk1[i] = Wke[i]; wk2[i] = Wke[256 + i]; }
    if (threadIdx.x < 16) bks[threadIdx.x] = bke[threadIdx.x];
    __syncthreads();
    int idx = blockIdx.x * 256 + threadIdx.x;   // idx = ((d*8 + h)*16 + j)
    int j = idx & 15; int dh = idx >> 4; int h = dh & 7; int d = dh >> 3;
    if (d >= N_NODES) return;
    const float* q = Q + (size_t)d * HCDIM + h * CH;
    const float* k = K + (size_t)d * HCDIM + h * CH;
    float qv[16], kv[16];
#pragma unroll
    for (int t = 0; t < 4; ++t) {
        *(float4*)&qv[t * 4] = *(const float4*)(q + t * 4);
        *(float4*)&kv[t * 4] = *(const float4*)(k + t * 4);
    }
    float a2 = 0.f;
#pragma unroll
    for (int t = 0; t < 16; ++t) a2 += wk2[j * 16 + t] * qv[t];
    A2[idx] = a2;
    float kn = bks[j];
#pragma unroll
    for (int c = 0; c < 16; ++c) kn += kv[c] * wk1[c * 16 + j];
    float t = qv[j] * kn;
    t += __shfl_xor(t, 1); t += __shfl_xor(t, 2); t += __shfl_xor(t, 4); t += __shfl_xor(t, 8);
    if (j == 0) c0[dh] = t;
}

// ---------------- logits (chunked) ----------------
__global__ __launch_bounds__(256) void logits_kernel(
    const float* __restrict__ Q, const float* __restrict__ K,
    const float* __restrict__ A2, const float* __restrict__ c0,
    const float* __restrict__ ep3,
    const int* __restrict__ src, const int* __restrict__ dst,
    float* __restrict__ logits, int e0, int ecnt)
{
    int idx = blockIdx.x * 256 + threadIdx.x;
    if (idx >= ecnt * HEADS) return;
    int el = idx >> 3, h = idx & 7, e = e0 + el;
    int s = src[e], d = dst[e];
    const float* q  = Q  + (size_t)d * HCDIM + h * CH;
    const float* a2 = A2 + (size_t)d * HCDIM + h * CH;
    const float* ks = K  + (size_t)s * HCDIM + h * CH;
    const float* ep = ep3 + (size_t)el * HCDIM + h * CH;
    float acc = c0[(size_t)d * HEADS + h];
    float qv[16], av[16], kv[16], ev[16];
#pragma unroll
    for (int t = 0; t < 4; ++t) {
        *(float4*)&qv[t * 4] = *(const float4*)(q + t * 4);
        *(float4*)&av[t * 4] = *(const float4*)(a2 + t * 4);
        *(float4*)&kv[t * 4] = *(const float4*)(ks + t * 4);
        *(float4*)&ev[t * 4] = *(const float4*)(ep + t * 4);
    }
#pragma unroll
    for (int t = 0; t < 16; ++t) acc += av[t] * kv[t] + qv[t] * ev[t];
    logits[(size_t)e * HEADS + h] = acc * 0.25f;
}

// ---------------- CSR build ----------------
__global__ __launch_bounds__(256) void count_kernel(const int* __restrict__ dst, int* __restrict__ cnt) {
    int e = blockIdx.x * 256 + threadIdx.x;
    if (e < E_EDGES) atomicAdd(&cnt[dst[e]], 1);
}

__global__ __launch_bounds__(1024) void scan_kernel(
    const int* __restrict__ cnt, int* __restrict__ rowptr, int* __restrict__ cursor, int n)
{
    __shared__ int buf[1024];
    __shared__ int base;
    int tid = threadIdx.x;
    if (tid == 0) { base = 0; rowptr[0] = 0; }
    __syncthreads();
    for (int t0 = 0; t0 < n; t0 += 1024) {
        int i = t0 + tid;
        int v = (i < n) ? cnt[i] : 0;
        buf[tid] = v;
        __syncthreads();
        for (int off = 1; off < 1024; off <<= 1) {
            int add = (tid >= off) ? buf[tid - off] : 0;
            __syncthreads();
            buf[tid] += add;
            __syncthreads();
        }
        if (i < n) { rowptr[i + 1] = base + buf[tid]; cursor[i] = base + buf[tid] - v; }
        __syncthreads();
        if (tid == 0) base += buf[1023];
        __syncthreads();
    }
}

__global__ __launch_bounds__(256) void scatter_kernel(
    const int* __restrict__ dst, int* __restrict__ cursor, int* __restrict__ eidx) {
    int e = blockIdx.x * 256 + threadIdx.x;
    if (e < E_EDGES) {
        int p = atomicAdd(&cursor[dst[e]], 1);
        eidx[p] = e;
    }
}

// ---------------- per-node attention ----------------
__global__ __launch_bounds__(256) void node_attn_kernel(
    const float* __restrict__ Vb, const float* __restrict__ edge_attr,
    float* __restrict__ logits,
    const int* __restrict__ rowptr, const int* __restrict__ eidx,
    const int* __restrict__ src,
    const float* __restrict__ Wve, const float* __restrict__ bve,
    const float* __restrict__ WeWv3, float* __restrict__ aggout)
{
    __shared__ float wv1s[256], wv2s[256], bvs[16];
    __shared__ float stage[NODE_WAVES][640];

    for (int i = threadIdx.x; i < 256; i += 256) { wv1s[i] = Wve[i]; wv2s[i] = Wve[256 + i]; }
    if (threadIdx.x < 16) bvs[threadIdx.x] = bve[threadIdx.x];
    __syncthreads();

    int w = threadIdx.x >> 6, lane = threadIdx.x & 63;
    int d = blockIdx.x * NODE_WAVES + w;
    int r0 = rowptr[d], r1 = rowptr[d + 1], deg = r1 - r0;
    int h = lane >> 3, kg = lane & 7;

    if (deg == 0) {
        aggout[(size_t)d * HCDIM + lane] = 0.f;
        aggout[(size_t)d * HCDIM + 64 + lane] = 0.f;
    } else {
        float m[8], ssum[8];
#pragma unroll
        for (int t = 0; t < 8; ++t) { m[t] = -INFINITY; ssum[t] = 0.f; }
        for (int i = r0 + lane; i < r1; i += 64) {
            int e = eidx[i];
            const float* lp = logits + (size_t)e * HEADS;
            float l[8];
            *(float4*)&l[0] = *(const float4*)lp;
            *(float4*)&l[4] = *(const float4*)(lp + 4);
#pragma unroll
            for (int t = 0; t < 8; ++t) m[t] = fmaxf(m[t], l[t]);
        }
#pragma unroll
        for (int o = 1; o < 64; o <<= 1) {
#pragma unroll
            for (int t = 0; t < 8; ++t) m[t] = fmaxf(m[t], __shfl_xor(m[t], o));
        }
        for (int i = r0 + lane; i < r1; i += 64) {
            int e = eidx[i];
            const float* lp = logits + (size_t)e * HEADS;
            float l[8];
            *(float4*)&l[0] = *(const float4*)lp;
            *(float4*)&l[4] = *(const float4*)(lp + 4);
#pragma unroll
            for (int t = 0; t < 8; ++t) ssum[t] += expf(l[t] - m[t]);
        }
#pragma unroll
        for (int o = 1; o < 64; o <<= 1) {
#pragma unroll
            for (int t = 0; t < 8; ++t) ssum[t] += __shfl_xor(ssum[t], o);
        }
        float mh = m[0], dd = ssum[0];
#pragma unroll
        for (int t = 1; t < 8; ++t) { if (h == t) { mh = m[t]; dd = ssum[t]; } }
        float den = dd + 1e-16f;

        float wea[8] = {0.f, 0.f, 0.f, 0.f, 0.f, 0.f, 0.f, 0.f};
        float av0 = 0.f, av1 = 0.f;
        for (int i = r0; i < r1; ++i) {
            int e = eidx[i];
            float lg = logits[(size_t)e * HEADS + h];
            float alpha = expf(lg - mh) / den;
            if (kg == 0) logits[(size_t)e * HEADS + h] = alpha;
            int s = src[e];
            const float* ea = edge_attr + (size_t)e * EDIM + kg * 8;
            float ev[8];
            *(float4*)&ev[0] = *(const float4*)ea;
            *(float4*)&ev[4] = *(const float4*)(ea + 4);
#pragma unroll
            for (int t = 0; t < 8; ++t) wea[t] += alpha * ev[t];
            float2 vv = *(const float2*)(Vb + (size_t)s * HCDIM + h * CH + kg * 2);
            av0 += alpha * vv.x;
            av1 += alpha * vv.y;
        }
        float* st = stage[w];
#pragma unroll
        for (int t = 0; t < 8; ++t) st[h * 64 + kg * 8 + t] = wea[t];
        st[512 + h * 16 + kg * 2] = av0;
        st[512 + h * 16 + kg * 2 + 1] = av1;
    }
    __syncthreads();
    if (deg > 0) {
        float* st = stage[w];
        int c0i = kg * 2;
        float acc0 = bvs[c0i], acc1 = bvs[c0i + 1];
        const float* vd = Vb + (size_t)d * HCDIM + h * CH;
#pragma unroll
        for (int j = 0; j < 16; ++j) {
            float vj = vd[j];
            float a = st[512 + h * 16 + j];
            acc0 += vj * wv1s[j * 16 + c0i] + a * wv2s[j * 16 + c0i];
            acc1 += vj * wv1s[j * 16 + c0i + 1] + a * wv2s[j * 16 + c0i + 1];
        }
        const float* w3 = WeWv3 + h * 16 + c0i;
#pragma unroll 16
        for (int k = 0; k < 64; ++k) {
            float wv = st[h * 64 + k];
            float2 w2v = *(const float2*)(w3 + k * 128);
            acc0 += wv * w2v.x;
            acc1 += wv * w2v.y;
        }
        aggout[(size_t)d * HCDIM + h * CH + c0i] = acc0;
        aggout[(size_t)d * HCDIM + h * CH + c0i + 1] = acc1;
    }
}

// ---------------- layernorm (+ residual) ----------------
__global__ __launch_bounds__(256) void ln_res_kernel(
    float* __restrict__ y, const float* __restrict__ g, const float* __restrict__ b,
    const float* __restrict__ res, int rows, int w)
{
    int wave = threadIdx.x >> 6;
    int lane = threadIdx.x & 63;
    int nw = blockDim.x >> 6;
    for (int r = blockIdx.x * nw + wave; r < rows; r += gridDim.x * nw) {
        size_t base = (size_t)r * w;
        float v0 = y[base + lane];
        float v1 = (w == 128) ? y[base + 64 + lane] : 0.f;
        float s = v0 + v1;
#pragma unroll
        for (int o = 32; o; o >>= 1) s += __shfl_xor(s, o);
        float m = s / (float)w;
        float d0 = v0 - m;
        float d1 = (w == 128) ? (v1 - m) : 0.f;
        float q = d0 * d0 + d1 * d1;
#pragma unroll
        for (int o = 32; o; o >>= 1) q += __shfl_xor(q, o);
        float inv = rsqrtf(q / (float)w + 1e-5f);
        y[base + lane] = d0 * inv * g[lane] + b[lane] + res[base + lane];
        if (w == 128)
            y[base + 64 + lane] = d1 * inv * g[64 + lane] + b[64 + lane] + res[base + 64 + lane];
    }
}

// ---------------- batchnorm stats ----------------
__global__ __launch_bounds__(256) void bn_stats_kernel(
    const float* __restrict__ y, float* __restrict__ colsum, float* __restrict__ colsq,
    int rows, int cols)
{
    __shared__ float ss[256], sq[256];
    int tid = threadIdx.x;
    int col = tid % cols;
    int rsub = tid / cols;
    int rstep = blockDim.x / cols;
    float ls = 0.f, lq = 0.f;
    for (int r = blockIdx.x * rstep + rsub; r < rows; r += gridDim.x * rstep) {
        float v = y[(size_t)r * cols + col];
        ls += v;
        lq += v * v;
    }
    ss[tid] = ls;
    sq[tid] = lq;
    __syncthreads();
    if (tid < cols) {
        for (int o = cols; o < 256; o += cols) { ls += ss[tid + o]; lq += sq[tid + o]; }
        atomicAdd(&colsum[tid], ls);
        atomicAdd(&colsq[tid], lq);
    }
}

// ---------------- batchnorm apply + residual + softplus ----------------
__global__ __launch_bounds__(256) void bn_apply_softplus_kernel(
    const float* __restrict__ y, const float* __restrict__ res,
    const float* __restrict__ colsum, const float* __restrict__ colsq,
    const float* __restrict__ g, const float* __restrict__ b,
    float* __restrict__ out, int rows, int cols)
{
    int idx = blockIdx.x * blockDim.x + threadIdx.x;
    int n = rows * cols;
    if (idx >= n) return;
    int c = idx % cols;
    float m = colsum[c] / (float)rows;
    float var = colsq[c] / (float)rows - m * m;
    float inv = rsqrtf(var + 1e-5f);
    float v = (y[idx] - m) * inv * g[c] + b[c] + res[idx];
    out[idx] = softplus_f(v);
}

// ---------------- launcher ----------------

extern "C" void kernel_launch(void* const* d_in, const int* in_sizes, int n_in,
                              void* d_out, int out_size, void* d_ws, size_t ws_size,
                              hipStream_t stream) {
    const float* x         = (const float*)d_in[0];
    const int*   ei        = (const int*)d_in[1];
    const float* edge_attr = (const float*)d_in[2];
    const float* Wq  = (const float*)d_in[3];
    const float* bq  = (const float*)d_in[4];
    const float* Wk  = (const float*)d_in[5];
    const float* bk  = (const float*)d_in[6];
    const float* Wv  = (const float*)d_in[7];
    const float* bv  = (const float*)d_in[8];
    const float* We  = (const float*)d_in[9];
    const float* Wke = (const float*)d_in[10];
    const float* bke = (const float*)d_in[11];
    const float* Wve = (const float*)d_in[12];
    const float* bve = (const float*)d_in[13];
    const float* Wfce = (const float*)d_in[14];
    const float* bfce = (const float*)d_in[15];
    const float* lne_g = (const float*)d_in[16];
    const float* lne_b = (const float*)d_in[17];
    const float* Wfcn = (const float*)d_in[18];
    const float* bfcn = (const float*)d_in[19];
    const float* lnn_g = (const float*)d_in[20];
    const float* lnn_b = (const float*)d_in[21];
    const float* W1n = (const float*)d_in[22];
    const float* b1n = (const float*)d_in[23];
    const float* W2n = (const float*)d_in[24];
    const float* b2n = (const float*)d_in[25];
    const float* W1e = (const float*)d_in[26];
    const float* b1e = (const float*)d_in[27];
    const float* W2e = (const float*)d_in[28];
    const float* b2e = (const float*)d_in[29];
    const float* bnn_g = (const float*)d_in[30];
    const float* bnn_b = (const float*)d_in[31];
    const float* bne_g = (const float*)d_in[32];
    const float* bne_b = (const float*)d_in[33];

    const int* src = ei;
    const int* dst = ei + E_EDGES;

    float* ws = (float*)d_ws;
    const size_t M64   = (size_t)E_EDGES * EDIM;       // 25.6M
    const size_t NODE2 = (size_t)N_NODES * HCDIM;      // 6.4M

    // regionR [0, 25.6M): Qb|Kb|Vb
    float* regionR = ws;
    float* Qb  = regionR;
    float* Kb  = regionR + NODE2;
    float* Vb  = regionR + 2 * NODE2;

    // overlayY [25.6M, 51.2M): logits|c0|csr|aggout|y_n|x_out; later y_e
    float* overlayY = ws + M64;
    float* logits = overlayY;                                  // 3.2M (holds alpha later)
    float* c0buf  = logits + (size_t)E_EDGES * HEADS;          // 0.4M
    int*   cnt_i    = (int*)(c0buf + (size_t)N_NODES * HEADS); // 50000
    int*   rowptr_i = cnt_i + N_NODES;                         // 50001
    int*   cursor_i = rowptr_i + N_NODES + 1;                  // 50000
    int*   eidx_i   = cursor_i + N_NODES;                      // 400000
    float* aggout = (float*)(((uintptr_t)(eidx_i + E_EDGES) + 15) & ~(uintptr_t)15); // 6.4M
    float* y_n    = aggout + NODE2;                            // 6.4M
    float* x_out  = y_n + NODE2;                               // 6.4M
    float* y_e    = overlayY;                                  // 25.6M (late phase)
    float* epbig  = y_n;       // 12.8M scratch (EPCHUNK x 128) while y_n/x_out are dead

    // e_out region [51.2M, 76.8M): A2 parks at its start (dead before e_out written)
    float* e_out = ws + 2 * M64;
    float* A2buf = e_out;                                      // 6.4M, dead after logits

    // tail [76.8M, +)
    float* tail = ws + 3 * M64;
    float* colsum_n = tail;            // 128
    float* colsq_n  = tail + 128;      // 128
    float* colsum_e = tail + 256;      // 64
    float* colsq_e  = tail + 320;      // 64
    float* WeK3  = tail + 384;         // 8192
    float* WeWv3 = WeK3 + 8192;        // 8192
    float* bqkv  = WeWv3 + 8192;       // 384

    // split-weight arena (bf16 hi/lo planes, [n][k] layout), ~1 MB
    unsigned short* wsp = (unsigned short*)(bqkv + 384);
    unsigned short* QKV_s  = wsp;                     // [384][128] hi then lo (49152 each)
    unsigned short* WeK3_s = QKV_s  + 2 * 49152;      // K=64,N=128
    unsigned short* We_s   = WeK3_s + 2 * 8192;       // K=64,N=128
    unsigned short* Wfce_s = We_s   + 2 * 8192;       // K=128,N=64 (perm)
    unsigned short* Wfcn_s = Wfce_s + 2 * 8192;       // K=128,N=128
    unsigned short* W1n_s  = Wfcn_s + 2 * 16384;      // K=128,N=512
    unsigned short* W2n_s  = W1n_s  + 2 * 65536;      // K=512,N=128 (perm)
    unsigned short* W1e_s  = W2n_s  + 2 * 65536;      // K=64,N=256
    unsigned short* W2e_s  = W1e_s  + 2 * 16384;      // K=256,N=64 (perm)

    dim3 blk(256);

    // ---- init ----
    fill_kernel<<<dim3(2), blk, 0, stream>>>(colsum_n, 0.f, 384);
    fill_kernel<<<dim3((N_NODES + 255) / 256), blk, 0, stream>>>((float*)cnt_i, 0.f, N_NODES);

    // ---- folded weights ----
    wex_kernel<<<dim3(32), blk, 0, stream>>>(We, Wke + 2 * CH * CH, WeK3);
    wex_kernel<<<dim3(32), blk, 0, stream>>>(We, Wve + 2 * CH * CH, WeWv3);

    // ---- weight transpose + bf16 split (W2-matrices of fused kernels: permuted) ----
    wsplit_kernel<<<dim3(64), blk, 0, stream>>>(Wq, QKV_s,          QKV_s + 49152,          128, 128);
    wsplit_kernel<<<dim3(64), blk, 0, stream>>>(Wk, QKV_s + 16384,  QKV_s + 49152 + 16384,  128, 128);
    wsplit_kernel<<<dim3(64), blk, 0, stream>>>(Wv, QKV_s + 32768,  QKV_s + 49152 + 32768,  128, 128);
    wsplit_kernel<<<dim3(32), blk, 0, stream>>>(WeK3, WeK3_s, WeK3_s + 8192,  64, 128);
    wsplit_kernel<<<dim3(32), blk, 0, stream>>>(We,   We_s,   We_s + 8192,    64, 128);
    wsplit_perm_kernel<<<dim3(32), blk, 0, stream>>>(Wfce, Wfce_s, Wfce_s + 8192,  128, 64);
    wsplit_kernel<<<dim3(64), blk, 0, stream>>>(Wfcn, Wfcn_s, Wfcn_s + 16384, 128, 128);
    wsplit_kernel<<<dim3(256), blk, 0, stream>>>(W1n, W1n_s, W1n_s + 65536,   128, 512);
    wsplit_perm_kernel<<<dim3(256), blk, 0, stream>>>(W2n, W2n_s, W2n_s + 65536,   512, 128);
    wsplit_kernel<<<dim3(64), blk, 0, stream>>>(W1e, W1e_s, W1e_s + 16384,    64, 256);
    wsplit_perm_kernel<<<dim3(64), blk, 0, stream>>>(W2e, W2e_s, W2e_s + 16384,    256, 64);
    concat3_kernel<<<dim3(2), blk, 0, stream>>>(bq, bk, bv, bqkv);

    // ---- QKV projection (merged, N=384, split-output) ----
    launch_mfma(x, QKV_s, QKV_s + 49152, bqkv, nullptr, Qb, N_NODES, 128, 384, 0, 1, stream);

    // ---- per-node QK precompute ----
    qk_pre_kernel<<<dim3(N_NODES * HCDIM / 256), blk, 0, stream>>>(Qb, Kb, Wke, bke, A2buf, c0buf);

    // ---- CSR build ----
    count_kernel<<<dim3((E_EDGES + 255) / 256), blk, 0, stream>>>(dst, cnt_i);
    scan_kernel<<<dim3(1), dim3(1024), 0, stream>>>(cnt_i, rowptr_i, cursor_i, N_NODES);
    scatter_kernel<<<dim3((E_EDGES + 255) / 256), blk, 0, stream>>>(dst, cursor_i, eidx_i);

    // ---- logits per edge chunk (eproj3 = edge_attr @ WeK3) ----
    for (int e0 = 0; e0 < E_EDGES; e0 += EPCHUNK) {
        launch_mfma(edge_attr + (size_t)e0 * EDIM, WeK3_s, WeK3_s + 8192, nullptr, nullptr,
                    epbig, EPCHUNK, EDIM, HCDIM, 0, 0, stream);
        logits_kernel<<<dim3((EPCHUNK * HEADS + 255) / 256), blk, 0, stream>>>(
            Qb, Kb, A2buf, c0buf, epbig, src, dst, logits, e0, EPCHUNK);
    }

    // ---- per-node softmax + aggregation; logits -> alpha ----
    node_attn_kernel<<<dim3(N_NODES / NODE_WAVES), blk, 0, stream>>>(
        Vb, edge_attr, logits, rowptr_i, eidx_i, src, Wve, bve, WeWv3, aggout);

    // ---- e_out = LN((alpha ⊙ (edge_attr@We)) @ Wfce + bfce) + edge_attr  (barrier-free fused) ----
    ffn2_nobar<2, 64, 128, 64, 0, 1, 1><<<dim3(E_EDGES / 128), blk, 0, stream>>>(
        edge_attr, We_s, We_s + 8192, nullptr, Wfce_s, Wfce_s + 8192, bfce,
        logits, lne_g, lne_b, edge_attr, e_out, E_EDGES);

    // ---- node output path ----
    launch_mfma(aggout, Wfcn_s, Wfcn_s + 16384, bfcn, nullptr, x_out, N_NODES, HCDIM, DIM, 0, 0, stream);
    ln_res_kernel<<<dim3(12500), blk, 0, stream>>>(x_out, lnn_g, lnn_b, x, N_NODES, DIM);

    // ---- node FFN (barrier-free fused W1n+gelu+W2n) + BN + residual + softplus ----
    ffn2_nobar<1, 128, 512, 128, 1, 0, 0><<<dim3((N_NODES + 63) / 64), blk, 0, stream>>>(
        x_out, W1n_s, W1n_s + 65536, b1n, W2n_s, W2n_s + 65536, b2n,
        nullptr, nullptr, nullptr, nullptr, y_n, N_NODES);
    bn_stats_kernel<<<dim3(256), blk, 0, stream>>>(y_n, colsum_n, colsq_n, N_NODES, DIM);
    {
        int n = N_NODES * DIM;
        bn_apply_softplus_kernel<<<dim3((n + 255) / 256), blk, 0, stream>>>(
            y_n, x_out, colsum_n, colsq_n, bnn_g, bnn_b, (float*)d_out, N_NODES, DIM);
    }

    // ---- edge FFN (barrier-free fused W1e+gelu+W2e) ----
    ffn2_nobar<2, 64, 256, 64, 1, 0, 0><<<dim3(E_EDGES / 128), blk, 0, stream>>>(
        e_out, W1e_s, W1e_s + 16384, b1e, W2e_s, W2e_s + 16384, b2e,
        nullptr, nullptr, nullptr, nullptr, y_e, E_EDGES);
    bn_stats_kernel<<<dim3(256), blk, 0, stream>>>(y_e, colsum_e, colsq_e, E_EDGES, EDIM);
    {
        int n = E_EDGES * EDIM;
        bn_apply_softplus_kernel<<<dim3((n + 255) / 256), blk, 0, stream>>>(
            y_e, e_out, colsum_e, colsq_e, bne_g, bne_b, (float*)d_out + (size_t)N_NODES * DIM, E_EDGES, EDIM);
    }
}

// Round 7
// 1810.366 us; speedup vs baseline: 1.4633x; 1.1285x over previous
//
#include <hip/hip_runtime.h>
#include <math.h>
#include <stdint.h>

#define N_NODES 50000
#define E_EDGES 400000
#define DIM 128
#define HEADS 8
#define CH 16
#define EDIM 64
#define HCDIM 128   // HEADS*CH

#define NODE_WAVES 4

using bf16x8 = __attribute__((ext_vector_type(8))) short;
using f32x4v = __attribute__((ext_vector_type(4))) float;

// ---------------- utility ----------------

__global__ void fill_kernel(float* p, float v, int n) {
    int i = blockIdx.x * blockDim.x + threadIdx.x;
    if (i < n) p[i] = v;
}

__global__ void concat3_kernel(const float* __restrict__ a, const float* __restrict__ b,
                               const float* __restrict__ c, float* __restrict__ o) {
    int i = blockIdx.x * 256 + threadIdx.x;
    if (i < 128) o[i] = a[i];
    else if (i < 256) o[i] = b[i - 128];
    else if (i < 384) o[i] = c[i - 256];
}

__device__ inline float gelu_f(float x) {
    return 0.5f * x * (1.0f + erff(x * 0.70710678118654752f));
}

__device__ inline float softplus_f(float x) {
    return x > 20.f ? x : log1pf(expf(x));
}

__device__ inline unsigned short f32_to_bf16_rn(float f) {
    unsigned u = __float_as_uint(f);
    u += 0x7FFFu + ((u >> 16) & 1u);
    return (unsigned short)(u >> 16);
}
__device__ inline float bf16_to_f32(unsigned short h) {
    return __uint_as_float((unsigned)h << 16);
}

// ---------------- weight pre-transpose + bf16 split ----------------
// in: W (KxN f32, row-major). out: hi/lo bf16 planes, [n][k] layout.
__global__ __launch_bounds__(256) void wsplit_kernel(
    const float* __restrict__ W, unsigned short* __restrict__ hi,
    unsigned short* __restrict__ lo, int K, int N)
{
    int idx = blockIdx.x * 256 + threadIdx.x;
    if (idx >= K * N) return;
    int n = idx / K, k = idx - n * K;
    float x = W[(size_t)k * N + n];
    unsigned short h = f32_to_bf16_rn(x);
    hi[idx] = h;
    lo[idx] = f32_to_bf16_rn(x - bf16_to_f32(h));
}

// Same, but k-slots permuted within each 32-block to match the packed-hidden
// fragment layout of ffn2_nobar's GEMM2: slot s holds source k = base + pi(s),
// pi(s): lg=s>>3, j=s&7 -> (j<4 ? lg*4+j : 16+lg*4+(j-4))  (bijection on [0,32)).
__global__ __launch_bounds__(256) void wsplit_perm_kernel(
    const float* __restrict__ W, unsigned short* __restrict__ hi,
    unsigned short* __restrict__ lo, int K, int N)
{
    int idx = blockIdx.x * 256 + threadIdx.x;
    if (idx >= K * N) return;
    int n = idx / K, k = idx - n * K;
    int s = k & 31, base = k & ~31;
    int lgp = s >> 3, j = s & 7;
    int ksrc = base + ((j < 4) ? (lgp * 4 + j) : (16 + lgp * 4 + (j - 4)));
    float x = W[(size_t)ksrc * N + n];
    unsigned short h = f32_to_bf16_rn(x);
    hi[idx] = h;
    lo[idx] = f32_to_bf16_rn(x - bf16_to_f32(h));
}

// ---------------- MFMA GEMM (single): C = act(A @ W + bias) ----------------
template<int BN>
__global__ __launch_bounds__(256) void gemm_mfma(
    const float* __restrict__ A,
    const unsigned short* __restrict__ Whi, const unsigned short* __restrict__ Wlo,
    const float* __restrict__ bias, const float* __restrict__ ascale,
    float* __restrict__ C, int M, int K, int Nc, int act, int cmode)
{
    constexpr int MT = (BN == 128) ? 4 : 2;
    __shared__ bf16x8 As[2][4][128];   // [plane hi/lo][k-granule][row], 16 KB

    const int tid = threadIdx.x;
    const int w = tid >> 6, lane = tid & 63;
    const int l15 = lane & 15, lg = lane >> 4;
    const int m0 = blockIdx.y * 128;
    const int n0 = blockIdx.x * BN;
    const int rowbase = (BN == 128) ? (w >> 1) * 64 : w * 32;
    const int colbase = (BN == 128) ? (w & 1) * 64 : 0;
    const int k16 = K >> 4;

    f32x4v acc[MT][4];
#pragma unroll
    for (int i = 0; i < MT; ++i)
#pragma unroll
        for (int j = 0; j < 4; ++j)
#pragma unroll
            for (int cidx = 0; cidx < 4; ++cidx) acc[i][j][cidx] = 0.f;

    for (int k0 = 0; k0 < K; k0 += 32) {
#pragma unroll
        for (int it = 0; it < 2; ++it) {
            int row = w * 16 + l15 + it * 64;
            int ar = m0 + row;
            float v[8];
            if (ar < M) {
                const float* ap = A + (size_t)ar * K + k0 + lg * 8;
                *(float4*)&v[0] = *(const float4*)ap;
                *(float4*)&v[4] = *(const float4*)(ap + 4);
                if (ascale) {
                    float s = ascale[(size_t)ar * k16 + ((k0 >> 4) + (lg >> 1))];
#pragma unroll
                    for (int j = 0; j < 8; ++j) v[j] *= s;
                }
            } else {
#pragma unroll
                for (int j = 0; j < 8; ++j) v[j] = 0.f;
            }
            bf16x8 gh, gl;
#pragma unroll
            for (int j = 0; j < 8; ++j) {
                unsigned short h = f32_to_bf16_rn(v[j]);
                gh[j] = (short)h;
                gl[j] = (short)f32_to_bf16_rn(v[j] - bf16_to_f32(h));
            }
            As[0][lg][row] = gh;
            As[1][lg][row] = gl;
        }
        bf16x8 bh[4], bl[4];
#pragma unroll
        for (int nt = 0; nt < 4; ++nt) {
            size_t off = (size_t)(n0 + colbase + nt * 16 + l15) * K + k0 + lg * 8;
            bh[nt] = *(const bf16x8*)(Whi + off);
            bl[nt] = *(const bf16x8*)(Wlo + off);
        }
        __syncthreads();
#pragma unroll
        for (int mt = 0; mt < MT; ++mt) {
            int arow = rowbase + mt * 16 + l15;
            bf16x8 ah = As[0][lg][arow];
            bf16x8 al = As[1][lg][arow];
#pragma unroll
            for (int nt = 0; nt < 4; ++nt) {
                acc[mt][nt] = __builtin_amdgcn_mfma_f32_16x16x32_bf16(ah, bh[nt], acc[mt][nt], 0, 0, 0);
                acc[mt][nt] = __builtin_amdgcn_mfma_f32_16x16x32_bf16(al, bh[nt], acc[mt][nt], 0, 0, 0);
                acc[mt][nt] = __builtin_amdgcn_mfma_f32_16x16x32_bf16(ah, bl[nt], acc[mt][nt], 0, 0, 0);
            }
        }
        __syncthreads();
    }

#pragma unroll
    for (int nt = 0; nt < 4; ++nt) {
        int col = n0 + colbase + nt * 16 + l15;
        float bb = bias ? bias[col] : 0.f;
#pragma unroll
        for (int mt = 0; mt < MT; ++mt) {
#pragma unroll
            for (int i = 0; i < 4; ++i) {
                int r = m0 + rowbase + mt * 16 + lg * 4 + i;
                if (r < M) {
                    float o = acc[mt][nt][i] + bb;
                    if (act == 1) o = gelu_f(o);
                    if (cmode == 1) {
                        C[(size_t)(col >> 7) * ((size_t)N_NODES * HCDIM) + (size_t)r * HCDIM + (col & 127)] = o;
                    } else {
                        C[(size_t)r * Nc + col] = o;
                    }
                }
            }
        }
    }
}

static inline void launch_mfma(const float* A, const unsigned short* Whi, const unsigned short* Wlo,
                               const float* bias, const float* ascale, float* C,
                               int M, int K, int Nc, int act, int cmode, hipStream_t stream)
{
    int gy = (M + 127) / 128;
    if (Nc % 128 == 0)
        gemm_mfma<128><<<dim3(Nc / 128, gy), dim3(256), 0, stream>>>(A, Whi, Wlo, bias, ascale, C, M, K, Nc, act, cmode);
    else
        gemm_mfma<64><<<dim3(Nc / 64, gy), dim3(256), 0, stream>>>(A, Whi, Wlo, bias, ascale, C, M, K, Nc, act, cmode);
}

// ---------------- fused eproj + logits ----------------
// eproj3 = edge_attr @ WeK3 (computed per 128-edge tile, never stored);
// logit[e][h] = 0.25*(c0[d,h] + sum_j A2[d][h*16+j]*K[s][h*16+j] + sum_j Q[d][h*16+j]*ep[e][h*16+j])
// Epilogue exploits the D-fragment layout: lane (lg,l15) holds ep[e][h*16+l15] -> 16-lane
// shfl_xor tree does the j-sum. Kills the 205MB ep write + 205MB re-read + 4 extra dispatches.
__global__ __launch_bounds__(256) void eproj_logits_kernel(
    const float* __restrict__ EA,
    const unsigned short* __restrict__ Whi, const unsigned short* __restrict__ Wlo,
    const float* __restrict__ Qp, const float* __restrict__ Kp,
    const float* __restrict__ A2, const float* __restrict__ c0,
    const int* __restrict__ src, const int* __restrict__ dst,
    float* __restrict__ logits)
{
    __shared__ bf16x8 As[2][4][128];
    const int tid = threadIdx.x;
    const int w = tid >> 6, lane = tid & 63;
    const int l15 = lane & 15, lg = lane >> 4;
    const int m0 = blockIdx.x * 128;
    const int rowbase = (w >> 1) * 64;
    const int colbase = (w & 1) * 64;

    f32x4v acc[4][4];
#pragma unroll
    for (int i = 0; i < 4; ++i)
#pragma unroll
        for (int j = 0; j < 4; ++j)
#pragma unroll
            for (int cidx = 0; cidx < 4; ++cidx) acc[i][j][cidx] = 0.f;

    for (int k0 = 0; k0 < EDIM; k0 += 32) {
#pragma unroll
        for (int it = 0; it < 2; ++it) {
            int row = w * 16 + l15 + it * 64;
            const float* ap = EA + (size_t)(m0 + row) * EDIM + k0 + lg * 8;
            float v[8];
            *(float4*)&v[0] = *(const float4*)ap;
            *(float4*)&v[4] = *(const float4*)(ap + 4);
            bf16x8 gh, gl;
#pragma unroll
            for (int j = 0; j < 8; ++j) {
                unsigned short h = f32_to_bf16_rn(v[j]);
                gh[j] = (short)h;
                gl[j] = (short)f32_to_bf16_rn(v[j] - bf16_to_f32(h));
            }
            As[0][lg][row] = gh;
            As[1][lg][row] = gl;
        }
        bf16x8 bh[4], bl[4];
#pragma unroll
        for (int nt = 0; nt < 4; ++nt) {
            size_t off = (size_t)(colbase + nt * 16 + l15) * EDIM + k0 + lg * 8;
            bh[nt] = *(const bf16x8*)(Whi + off);
            bl[nt] = *(const bf16x8*)(Wlo + off);
        }
        __syncthreads();
#pragma unroll
        for (int mt = 0; mt < 4; ++mt) {
            int arow = rowbase + mt * 16 + l15;
            bf16x8 ah = As[0][lg][arow];
            bf16x8 al = As[1][lg][arow];
#pragma unroll
            for (int nt = 0; nt < 4; ++nt) {
                acc[mt][nt] = __builtin_amdgcn_mfma_f32_16x16x32_bf16(ah, bh[nt], acc[mt][nt], 0, 0, 0);
                acc[mt][nt] = __builtin_amdgcn_mfma_f32_16x16x32_bf16(al, bh[nt], acc[mt][nt], 0, 0, 0);
                acc[mt][nt] = __builtin_amdgcn_mfma_f32_16x16x32_bf16(ah, bl[nt], acc[mt][nt], 0, 0, 0);
            }
        }
        __syncthreads();
    }

    // ---- logits epilogue ----
    const int hbase = (w & 1) * 4;
#pragma unroll
    for (int mt = 0; mt < 4; ++mt) {
#pragma unroll
        for (int i = 0; i < 4; ++i) {
            int e = m0 + rowbase + mt * 16 + lg * 4 + i;
            int d = dst[e], s = src[e];
            const float* qd  = Qp + (size_t)d * HCDIM + hbase * 16;
            const float* a2d = A2 + (size_t)d * HCDIM + hbase * 16;
            const float* ks  = Kp + (size_t)s * HCDIM + hbase * 16;
            float part[4];
#pragma unroll
            for (int nt = 0; nt < 4; ++nt) {
                int cc = nt * 16 + l15;
                part[nt] = acc[mt][nt][i] * qd[cc] + a2d[cc] * ks[cc];
            }
#pragma unroll
            for (int o = 1; o < 16; o <<= 1) {
#pragma unroll
                for (int nt = 0; nt < 4; ++nt) part[nt] += __shfl_xor(part[nt], o);
            }
            if (l15 == 0) {
                const float* c0d = c0 + (size_t)d * HEADS + hbase;
#pragma unroll
                for (int nt = 0; nt < 4; ++nt)
                    logits[(size_t)e * HEADS + hbase + nt] = (c0d[nt] + part[nt]) * 0.25f;
            }
        }
    }
}

// ---------------- barrier-free fused double GEMM ----------------
// out = (act(A@W1 + b1) [* ascale]) @ W2 + b2  [+ LN+resid]
// GEMM1 swapped; hidden consumed from registers via pi()-permuted W2. NO LDS/barriers.
template<int MT, int K1, int NH, int N2, int ACT1, int ASC, int LN2>
__global__ __launch_bounds__(256) void ffn2_nobar(
    const float* __restrict__ A,
    const unsigned short* __restrict__ W1hi, const unsigned short* __restrict__ W1lo,
    const float* __restrict__ b1,
    const unsigned short* __restrict__ W2hi, const unsigned short* __restrict__ W2lo,
    const float* __restrict__ b2,
    const float* __restrict__ ascale,
    const float* __restrict__ lng, const float* __restrict__ lnb,
    const float* __restrict__ resid,
    float* __restrict__ Cout, int M)
{
    constexpr int NK = K1 / 32;    // GEMM1 k-steps
    constexpr int NT2 = N2 / 16;   // output col tiles
    constexpr int NI = NH / 16;    // hidden subtiles
    constexpr int NP = NH / 32;    // hidden subtile pairs (= GEMM2 k-steps)
    const int tid = threadIdx.x;
    const int w = tid >> 6, lane = tid & 63;
    const int l15 = lane & 15, lg = lane >> 4;
    const int row0 = (blockIdx.x * 4 + w) * (MT * 16);

    bf16x8 aAh[MT][NK], aAl[MT][NK];
#pragma unroll
    for (int mt = 0; mt < MT; ++mt) {
        int r = row0 + mt * 16 + l15;
#pragma unroll
        for (int ks = 0; ks < NK; ++ks) {
            float v[8];
            if (r < M) {
                const float* ap = A + (size_t)r * K1 + ks * 32 + lg * 8;
                *(float4*)&v[0] = *(const float4*)ap;
                *(float4*)&v[4] = *(const float4*)(ap + 4);
            } else {
#pragma unroll
                for (int j = 0; j < 8; ++j) v[j] = 0.f;
            }
            bf16x8 gh, gl;
#pragma unroll
            for (int j = 0; j < 8; ++j) {
                unsigned short h = f32_to_bf16_rn(v[j]);
                gh[j] = (short)h;
                gl[j] = (short)f32_to_bf16_rn(v[j] - bf16_to_f32(h));
            }
            aAh[mt][ks] = gh;
            aAl[mt][ks] = gl;
        }
    }

    f32x4v oacc[MT][NT2];
#pragma unroll
    for (int mt = 0; mt < MT; ++mt)
#pragma unroll
        for (int nt = 0; nt < NT2; ++nt)
#pragma unroll
            for (int c = 0; c < 4; ++c) oacc[mt][nt][c] = 0.f;

    for (int p = 0; p < NP; ++p) {
        bf16x8 hh[MT], hl[MT];
#pragma unroll
        for (int half = 0; half < 2; ++half) {
            const int it = p * 2 + half;
            f32x4v h[MT];
#pragma unroll
            for (int mt = 0; mt < MT; ++mt)
#pragma unroll
                for (int c = 0; c < 4; ++c) h[mt][c] = 0.f;
#pragma unroll
            for (int ks = 0; ks < NK; ++ks) {
                size_t off = (size_t)(it * 16 + l15) * K1 + ks * 32 + lg * 8;
                bf16x8 xh = *(const bf16x8*)(W1hi + off);
                bf16x8 xl = *(const bf16x8*)(W1lo + off);
#pragma unroll
                for (int mt = 0; mt < MT; ++mt) {
                    h[mt] = __builtin_amdgcn_mfma_f32_16x16x32_bf16(xh, aAh[mt][ks], h[mt], 0, 0, 0);
                    h[mt] = __builtin_amdgcn_mfma_f32_16x16x32_bf16(xl, aAh[mt][ks], h[mt], 0, 0, 0);
                    h[mt] = __builtin_amdgcn_mfma_f32_16x16x32_bf16(xh, aAl[mt][ks], h[mt], 0, 0, 0);
                }
            }
            float b1a[4] = {0.f, 0.f, 0.f, 0.f};
            if (b1) *(float4*)b1a = *(const float4*)(b1 + it * 16 + lg * 4);
#pragma unroll
            for (int mt = 0; mt < MT; ++mt) {
                float sc = 1.f;
                if (ASC) {
                    int r = row0 + mt * 16 + l15;
                    sc = (r < M) ? ascale[(size_t)r * NI + it] : 0.f;
                }
#pragma unroll
                for (int i = 0; i < 4; ++i) {
                    float o = h[mt][i] + b1a[i];
                    if (ACT1) o = gelu_f(o);
                    if (ASC) o *= sc;
                    unsigned short oh = f32_to_bf16_rn(o);
                    hh[mt][half * 4 + i] = (short)oh;
                    hl[mt][half * 4 + i] = (short)f32_to_bf16_rn(o - bf16_to_f32(oh));
                }
            }
        }
#pragma unroll
        for (int nt2 = 0; nt2 < NT2; ++nt2) {
            size_t off2 = (size_t)(nt2 * 16 + l15) * NH + p * 32 + lg * 8;
            bf16x8 x2h = *(const bf16x8*)(W2hi + off2);
            bf16x8 x2l = *(const bf16x8*)(W2lo + off2);
#pragma unroll
            for (int mt = 0; mt < MT; ++mt) {
                oacc[mt][nt2] = __builtin_amdgcn_mfma_f32_16x16x32_bf16(x2h, hh[mt], oacc[mt][nt2], 0, 0, 0);
                oacc[mt][nt2] = __builtin_amdgcn_mfma_f32_16x16x32_bf16(x2l, hh[mt], oacc[mt][nt2], 0, 0, 0);
                oacc[mt][nt2] = __builtin_amdgcn_mfma_f32_16x16x32_bf16(x2h, hl[mt], oacc[mt][nt2], 0, 0, 0);
            }
        }
    }

    float b2a[NT2][4];
#pragma unroll
    for (int nt2 = 0; nt2 < NT2; ++nt2) {
        if (b2) *(float4*)b2a[nt2] = *(const float4*)(b2 + nt2 * 16 + lg * 4);
        else { b2a[nt2][0] = 0.f; b2a[nt2][1] = 0.f; b2a[nt2][2] = 0.f; b2a[nt2][3] = 0.f; }
    }
    if (LN2) {
        float ga[NT2][4], bba[NT2][4];
#pragma unroll
        for (int nt2 = 0; nt2 < NT2; ++nt2) {
            *(float4*)ga[nt2] = *(const float4*)(lng + nt2 * 16 + lg * 4);
            *(float4*)bba[nt2] = *(const float4*)(lnb + nt2 * 16 + lg * 4);
        }
#pragma unroll
        for (int mt = 0; mt < MT; ++mt) {
            int r = row0 + mt * 16 + l15;
            float o[NT2][4];
            float s = 0.f;
#pragma unroll
            for (int nt2 = 0; nt2 < NT2; ++nt2)
#pragma unroll
                for (int i = 0; i < 4; ++i) { o[nt2][i] = oacc[mt][nt2][i] + b2a[nt2][i]; s += o[nt2][i]; }
            s += __shfl_xor(s, 16); s += __shfl_xor(s, 32);
            float mean = s * (1.f / (float)N2);
            float q = 0.f;
#pragma unroll
            for (int nt2 = 0; nt2 < NT2; ++nt2)
#pragma unroll
                for (int i = 0; i < 4; ++i) { o[nt2][i] -= mean; q += o[nt2][i] * o[nt2][i]; }
            q += __shfl_xor(q, 16); q += __shfl_xor(q, 32);
            float inv = rsqrtf(q * (1.f / (float)N2) + 1e-5f);
            if (r < M) {
#pragma unroll
                for (int nt2 = 0; nt2 < NT2; ++nt2) {
                    float4 rv = *(const float4*)(resid + (size_t)r * N2 + nt2 * 16 + lg * 4);
                    float4 ov;
                    ov.x = o[nt2][0] * inv * ga[nt2][0] + bba[nt2][0] + rv.x;
                    ov.y = o[nt2][1] * inv * ga[nt2][1] + bba[nt2][1] + rv.y;
                    ov.z = o[nt2][2] * inv * ga[nt2][2] + bba[nt2][2] + rv.z;
                    ov.w = o[nt2][3] * inv * ga[nt2][3] + bba[nt2][3] + rv.w;
                    *(float4*)(Cout + (size_t)r * N2 + nt2 * 16 + lg * 4) = ov;
                }
            }
        }
    } else {
#pragma unroll
        for (int mt = 0; mt < MT; ++mt) {
            int r = row0 + mt * 16 + l15;
            if (r < M) {
#pragma unroll
                for (int nt2 = 0; nt2 < NT2; ++nt2) {
                    float4 ov;
                    ov.x = oacc[mt][nt2][0] + b2a[nt2][0];
                    ov.y = oacc[mt][nt2][1] + b2a[nt2][1];
                    ov.z = oacc[mt][nt2][2] + b2a[nt2][2];
                    ov.w = oacc[mt][nt2][3] + b2a[nt2][3];
                    *(float4*)(Cout + (size_t)r * N2 + nt2 * 16 + lg * 4) = ov;
                }
            }
        }
    }
}

// ---------------- precompute: WeX[k][h*16+j] = sum_c We[k][h*16+c] * X[c][j] ----------------
__global__ __launch_bounds__(256) void wex_kernel(
    const float* __restrict__ We, const float* __restrict__ X, float* __restrict__ out)
{
    int idx = blockIdx.x * 256 + threadIdx.x;
    if (idx >= 64 * 128) return;
    int k = idx >> 7, hj = idx & 127, h = hj >> 4, j = hj & 15;
    float s = 0.f;
#pragma unroll
    for (int c = 0; c < 16; ++c) s += We[k * 128 + h * 16 + c] * X[c * 16 + j];
    out[idx] = s;
}

// ---------------- precompute per (d,h): c0 = Q·(K@Wk1 + bke); A2[c] = sum_j Wk2[c][j]*Q[j] ----------------
__global__ __launch_bounds__(256) void qk_pre_kernel(
    const float* __restrict__ Q, const float* __restrict__ K,
    const float* __restrict__ Wke, const float* __restrict__ bke,
    float* __restrict__ A2, float* __restrict__ c0)
{
    __shared__ float wk1[256], wk2[256], bks[16];
    for (int i = threadIdx.x; i < 256; i += 256) { wk1[i] = Wke[i]; wk2[i] = Wke[256 + i]; }
    if (threadIdx.x < 16) bks[threadIdx.x] = bke[threadIdx.x];
    __syncthreads();
    int idx = blockIdx.x * 256 + threadIdx.x;   // idx = ((d*8 + h)*16 + j)
    int j = idx & 15; int dh = idx >> 4; int h = dh & 7; int d = dh >> 3;
    if (d >= N_NODES) return;
    const float* q = Q + (size_t)d * HCDIM + h * CH;
    const float* k = K + (size_t)d * HCDIM + h * CH;
    float qv[16], kv[16];
#pragma unroll
    for (int t = 0; t < 4; ++t) {
        *(float4*)&qv[t * 4] = *(const float4*)(q + t * 4);
        *(float4*)&kv[t * 4] = *(const float4*)(k + t * 4);
    }
    float a2 = 0.f;
#pragma unroll
    for (int t = 0; t < 16; ++t) a2 += wk2[j * 16 + t] * qv[t];
    A2[idx] = a2;
    float kn = bks[j];
#pragma unroll
    for (int c = 0; c < 16; ++c) kn += kv[c] * wk1[c * 16 + j];
    float t = qv[j] * kn;
    t += __shfl_xor(t, 1); t += __shfl_xor(t, 2); t += __shfl_xor(t, 4); t += __shfl_xor(t, 8);
    if (j == 0) c0[dh] = t;
}

// ---------------- CSR build ----------------
__global__ __launch_bounds__(256) void count_kernel(const int* __restrict__ dst, int* __restrict__ cnt) {
    int e = blockIdx.x * 256 + threadIdx.x;
    if (e < E_EDGES) atomicAdd(&cnt[dst[e]], 1);
}

__global__ __launch_bounds__(1024) void scan_kernel(
    const int* __restrict__ cnt, int* __restrict__ rowptr, int* __restrict__ cursor, int n)
{
    __shared__ int buf[1024];
    __shared__ int base;
    int tid = threadIdx.x;
    if (tid == 0) { base = 0; rowptr[0] = 0; }
    __syncthreads();
    for (int t0 = 0; t0 < n; t0 += 1024) {
        int i = t0 + tid;
        int v = (i < n) ? cnt[i] : 0;
        buf[tid] = v;
        __syncthreads();
        for (int off = 1; off < 1024; off <<= 1) {
            int add = (tid >= off) ? buf[tid - off] : 0;
            __syncthreads();
            buf[tid] += add;
            __syncthreads();
        }
        if (i < n) { rowptr[i + 1] = base + buf[tid]; cursor[i] = base + buf[tid] - v; }
        __syncthreads();
        if (tid == 0) base += buf[1023];
        __syncthreads();
    }
}

__global__ __launch_bounds__(256) void scatter_kernel(
    const int* __restrict__ dst, int* __restrict__ cursor, int* __restrict__ eidx) {
    int e = blockIdx.x * 256 + threadIdx.x;
    if (e < E_EDGES) {
        int p = atomicAdd(&cursor[dst[e]], 1);
        eidx[p] = e;
    }
}

// ---------------- per-node attention ----------------
// stage layout (per wave): wea[8][64] at stride 65 (h*65+k), aggv[8][16] at 520 stride 17
// -> conflict-free k-loop reads (h*65+k distinct banks per h) and aggv (h*17 distinct).
__global__ __launch_bounds__(256) void node_attn_kernel(
    const float* __restrict__ Vb, const float* __restrict__ edge_attr,
    float* __restrict__ logits,
    const int* __restrict__ rowptr, const int* __restrict__ eidx,
    const int* __restrict__ src,
    const float* __restrict__ Wve, const float* __restrict__ bve,
    const float* __restrict__ WeWv3, float* __restrict__ aggout)
{
    __shared__ float wv1s[256], wv2s[256], bvs[16];
    __shared__ float stage[NODE_WAVES][656];

    for (int i = threadIdx.x; i < 256; i += 256) { wv1s[i] = Wve[i]; wv2s[i] = Wve[256 + i]; }
    if (threadIdx.x < 16) bvs[threadIdx.x] = bve[threadIdx.x];
    __syncthreads();

    int w = threadIdx.x >> 6, lane = threadIdx.x & 63;
    int d = blockIdx.x * NODE_WAVES + w;
    int r0 = rowptr[d], r1 = rowptr[d + 1], deg = r1 - r0;
    int h = lane >> 3, kg = lane & 7;

    if (deg == 0) {
        aggout[(size_t)d * HCDIM + lane] = 0.f;
        aggout[(size_t)d * HCDIM + 64 + lane] = 0.f;
    } else {
        float m[8], ssum[8];
        if (deg <= 64) {
            // fast path: one logits read, kept in registers across max+sum
            float l[8];
            if (r0 + lane < r1) {
                int e = eidx[r0 + lane];
                const float* lp = logits + (size_t)e * HEADS;
                *(float4*)&l[0] = *(const float4*)lp;
                *(float4*)&l[4] = *(const float4*)(lp + 4);
            } else {
#pragma unroll
                for (int t = 0; t < 8; ++t) l[t] = -INFINITY;
            }
#pragma unroll
            for (int t = 0; t < 8; ++t) m[t] = l[t];
#pragma unroll
            for (int o = 1; o < 64; o <<= 1) {
#pragma unroll
                for (int t = 0; t < 8; ++t) m[t] = fmaxf(m[t], __shfl_xor(m[t], o));
            }
#pragma unroll
            for (int t = 0; t < 8; ++t) ssum[t] = expf(l[t] - m[t]);
#pragma unroll
            for (int o = 1; o < 64; o <<= 1) {
#pragma unroll
                for (int t = 0; t < 8; ++t) ssum[t] += __shfl_xor(ssum[t], o);
            }
        } else {
#pragma unroll
            for (int t = 0; t < 8; ++t) { m[t] = -INFINITY; ssum[t] = 0.f; }
            for (int i = r0 + lane; i < r1; i += 64) {
                int e = eidx[i];
                const float* lp = logits + (size_t)e * HEADS;
                float l[8];
                *(float4*)&l[0] = *(const float4*)lp;
                *(float4*)&l[4] = *(const float4*)(lp + 4);
#pragma unroll
                for (int t = 0; t < 8; ++t) m[t] = fmaxf(m[t], l[t]);
            }
#pragma unroll
            for (int o = 1; o < 64; o <<= 1) {
#pragma unroll
                for (int t = 0; t < 8; ++t) m[t] = fmaxf(m[t], __shfl_xor(m[t], o));
            }
            for (int i = r0 + lane; i < r1; i += 64) {
                int e = eidx[i];
                const float* lp = logits + (size_t)e * HEADS;
                float l[8];
                *(float4*)&l[0] = *(const float4*)lp;
                *(float4*)&l[4] = *(const float4*)(lp + 4);
#pragma unroll
                for (int t = 0; t < 8; ++t) ssum[t] += expf(l[t] - m[t]);
            }
#pragma unroll
            for (int o = 1; o < 64; o <<= 1) {
#pragma unroll
                for (int t = 0; t < 8; ++t) ssum[t] += __shfl_xor(ssum[t], o);
            }
        }
        float mh = m[0], dd = ssum[0];
#pragma unroll
        for (int t = 1; t < 8; ++t) { if (h == t) { mh = m[t]; dd = ssum[t]; } }
        float den = dd + 1e-16f;

        float wea[8] = {0.f, 0.f, 0.f, 0.f, 0.f, 0.f, 0.f, 0.f};
        float av0 = 0.f, av1 = 0.f;
        for (int i = r0; i < r1; ++i) {
            int e = eidx[i];
            float lg = logits[(size_t)e * HEADS + h];
            float alpha = expf(lg - mh) / den;
            if (kg == 0) logits[(size_t)e * HEADS + h] = alpha;
            int s = src[e];
            const float* ea = edge_attr + (size_t)e * EDIM + kg * 8;
            float ev[8];
            *(float4*)&ev[0] = *(const float4*)ea;
            *(float4*)&ev[4] = *(const float4*)(ea + 4);
#pragma unroll
            for (int t = 0; t < 8; ++t) wea[t] += alpha * ev[t];
            float2 vv = *(const float2*)(Vb + (size_t)s * HCDIM + h * CH + kg * 2);
            av0 += alpha * vv.x;
            av1 += alpha * vv.y;
        }
        float* st = stage[w];
#pragma unroll
        for (int t = 0; t < 8; ++t) st[h * 65 + kg * 8 + t] = wea[t];
        st[520 + h * 17 + kg * 2] = av0;
        st[520 + h * 17 + kg * 2 + 1] = av1;
    }
    __syncthreads();
    if (deg > 0) {
        float* st = stage[w];
        int c0i = kg * 2;
        float acc0 = bvs[c0i], acc1 = bvs[c0i + 1];
        const float* vd = Vb + (size_t)d * HCDIM + h * CH;
#pragma unroll
        for (int j = 0; j < 16; ++j) {
            float vj = vd[j];
            float a = st[520 + h * 17 + j];
            acc0 += vj * wv1s[j * 16 + c0i] + a * wv2s[j * 16 + c0i];
            acc1 += vj * wv1s[j * 16 + c0i + 1] + a * wv2s[j * 16 + c0i + 1];
        }
        const float* w3 = WeWv3 + h * 16 + c0i;
#pragma unroll 16
        for (int k = 0; k < 64; ++k) {
            float wv = st[h * 65 + k];
            float2 w2v = *(const float2*)(w3 + k * 128);
            acc0 += wv * w2v.x;
            acc1 += wv * w2v.y;
        }
        aggout[(size_t)d * HCDIM + h * CH + c0i] = acc0;
        aggout[(size_t)d * HCDIM + h * CH + c0i + 1] = acc1;
    }
}

// ---------------- layernorm (+ residual) ----------------
__global__ __launch_bounds__(256) void ln_res_kernel(
    float* __restrict__ y, const float* __restrict__ g, const float* __restrict__ b,
    const float* __restrict__ res, int rows, int w)
{
    int wave = threadIdx.x >> 6;
    int lane = threadIdx.x & 63;
    int nw = blockDim.x >> 6;
    for (int r = blockIdx.x * nw + wave; r < rows; r += gridDim.x * nw) {
        size_t base = (size_t)r * w;
        float v0 = y[base + lane];
        float v1 = (w == 128) ? y[base + 64 + lane] : 0.f;
        float s = v0 + v1;
#pragma unroll
        for (int o = 32; o; o >>= 1) s += __shfl_xor(s, o);
        float m = s / (float)w;
        float d0 = v0 - m;
        float d1 = (w == 128) ? (v1 - m) : 0.f;
        float q = d0 * d0 + d1 * d1;
#pragma unroll
        for (int o = 32; o; o >>= 1) q += __shfl_xor(q, o);
        float inv = rsqrtf(q / (float)w + 1e-5f);
        y[base + lane] = d0 * inv * g[lane] + b[lane] + res[base + lane];
        if (w == 128)
            y[base + 64 + lane] = d1 * inv * g[64 + lane] + b[64 + lane] + res[base + 64 + lane];
    }
}

// ---------------- batchnorm stats ----------------
__global__ __launch_bounds__(256) void bn_stats_kernel(
    const float* __restrict__ y, float* __restrict__ colsum, float* __restrict__ colsq,
    int rows, int cols)
{
    __shared__ float ss[256], sq[256];
    int tid = threadIdx.x;
    int col = tid % cols;
    int rsub = tid / cols;
    int rstep = blockDim.x / cols;
    float ls = 0.f, lq = 0.f;
    for (int r = blockIdx.x * rstep + rsub; r < rows; r += gridDim.x * rstep) {
        float v = y[(size_t)r * cols + col];
        ls += v;
        lq += v * v;
    }
    ss[tid] = ls;
    sq[tid] = lq;
    __syncthreads();
    if (tid < cols) {
        for (int o = cols; o < 256; o += cols) { ls += ss[tid + o]; lq += sq[tid + o]; }
        atomicAdd(&colsum[tid], ls);
        atomicAdd(&colsq[tid], lq);
    }
}

// ---------------- batchnorm apply + residual + softplus ----------------
__global__ __launch_bounds__(256) void bn_apply_softplus_kernel(
    const float* __restrict__ y, const float* __restrict__ res,
    const float* __restrict__ colsum, const float* __restrict__ colsq,
    const float* __restrict__ g, const float* __restrict__ b,
    float* __restrict__ out, int rows, int cols)
{
    int idx = blockIdx.x * blockDim.x + threadIdx.x;
    int n = rows * cols;
    if (idx >= n) return;
    int c = idx % cols;
    float m = colsum[c] / (float)rows;
    float var = colsq[c] / (float)rows - m * m;
    float inv = rsqrtf(var + 1e-5f);
    float v = (y[idx] - m) * inv * g[c] + b[c] + res[idx];
    out[idx] = softplus_f(v);
}

// ---------------- launcher ----------------

extern "C" void kernel_launch(void* const* d_in, const int* in_sizes, int n_in,
                              void* d_out, int out_size, void* d_ws, size_t ws_size,
                              hipStream_t stream) {
    const float* x         = (const float*)d_in[0];
    const int*   ei        = (const int*)d_in[1];
    const float* edge_attr = (const float*)d_in[2];
    const float* Wq  = (const float*)d_in[3];
    const float* bq  = (const float*)d_in[4];
    const float* Wk  = (const float*)d_in[5];
    const float* bk  = (const float*)d_in[6];
    const float* Wv  = (const float*)d_in[7];
    const float* bv  = (const float*)d_in[8];
    const float* We  = (const float*)d_in[9];
    const float* Wke = (const float*)d_in[10];
    const float* bke = (const float*)d_in[11];
    const float* Wve = (const float*)d_in[12];
    const float* bve = (const float*)d_in[13];
    const float* Wfce = (const float*)d_in[14];
    const float* bfce = (const float*)d_in[15];
    const float* lne_g = (const float*)d_in[16];
    const float* lne_b = (const float*)d_in[17];
    const float* Wfcn = (const float*)d_in[18];
    const float* bfcn = (const float*)d_in[19];
    const float* lnn_g = (const float*)d_in[20];
    const float* lnn_b = (const float*)d_in[21];
    const float* W1n = (const float*)d_in[22];
    const float* b1n = (const float*)d_in[23];
    const float* W2n = (const float*)d_in[24];
    const float* b2n = (const float*)d_in[25];
    const float* W1e = (const float*)d_in[26];
    const float* b1e = (const float*)d_in[27];
    const float* W2e = (const float*)d_in[28];
    const float* b2e = (const float*)d_in[29];
    const float* bnn_g = (const float*)d_in[30];
    const float* bnn_b = (const float*)d_in[31];
    const float* bne_g = (const float*)d_in[32];
    const float* bne_b = (const float*)d_in[33];

    const int* src = ei;
    const int* dst = ei + E_EDGES;

    float* ws = (float*)d_ws;
    const size_t M64   = (size_t)E_EDGES * EDIM;       // 25.6M
    const size_t NODE2 = (size_t)N_NODES * HCDIM;      // 6.4M

    // regionR [0, 25.6M): Qb|Kb|Vb
    float* regionR = ws;
    float* Qb  = regionR;
    float* Kb  = regionR + NODE2;
    float* Vb  = regionR + 2 * NODE2;

    // overlayY [25.6M, 51.2M): logits|c0|csr|aggout|y_n|x_out; later y_e
    float* overlayY = ws + M64;
    float* logits = overlayY;                                  // 3.2M (holds alpha later)
    float* c0buf  = logits + (size_t)E_EDGES * HEADS;          // 0.4M
    int*   cnt_i    = (int*)(c0buf + (size_t)N_NODES * HEADS); // 50000
    int*   rowptr_i = cnt_i + N_NODES;                         // 50001
    int*   cursor_i = rowptr_i + N_NODES + 1;                  // 50000
    int*   eidx_i   = cursor_i + N_NODES;                      // 400000
    float* aggout = (float*)(((uintptr_t)(eidx_i + E_EDGES) + 15) & ~(uintptr_t)15); // 6.4M
    float* y_n    = aggout + NODE2;                            // 6.4M
    float* x_out  = y_n + NODE2;                               // 6.4M
    float* y_e    = overlayY;                                  // 25.6M (late phase)

    // e_out region [51.2M, 76.8M): A2 parks at its start (dead after logits)
    float* e_out = ws + 2 * M64;
    float* A2buf = e_out;                                      // 6.4M

    // tail [76.8M, +)
    float* tail = ws + 3 * M64;
    float* colsum_n = tail;            // 128
    float* colsq_n  = tail + 128;      // 128
    float* colsum_e = tail + 256;      // 64
    float* colsq_e  = tail + 320;      // 64
    float* WeK3  = tail + 384;         // 8192
    float* WeWv3 = WeK3 + 8192;        // 8192
    float* bqkv  = WeWv3 + 8192;       // 384

    // split-weight arena (bf16 hi/lo planes, [n][k] layout), ~1 MB
    unsigned short* wsp = (unsigned short*)(bqkv + 384);
    unsigned short* QKV_s  = wsp;                     // [384][128] hi then lo (49152 each)
    unsigned short* WeK3_s = QKV_s  + 2 * 49152;      // K=64,N=128
    unsigned short* We_s   = WeK3_s + 2 * 8192;       // K=64,N=128
    unsigned short* Wfce_s = We_s   + 2 * 8192;       // K=128,N=64 (perm)
    unsigned short* Wfcn_s = Wfce_s + 2 * 8192;       // K=128,N=128
    unsigned short* W1n_s  = Wfcn_s + 2 * 16384;      // K=128,N=512
    unsigned short* W2n_s  = W1n_s  + 2 * 65536;      // K=512,N=128 (perm)
    unsigned short* W1e_s  = W2n_s  + 2 * 65536;      // K=64,N=256
    unsigned short* W2e_s  = W1e_s  + 2 * 16384;      // K=256,N=64 (perm)

    dim3 blk(256);

    // ---- init ----
    fill_kernel<<<dim3(2), blk, 0, stream>>>(colsum_n, 0.f, 384);
    fill_kernel<<<dim3((N_NODES + 255) / 256), blk, 0, stream>>>((float*)cnt_i, 0.f, N_NODES);

    // ---- folded weights ----
    wex_kernel<<<dim3(32), blk, 0, stream>>>(We, Wke + 2 * CH * CH, WeK3);
    wex_kernel<<<dim3(32), blk, 0, stream>>>(We, Wve + 2 * CH * CH, WeWv3);

    // ---- weight transpose + bf16 split (W2-matrices of fused kernels: permuted) ----
    wsplit_kernel<<<dim3(64), blk, 0, stream>>>(Wq, QKV_s,          QKV_s + 49152,          128, 128);
    wsplit_kernel<<<dim3(64), blk, 0, stream>>>(Wk, QKV_s + 16384,  QKV_s + 49152 + 16384,  128, 128);
    wsplit_kernel<<<dim3(64), blk, 0, stream>>>(Wv, QKV_s + 32768,  QKV_s + 49152 + 32768,  128, 128);
    wsplit_kernel<<<dim3(32), blk, 0, stream>>>(WeK3, WeK3_s, WeK3_s + 8192,  64, 128);
    wsplit_kernel<<<dim3(32), blk, 0, stream>>>(We,   We_s,   We_s + 8192,    64, 128);
    wsplit_perm_kernel<<<dim3(32), blk, 0, stream>>>(Wfce, Wfce_s, Wfce_s + 8192,  128, 64);
    wsplit_kernel<<<dim3(64), blk, 0, stream>>>(Wfcn, Wfcn_s, Wfcn_s + 16384, 128, 128);
    wsplit_kernel<<<dim3(256), blk, 0, stream>>>(W1n, W1n_s, W1n_s + 65536,   128, 512);
    wsplit_perm_kernel<<<dim3(256), blk, 0, stream>>>(W2n, W2n_s, W2n_s + 65536,   512, 128);
    wsplit_kernel<<<dim3(64), blk, 0, stream>>>(W1e, W1e_s, W1e_s + 16384,    64, 256);
    wsplit_perm_kernel<<<dim3(64), blk, 0, stream>>>(W2e, W2e_s, W2e_s + 16384,    256, 64);
    concat3_kernel<<<dim3(2), blk, 0, stream>>>(bq, bk, bv, bqkv);

    // ---- QKV projection (merged, N=384, split-output) ----
    launch_mfma(x, QKV_s, QKV_s + 49152, bqkv, nullptr, Qb, N_NODES, 128, 384, 0, 1, stream);

    // ---- per-node QK precompute ----
    qk_pre_kernel<<<dim3(N_NODES * HCDIM / 256), blk, 0, stream>>>(Qb, Kb, Wke, bke, A2buf, c0buf);

    // ---- CSR build ----
    count_kernel<<<dim3((E_EDGES + 255) / 256), blk, 0, stream>>>(dst, cnt_i);
    scan_kernel<<<dim3(1), dim3(1024), 0, stream>>>(cnt_i, rowptr_i, cursor_i, N_NODES);
    scatter_kernel<<<dim3((E_EDGES + 255) / 256), blk, 0, stream>>>(dst, cursor_i, eidx_i);

    // ---- fused eproj + logits (single dispatch, no ep round-trip) ----
    eproj_logits_kernel<<<dim3(E_EDGES / 128), blk, 0, stream>>>(
        edge_attr, WeK3_s, WeK3_s + 8192, Qb, Kb, A2buf, c0buf, src, dst, logits);

    // ---- per-node softmax + aggregation; logits -> alpha ----
    node_attn_kernel<<<dim3(N_NODES / NODE_WAVES), blk, 0, stream>>>(
        Vb, edge_attr, logits, rowptr_i, eidx_i, src, Wve, bve, WeWv3, aggout);

    // ---- e_out = LN((alpha ⊙ (edge_attr@We)) @ Wfce + bfce) + edge_attr  (barrier-free fused) ----
    ffn2_nobar<2, 64, 128, 64, 0, 1, 1><<<dim3(E_EDGES / 128), blk, 0, stream>>>(
        edge_attr, We_s, We_s + 8192, nullptr, Wfce_s, Wfce_s + 8192, bfce,
        logits, lne_g, lne_b, edge_attr, e_out, E_EDGES);

    // ---- node output path ----
    launch_mfma(aggout, Wfcn_s, Wfcn_s + 16384, bfcn, nullptr, x_out, N_NODES, HCDIM, DIM, 0, 0, stream);
    ln_res_kernel<<<dim3(12500), blk, 0, stream>>>(x_out, lnn_g, lnn_b, x, N_NODES, DIM);

    // ---- node FFN (barrier-free fused W1n+gelu+W2n) + BN + residual + softplus ----
    ffn2_nobar<1, 128, 512, 128, 1, 0, 0><<<dim3((N_NODES + 63) / 64), blk, 0, stream>>>(
        x_out, W1n_s, W1n_s + 65536, b1n, W2n_s, W2n_s + 65536, b2n,
        nullptr, nullptr, nullptr, nullptr, y_n, N_NODES);
    bn_stats_kernel<<<dim3(256), blk, 0, stream>>>(y_n, colsum_n, colsq_n, N_NODES, DIM);
    {
        int n = N_NODES * DIM;
        bn_apply_softplus_kernel<<<dim3((n + 255) / 256), blk, 0, stream>>>(
            y_n, x_out, colsum_n, colsq_n, bnn_g, bnn_b, (float*)d_out, N_NODES, DIM);
    }

    // ---- edge FFN (barrier-free fused W1e+gelu+W2e) ----
    ffn2_nobar<2, 64, 256, 64, 1, 0, 0><<<dim3(E_EDGES / 128), blk, 0, stream>>>(
        e_out, W1e_s, W1e_s + 16384, b1e, W2e_s, W2e_s + 16384, b2e,
        nullptr, nullptr, nullptr, nullptr, y_e, E_EDGES);
    bn_stats_kernel<<<dim3(256), blk, 0, stream>>>(y_e, colsum_e, colsq_e, E_EDGES, EDIM);
    {
        int n = E_EDGES * EDIM;
        bn_apply_softplus_kernel<<<dim3((n + 255) / 256), blk, 0, stream>>>(
            y_e, e_out, colsum_e, colsq_e, bne_g, bne_b, (float*)d_out + (size_t)N_NODES * DIM, E_EDGES, EDIM);
    }
}